// Round 1
// baseline (11620.610 us; speedup 1.0000x reference)
//
#include <hip/hip_runtime.h>
#include <hip/hip_bf16.h>
#include <math.h>

#define BATCH 4
#define SEQ 2048
#define DMODEL 768
#define NLAYER 8
#define DINNER 1536
#define HEADDIM 64
#define NHEADS 24
#define DSTATE 128
#define CONVDIM 1792
#define DINPROJ 3352
#define NPAD 3456
#define ROWS (BATCH*SEQ)
#define EPS 1e-5f

typedef __bf16 bf16;
typedef bf16 bf16x8 __attribute__((ext_vector_type(8)));
typedef float f32x4 __attribute__((ext_vector_type(4)));

__device__ __forceinline__ float fsilu(float x) { return x / (1.f + __expf(-x)); }

// ---------------- embed: h = x @ W_emb^T + b_emb ; res = 0 ----------------
__global__ void k_embed(const float* __restrict__ x, const float* __restrict__ We,
                        const float* __restrict__ be, float* __restrict__ h,
                        float* __restrict__ res) {
    int idx = blockIdx.x * 256 + threadIdx.x;   // ROWS*DMODEL
    int d = idx % DMODEL; int bl = idx / DMODEL;
    float acc = be[d];
#pragma unroll
    for (int i = 0; i < 6; ++i) acc += x[bl * 6 + i] * We[d * 6 + i];
    h[idx] = acc;
    res[idx] = 0.f;
}

// ---------------- fused residual add + rmsnorm -> bf16 ----------------
__global__ __launch_bounds__(256) void k_add_rmsnorm(const float* __restrict__ hin,
                                                     float* __restrict__ res,
                                                     const float* __restrict__ w,
                                                     bf16* __restrict__ out) {
    __shared__ float sm[4];
    int r = blockIdx.x, tid = threadIdx.x;
    float v[3]; float ss = 0.f;
#pragma unroll
    for (int k = 0; k < 3; ++k) {
        int d = tid + k * 256;
        float t = res[r * DMODEL + d] + hin[r * DMODEL + d];
        res[r * DMODEL + d] = t; v[k] = t; ss += t * t;
    }
#pragma unroll
    for (int off = 32; off; off >>= 1) ss += __shfl_down(ss, off, 64);
    if ((tid & 63) == 0) sm[tid >> 6] = ss;
    __syncthreads();
    float tot = sm[0] + sm[1] + sm[2] + sm[3];
    float sc = rsqrtf(tot / (float)DMODEL + EPS);
#pragma unroll
    for (int k = 0; k < 3; ++k) {
        int d = tid + k * 256;
        out[r * DMODEL + d] = (bf16)(v[k] * sc * w[d]);
    }
}

// ---------------- weight f32 -> bf16 (with optional row pad) ----------------
__global__ void k_cvt(const float* __restrict__ src, bf16* __restrict__ dst, int nsrc, int K) {
    long idx = (long)blockIdx.x * 256 + threadIdx.x;
    int n = (int)(idx / K);
    dst[idx] = (n < nsrc) ? (bf16)src[idx] : (bf16)0.f;
}

// ---------------- bf16 MFMA GEMM: C[M,N] = A[M,K] @ B[N,K]^T ----------------
// 128x128 tile, BK=64, 256 threads (4 waves 2x2, each 64x64 = 4x4 frags of 16x16x32)
__global__ __launch_bounds__(256) void k_gemm(const bf16* __restrict__ A, const bf16* __restrict__ B,
                                              float* __restrict__ C, int K, int ldc) {
    __shared__ bf16 As[128 * 64];
    __shared__ bf16 Bs[128 * 64];
    const int tid = threadIdx.x;
    const int lane = tid & 63;
    const int w = tid >> 6;
    const int wm = w >> 1, wn = w & 1;
    const long rowA0 = (long)blockIdx.x * 128;
    const long rowB0 = (long)blockIdx.y * 128;
    const int srow = tid >> 3;          // 0..31
    const int scol = (tid & 7) * 8;     // k-offset
    f32x4 acc[4][4];
    const f32x4 vz = {0.f, 0.f, 0.f, 0.f};
#pragma unroll
    for (int i = 0; i < 4; ++i)
#pragma unroll
        for (int j = 0; j < 4; ++j) acc[i][j] = vz;

    const bf16* Ab = A + rowA0 * K;
    const bf16* Bb = B + rowB0 * K;
    for (int kt = 0; kt < K; kt += 64) {
#pragma unroll
        for (int j = 0; j < 4; ++j) {
            __builtin_amdgcn_global_load_lds(
                (const __attribute__((address_space(1))) void*)(Ab + (long)(j * 32 + srow) * K + kt + scol),
                (__attribute__((address_space(3))) void*)&As[(j * 32 + w * 8) * 64], 16, 0, 0);
        }
#pragma unroll
        for (int j = 0; j < 4; ++j) {
            __builtin_amdgcn_global_load_lds(
                (const __attribute__((address_space(1))) void*)(Bb + (long)(j * 32 + srow) * K + kt + scol),
                (__attribute__((address_space(3))) void*)&Bs[(j * 32 + w * 8) * 64], 16, 0, 0);
        }
        __syncthreads();
#pragma unroll
        for (int s = 0; s < 2; ++s) {
            bf16x8 af[4], bfr[4];
#pragma unroll
            for (int mi = 0; mi < 4; ++mi)
                af[mi] = *(const bf16x8*)&As[(wm * 64 + mi * 16 + (lane & 15)) * 64 + s * 32 + (lane >> 4) * 8];
#pragma unroll
            for (int ni = 0; ni < 4; ++ni)
                bfr[ni] = *(const bf16x8*)&Bs[(wn * 64 + ni * 16 + (lane & 15)) * 64 + s * 32 + (lane >> 4) * 8];
#pragma unroll
            for (int mi = 0; mi < 4; ++mi)
#pragma unroll
                for (int ni = 0; ni < 4; ++ni)
                    acc[mi][ni] = __builtin_amdgcn_mfma_f32_16x16x32_bf16(af[mi], bfr[ni], acc[mi][ni], 0, 0, 0);
        }
        __syncthreads();
    }
    const int crow = (lane >> 4) * 4;
    const int ccol = lane & 15;
#pragma unroll
    for (int mi = 0; mi < 4; ++mi)
#pragma unroll
        for (int ni = 0; ni < 4; ++ni) {
            long r0 = rowA0 + wm * 64 + mi * 16 + crow;
            long c0 = rowB0 + wn * 64 + ni * 16 + ccol;
#pragma unroll
            for (int j = 0; j < 4; ++j) C[(r0 + j) * ldc + c0] = acc[mi][ni][j];
        }
}

// ---------------- causal conv1d (k=4) + bias + silu ----------------
__global__ void k_conv(const float* __restrict__ zx, const float* __restrict__ cw,
                       const float* __restrict__ cb, float* __restrict__ co) {
    int idx = blockIdx.x * 256 + threadIdx.x;   // ROWS*CONVDIM
    int c = idx % CONVDIM; int blt = idx / CONVDIM;
    int t = blt % SEQ;
    long bbase = (long)(blt - t) * NPAD;        // (b*SEQ)*NPAD
    float acc = cb[c];
#pragma unroll
    for (int k = 0; k < 4; ++k) {
        int tt = t + k - 3;
        if (tt >= 0) acc += zx[bbase + (long)tt * NPAD + DINNER + c] * cw[c * 4 + k];
    }
    co[(long)blt * CONVDIM + c] = fsilu(acc);
}

// ---------------- dt = softplus(raw + bias) ----------------
__global__ void k_dt(const float* __restrict__ zx, const float* __restrict__ dtb,
                     float* __restrict__ dt) {
    int idx = blockIdx.x * 256 + threadIdx.x;   // ROWS*NHEADS
    int hh = idx % NHEADS; int bl = idx / NHEADS;
    float v = zx[(long)bl * NPAD + DINNER + CONVDIM + hh] + dtb[hh];
    dt[idx] = (v > 15.f) ? v : log1pf(__expf(v));
}

// ---------------- sequential SSM scan ----------------
// block = (b, head, p-half). 256 threads: tid = ptile*32 + ntile ; each thread 4p x 4n state.
__global__ __launch_bounds__(256) void k_scan(const float* __restrict__ co, const float* __restrict__ dt,
                                              const float* __restrict__ Alog, const float* __restrict__ Dp,
                                              float* __restrict__ ys) {
    int blk = blockIdx.x;             // 0..191
    int b = blk / 48;
    int r48 = blk % 48;
    int h = r48 >> 1;
    int ph = r48 & 1;
    int tid = threadIdx.x;
    int ptl = tid >> 5;               // 0..7
    int nt = tid & 31;                // 0..31
    int p0 = ph * 32 + ptl * 4;
    int n0 = nt * 4;
    float Ah = -__expf(Alog[h]);
    float Dh = Dp[h];
    float s[4][4] = {{0.f}};
    long cbase = (long)b * SEQ * CONVDIM;
    int dbase = b * SEQ * NHEADS + h;
    long ybase = (long)b * SEQ * DINNER + h * HEADDIM + p0;
    for (int t = 0; t < SEQ; ++t) {
        long rb = cbase + (long)t * CONVDIM;
        float4 Bv = *(const float4*)(co + rb + DINNER + n0);
        float4 Cv = *(const float4*)(co + rb + DINNER + DSTATE + n0);
        float4 Xv = *(const float4*)(co + rb + h * HEADDIM + p0);
        float dtv = dt[dbase + t * NHEADS];
        float dec = __expf(dtv * Ah);
        float Ba[4] = {Bv.x, Bv.y, Bv.z, Bv.w};
        float Ca[4] = {Cv.x, Cv.y, Cv.z, Cv.w};
        float Xa[4] = {Xv.x, Xv.y, Xv.z, Xv.w};
        float yv[4];
#pragma unroll
        for (int i = 0; i < 4; ++i) {
            float dx = dtv * Xa[i];
            float yy = 0.f;
#pragma unroll
            for (int j = 0; j < 4; ++j) {
                s[i][j] = s[i][j] * dec + dx * Ba[j];
                yy += s[i][j] * Ca[j];
            }
            yv[i] = yy;
        }
#pragma unroll
        for (int i = 0; i < 4; ++i) {
#pragma unroll
            for (int m = 16; m; m >>= 1) yv[i] += __shfl_xor(yv[i], m, 64);
        }
        if (nt == 0) {
            float4 o4;
            o4.x = yv[0] + Dh * Xa[0];
            o4.y = yv[1] + Dh * Xa[1];
            o4.z = yv[2] + Dh * Xa[2];
            o4.w = yv[3] + Dh * Xa[3];
            *(float4*)(ys + ybase + (long)t * DINNER) = o4;
        }
    }
}

// ---------------- gated rmsnorm: yf = rmsnorm(ys * silu(z)) * w -> bf16 ----------------
__global__ __launch_bounds__(256) void k_gated(const float* __restrict__ ys, const float* __restrict__ zx,
                                               const float* __restrict__ w, bf16* __restrict__ out) {
    __shared__ float sm[4];
    int r = blockIdx.x, tid = threadIdx.x;
    float v[6]; float ss = 0.f;
#pragma unroll
    for (int k = 0; k < 6; ++k) {
        int d = tid + k * 256;
        float z = zx[(long)r * NPAD + d];
        float t = ys[(long)r * DINNER + d] * fsilu(z);
        v[k] = t; ss += t * t;
    }
#pragma unroll
    for (int off = 32; off; off >>= 1) ss += __shfl_down(ss, off, 64);
    if ((tid & 63) == 0) sm[tid >> 6] = ss;
    __syncthreads();
    float tot = sm[0] + sm[1] + sm[2] + sm[3];
    float sc = rsqrtf(tot / (float)DINNER + EPS);
#pragma unroll
    for (int k = 0; k < 6; ++k) {
        int d = tid + k * 256;
        out[(long)r * DINNER + d] = (bf16)(v[k] * sc * w[d]);
    }
}

// ---------------- head: out = hn @ W_head^T ; loss += mean((out-y)^2) ----------------
__global__ __launch_bounds__(256) void k_head(const bf16* __restrict__ hn, const float* __restrict__ Wh,
                                              const float* __restrict__ y, float* __restrict__ out,
                                              float* __restrict__ loss) {
    __shared__ float sm[4 * 5];
    int r = blockIdx.x, tid = threadIdx.x;
    float acc[5] = {0.f, 0.f, 0.f, 0.f, 0.f};
#pragma unroll
    for (int k = 0; k < 3; ++k) {
        int d = tid + k * 256;
        float hv = (float)hn[r * DMODEL + d];
#pragma unroll
        for (int o = 0; o < 5; ++o) acc[o] += hv * Wh[o * DMODEL + d];
    }
#pragma unroll
    for (int o = 0; o < 5; ++o) {
#pragma unroll
        for (int off = 32; off; off >>= 1) acc[o] += __shfl_down(acc[o], off, 64);
    }
    if ((tid & 63) == 0) {
        int wid = tid >> 6;
#pragma unroll
        for (int o = 0; o < 5; ++o) sm[wid * 5 + o] = acc[o];
    }
    __syncthreads();
    if (tid == 0) {
        float ls = 0.f;
#pragma unroll
        for (int o = 0; o < 5; ++o) {
            float v = sm[o] + sm[5 + o] + sm[10 + o] + sm[15 + o];
            out[r * 5 + o] = v;
            float d = v - y[r * 5 + o];
            ls += d * d;
        }
        atomicAdd(loss, ls / (float)(ROWS * 5));
    }
}

extern "C" void kernel_launch(void* const* d_in, const int* in_sizes, int n_in,
                              void* d_out, int out_size, void* d_ws, size_t ws_size,
                              hipStream_t stream) {
    const float* x      = (const float*)d_in[0];
    const float* y      = (const float*)d_in[1];
    const float* W_emb  = (const float*)d_in[2];
    const float* b_emb  = (const float*)d_in[3];
    const float* W_in   = (const float*)d_in[4];
    const float* conv_w = (const float*)d_in[5];
    const float* conv_b = (const float*)d_in[6];
    const float* dt_bias= (const float*)d_in[7];
    const float* A_log  = (const float*)d_in[8];
    const float* Dp     = (const float*)d_in[9];
    const float* norm_w = (const float*)d_in[10];
    const float* W_out  = (const float*)d_in[11];
    const float* bnw    = (const float*)d_in[12];
    const float* nfw    = (const float*)d_in[13];
    const float* W_head = (const float*)d_in[14];

    char* ws = (char*)d_ws;
    float* hb  = (float*)ws;                 ws += (size_t)ROWS * DMODEL * 4;
    float* res = (float*)ws;                 ws += (size_t)ROWS * DMODEL * 4;
    bf16*  hnb = (bf16*)ws;                  ws += (size_t)ROWS * DMODEL * 2;
    float* zx  = (float*)ws;                 ws += (size_t)ROWS * NPAD * 4;
    float* co  = (float*)ws;                 ws += (size_t)ROWS * CONVDIM * 4;
    float* dtb = (float*)ws;                 ws += (size_t)ROWS * NHEADS * 4;
    float* ysb = (float*)ws;                 ws += (size_t)ROWS * DINNER * 4;
    bf16*  yfb = (bf16*)ws;                  ws += (size_t)ROWS * DINNER * 2;
    bf16*  Wib = (bf16*)ws;                  ws += (size_t)NPAD * DMODEL * 2;
    bf16*  Wob = (bf16*)ws;                  ws += (size_t)DMODEL * DINNER * 2;

    float* out_p  = (float*)d_out;
    float* loss_p = out_p + (size_t)ROWS * 5;

    hipMemsetAsync(loss_p, 0, 4, stream);
    k_embed<<<ROWS * DMODEL / 256, 256, 0, stream>>>(x, W_emb, b_emb, hb, res);

    for (int l = 0; l < NLAYER; ++l) {
        k_cvt<<<NPAD * DMODEL / 256, 256, 0, stream>>>(W_in + (size_t)l * DINPROJ * DMODEL, Wib, DINPROJ, DMODEL);
        k_add_rmsnorm<<<ROWS, 256, 0, stream>>>(hb, res, bnw + l * DMODEL, hnb);
        dim3 g1(ROWS / 128, NPAD / 128);
        k_gemm<<<g1, 256, 0, stream>>>(hnb, Wib, zx, DMODEL, NPAD);
        k_conv<<<ROWS * CONVDIM / 256, 256, 0, stream>>>(zx, conv_w + (size_t)l * CONVDIM * 4, conv_b + l * CONVDIM, co);
        k_dt<<<ROWS * NHEADS / 256, 256, 0, stream>>>(zx, dt_bias + l * NHEADS, dtb);
        k_scan<<<192, 256, 0, stream>>>(co, dtb, A_log + l * NHEADS, Dp + l * NHEADS, ysb);
        k_gated<<<ROWS, 256, 0, stream>>>(ysb, zx, norm_w + l * DINNER, yfb);
        k_cvt<<<DMODEL * DINNER / 256, 256, 0, stream>>>(W_out + (size_t)l * DMODEL * DINNER, Wob, DMODEL, DINNER);
        dim3 g2(ROWS / 128, DMODEL / 128);
        k_gemm<<<g2, 256, 0, stream>>>(yfb, Wob, hb, DINNER, DMODEL);
    }

    k_add_rmsnorm<<<ROWS, 256, 0, stream>>>(hb, res, nfw, hnb);
    k_head<<<ROWS, 256, 0, stream>>>(hnb, W_head, y, out_p, loss_p);
}

// Round 2
// 5558.624 us; speedup vs baseline: 2.0906x; 2.0906x over previous
//
#include <hip/hip_runtime.h>
#include <hip/hip_bf16.h>
#include <math.h>

#define BATCH 4
#define SEQ 2048
#define DMODEL 768
#define NLAYER 8
#define DINNER 1536
#define HEADDIM 64
#define NHEADS 24
#define DSTATE 128
#define CONVDIM 1792
#define DINPROJ 3352
#define NPAD 3456
#define ROWS (BATCH*SEQ)
#define EPS 1e-5f
#define QCH 128
#define NCH (SEQ/QCH)

typedef __bf16 bf16;
typedef bf16 bf16x8 __attribute__((ext_vector_type(8)));
typedef bf16 bf16x4 __attribute__((ext_vector_type(4)));
typedef float f32x4 __attribute__((ext_vector_type(4)));

__device__ __forceinline__ float fsilu(float x) { return x / (1.f + __expf(-x)); }

// ---------------- embed: h = x @ W_emb^T + b_emb ; res = 0 ----------------
__global__ void k_embed(const float* __restrict__ x, const float* __restrict__ We,
                        const float* __restrict__ be, float* __restrict__ h,
                        float* __restrict__ res) {
    int idx = blockIdx.x * 256 + threadIdx.x;   // ROWS*DMODEL
    int d = idx % DMODEL; int bl = idx / DMODEL;
    float acc = be[d];
#pragma unroll
    for (int i = 0; i < 6; ++i) acc += x[bl * 6 + i] * We[d * 6 + i];
    h[idx] = acc;
    res[idx] = 0.f;
}

// ---------------- fused residual add + rmsnorm -> bf16 ----------------
__global__ __launch_bounds__(256) void k_add_rmsnorm(const float* __restrict__ hin,
                                                     float* __restrict__ res,
                                                     const float* __restrict__ w,
                                                     bf16* __restrict__ out) {
    __shared__ float sm[4];
    int r = blockIdx.x, tid = threadIdx.x;
    float v[3]; float ss = 0.f;
#pragma unroll
    for (int k = 0; k < 3; ++k) {
        int d = tid + k * 256;
        float t = res[r * DMODEL + d] + hin[r * DMODEL + d];
        res[r * DMODEL + d] = t; v[k] = t; ss += t * t;
    }
#pragma unroll
    for (int off = 32; off; off >>= 1) ss += __shfl_down(ss, off, 64);
    if ((tid & 63) == 0) sm[tid >> 6] = ss;
    __syncthreads();
    float tot = sm[0] + sm[1] + sm[2] + sm[3];
    float sc = rsqrtf(tot / (float)DMODEL + EPS);
#pragma unroll
    for (int k = 0; k < 3; ++k) {
        int d = tid + k * 256;
        out[r * DMODEL + d] = (bf16)(v[k] * sc * w[d]);
    }
}

// ---------------- weight f32 -> bf16 (with optional row pad) ----------------
__global__ void k_cvt(const float* __restrict__ src, bf16* __restrict__ dst, int nsrc, int K) {
    long idx = (long)blockIdx.x * 256 + threadIdx.x;
    int n = (int)(idx / K);
    dst[idx] = (n < nsrc) ? (bf16)src[idx] : (bf16)0.f;
}

// ---------------- bf16 MFMA GEMM: C[M,N] = A[M,K] @ B[N,K]^T ----------------
__global__ __launch_bounds__(256) void k_gemm(const bf16* __restrict__ A, const bf16* __restrict__ B,
                                              float* __restrict__ C, int K, int ldc) {
    __shared__ bf16 As[128 * 64];
    __shared__ bf16 Bs[128 * 64];
    const int tid = threadIdx.x;
    const int lane = tid & 63;
    const int w = tid >> 6;
    const int wm = w >> 1, wn = w & 1;
    const long rowA0 = (long)blockIdx.x * 128;
    const long rowB0 = (long)blockIdx.y * 128;
    const int srow = tid >> 3;          // 0..31
    const int scol = (tid & 7) * 8;     // k-offset
    f32x4 acc[4][4];
    const f32x4 vz = {0.f, 0.f, 0.f, 0.f};
#pragma unroll
    for (int i = 0; i < 4; ++i)
#pragma unroll
        for (int j = 0; j < 4; ++j) acc[i][j] = vz;

    const bf16* Ab = A + rowA0 * K;
    const bf16* Bb = B + rowB0 * K;
    for (int kt = 0; kt < K; kt += 64) {
#pragma unroll
        for (int j = 0; j < 4; ++j) {
            __builtin_amdgcn_global_load_lds(
                (const __attribute__((address_space(1))) void*)(Ab + (long)(j * 32 + srow) * K + kt + scol),
                (__attribute__((address_space(3))) void*)&As[(j * 32 + w * 8) * 64], 16, 0, 0);
        }
#pragma unroll
        for (int j = 0; j < 4; ++j) {
            __builtin_amdgcn_global_load_lds(
                (const __attribute__((address_space(1))) void*)(Bb + (long)(j * 32 + srow) * K + kt + scol),
                (__attribute__((address_space(3))) void*)&Bs[(j * 32 + w * 8) * 64], 16, 0, 0);
        }
        __syncthreads();
#pragma unroll
        for (int s = 0; s < 2; ++s) {
            bf16x8 af[4], bfr[4];
#pragma unroll
            for (int mi = 0; mi < 4; ++mi)
                af[mi] = *(const bf16x8*)&As[(wm * 64 + mi * 16 + (lane & 15)) * 64 + s * 32 + (lane >> 4) * 8];
#pragma unroll
            for (int ni = 0; ni < 4; ++ni)
                bfr[ni] = *(const bf16x8*)&Bs[(wn * 64 + ni * 16 + (lane & 15)) * 64 + s * 32 + (lane >> 4) * 8];
#pragma unroll
            for (int mi = 0; mi < 4; ++mi)
#pragma unroll
                for (int ni = 0; ni < 4; ++ni)
                    acc[mi][ni] = __builtin_amdgcn_mfma_f32_16x16x32_bf16(af[mi], bfr[ni], acc[mi][ni], 0, 0, 0);
        }
        __syncthreads();
    }
    const int crow = (lane >> 4) * 4;
    const int ccol = lane & 15;
#pragma unroll
    for (int mi = 0; mi < 4; ++mi)
#pragma unroll
        for (int ni = 0; ni < 4; ++ni) {
            long r0 = rowA0 + wm * 64 + mi * 16 + crow;
            long c0 = rowB0 + wn * 64 + ni * 16 + ccol;
#pragma unroll
            for (int j = 0; j < 4; ++j) C[(r0 + j) * ldc + c0] = acc[mi][ni][j];
        }
}

// ---------------- causal conv1d (k=4) + bias + silu ----------------
__global__ void k_conv(const float* __restrict__ zx, const float* __restrict__ cw,
                       const float* __restrict__ cb, float* __restrict__ co) {
    int idx = blockIdx.x * 256 + threadIdx.x;   // ROWS*CONVDIM
    int c = idx % CONVDIM; int blt = idx / CONVDIM;
    int t = blt % SEQ;
    long bbase = (long)(blt - t) * NPAD;
    float acc = cb[c];
#pragma unroll
    for (int k = 0; k < 4; ++k) {
        int tt = t + k - 3;
        if (tt >= 0) acc += zx[bbase + (long)tt * NPAD + DINNER + c] * cw[c * 4 + k];
    }
    co[(long)blt * CONVDIM + c] = fsilu(acc);
}

// ---------------- dt = softplus(raw + bias) ----------------
__global__ void k_dt(const float* __restrict__ zx, const float* __restrict__ dtb,
                     float* __restrict__ dt) {
    int idx = blockIdx.x * 256 + threadIdx.x;   // ROWS*NHEADS
    int hh = idx % NHEADS; int bl = idx / NHEADS;
    float v = zx[(long)bl * NPAD + DINNER + CONVDIM + hh] + dtb[hh];
    dt[idx] = (v > 15.f) ? v : log1pf(__expf(v));
}

// ---------------- Pass A: chunk-local scan (zero init), store final local state (bf16) + chunk decay ----------------
// grid 3072: (b, h, chunk, p-half). 256 threads: ptl=tid>>5 (0..7), nt=tid&31; thread owns 4p x 4n.
__global__ __launch_bounds__(256) void k_scanA(const float* __restrict__ co, const float* __restrict__ dt,
                                               const float* __restrict__ Alog,
                                               bf16* __restrict__ Lbuf, float* __restrict__ Pc) {
    int blk = blockIdx.x;
    int b = blk / 768; int r = blk % 768;
    int h = r >> 5; int r2 = r & 31;
    int c = r2 >> 1; int ph = r2 & 1;
    int tid = threadIdx.x;
    int ptl = tid >> 5, nt = tid & 31;
    int p0 = ph * 32 + ptl * 4, n0 = nt * 4;
    float Ah = -__expf(Alog[h]);
    float s[4][4] = {{0.f}};
    int t0 = c * QCH;
    long cbase = ((long)b * SEQ + t0) * CONVDIM;
    const float* dptr = dt + (b * SEQ + t0) * NHEADS + h;
    float sumdt = 0.f;
    float4 Bv = *(const float4*)(co + cbase + DINNER + n0);
    float4 Xv = *(const float4*)(co + cbase + h * HEADDIM + p0);
    float dtv = dptr[0];
    for (int t = 0; t < QCH; ++t) {
        int tn = (t + 1 < QCH) ? t + 1 : t;
        long rb = cbase + (long)tn * CONVDIM;
        float4 Bn = *(const float4*)(co + rb + DINNER + n0);
        float4 Xn = *(const float4*)(co + rb + h * HEADDIM + p0);
        float dtn = dptr[tn * NHEADS];
        float dec = __expf(dtv * Ah);
        sumdt += dtv;
        float Ba[4] = {Bv.x, Bv.y, Bv.z, Bv.w};
        float Xa[4] = {Xv.x, Xv.y, Xv.z, Xv.w};
#pragma unroll
        for (int i = 0; i < 4; ++i) {
            float dx = dtv * Xa[i];
#pragma unroll
            for (int j = 0; j < 4; ++j) s[i][j] = s[i][j] * dec + dx * Ba[j];
        }
        Bv = Bn; Xv = Xn; dtv = dtn;
    }
    bf16* Lp = Lbuf + ((long)((b * NHEADS + h) * NCH + c) << 13);
#pragma unroll
    for (int i = 0; i < 4; ++i) {
        bf16x4 v = {(bf16)s[i][0], (bf16)s[i][1], (bf16)s[i][2], (bf16)s[i][3]};
        *(bf16x4*)(Lp + (p0 + i) * DSTATE + n0) = v;
    }
    if (tid == 0) Pc[(b * NHEADS + h) * NCH + c] = __expf(Ah * sumdt);
}

// ---------------- Pass B: sequential inter-chunk combine; Lbuf (local-final) -> Ibuf (chunk-init), in place ----------------
// grid 384: bh = blk>>2, quarter = blk&3; each thread handles one bf16x8 across all 16 chunks.
__global__ __launch_bounds__(256) void k_scanB(bf16* __restrict__ Lbuf, const float* __restrict__ Pc) {
    int bh = blockIdx.x >> 2;
    int q = blockIdx.x & 3;
    int off = (q * 256 + threadIdx.x) * 8;
    long base = ((long)bh * NCH) << 13;
    float s[8] = {0.f};
#pragma unroll
    for (int c = 0; c < NCH; ++c) {
        bf16* p = Lbuf + base + ((long)c << 13) + off;
        bf16x8 L = *(bf16x8*)p;
        bf16x8 I;
#pragma unroll
        for (int k = 0; k < 8; ++k) I[k] = (bf16)s[k];
        float P = Pc[bh * NCH + c];
#pragma unroll
        for (int k = 0; k < 8; ++k) s[k] = P * s[k] + (float)L[k];
        *(bf16x8*)p = I;
    }
}

// ---------------- Pass C: re-scan chunk from true init state, emit y ----------------
__global__ __launch_bounds__(256) void k_scanC(const float* __restrict__ co, const float* __restrict__ dt,
                                               const float* __restrict__ Alog, const float* __restrict__ Dp,
                                               const bf16* __restrict__ Ibuf, float* __restrict__ ys) {
    int blk = blockIdx.x;
    int b = blk / 768; int r = blk % 768;
    int h = r >> 5; int r2 = r & 31;
    int c = r2 >> 1; int ph = r2 & 1;
    int tid = threadIdx.x;
    int ptl = tid >> 5, nt = tid & 31;
    int p0 = ph * 32 + ptl * 4, n0 = nt * 4;
    float Ah = -__expf(Alog[h]);
    float Dh = Dp[h];
    const bf16* Ip = Ibuf + ((long)((b * NHEADS + h) * NCH + c) << 13);
    float s[4][4];
#pragma unroll
    for (int i = 0; i < 4; ++i) {
        bf16x4 I4 = *(const bf16x4*)(Ip + (p0 + i) * DSTATE + n0);
#pragma unroll
        for (int j = 0; j < 4; ++j) s[i][j] = (float)I4[j];
    }
    int t0 = c * QCH;
    long cbase = ((long)b * SEQ + t0) * CONVDIM;
    const float* dptr = dt + (b * SEQ + t0) * NHEADS + h;
    long ybase = ((long)b * SEQ + t0) * DINNER + h * HEADDIM + p0;
    float4 Bv = *(const float4*)(co + cbase + DINNER + n0);
    float4 Cv = *(const float4*)(co + cbase + DINNER + DSTATE + n0);
    float4 Xv = *(const float4*)(co + cbase + h * HEADDIM + p0);
    float dtv = dptr[0];
    for (int t = 0; t < QCH; ++t) {
        int tn = (t + 1 < QCH) ? t + 1 : t;
        long rb = cbase + (long)tn * CONVDIM;
        float4 Bn = *(const float4*)(co + rb + DINNER + n0);
        float4 Cn = *(const float4*)(co + rb + DINNER + DSTATE + n0);
        float4 Xn = *(const float4*)(co + rb + h * HEADDIM + p0);
        float dtn = dptr[tn * NHEADS];
        float dec = __expf(dtv * Ah);
        float Ba[4] = {Bv.x, Bv.y, Bv.z, Bv.w};
        float Ca[4] = {Cv.x, Cv.y, Cv.z, Cv.w};
        float Xa[4] = {Xv.x, Xv.y, Xv.z, Xv.w};
        float yv[4];
#pragma unroll
        for (int i = 0; i < 4; ++i) {
            float dx = dtv * Xa[i];
            float yy = 0.f;
#pragma unroll
            for (int j = 0; j < 4; ++j) {
                s[i][j] = s[i][j] * dec + dx * Ba[j];
                yy += s[i][j] * Ca[j];
            }
            yv[i] = yy;
        }
#pragma unroll
        for (int i = 0; i < 4; ++i) {
#pragma unroll
            for (int m = 16; m; m >>= 1) yv[i] += __shfl_xor(yv[i], m, 64);
        }
        if (nt == 0) {
            float4 o4;
            o4.x = yv[0] + Dh * Xa[0];
            o4.y = yv[1] + Dh * Xa[1];
            o4.z = yv[2] + Dh * Xa[2];
            o4.w = yv[3] + Dh * Xa[3];
            *(float4*)(ys + ybase + (long)t * DINNER) = o4;
        }
        Bv = Bn; Cv = Cn; Xv = Xn; dtv = dtn;
    }
}

// ---------------- gated rmsnorm: yf = rmsnorm(ys * silu(z)) * w -> bf16 ----------------
__global__ __launch_bounds__(256) void k_gated(const float* __restrict__ ys, const float* __restrict__ zx,
                                               const float* __restrict__ w, bf16* __restrict__ out) {
    __shared__ float sm[4];
    int r = blockIdx.x, tid = threadIdx.x;
    float v[6]; float ss = 0.f;
#pragma unroll
    for (int k = 0; k < 6; ++k) {
        int d = tid + k * 256;
        float z = zx[(long)r * NPAD + d];
        float t = ys[(long)r * DINNER + d] * fsilu(z);
        v[k] = t; ss += t * t;
    }
#pragma unroll
    for (int off = 32; off; off >>= 1) ss += __shfl_down(ss, off, 64);
    if ((tid & 63) == 0) sm[tid >> 6] = ss;
    __syncthreads();
    float tot = sm[0] + sm[1] + sm[2] + sm[3];
    float sc = rsqrtf(tot / (float)DINNER + EPS);
#pragma unroll
    for (int k = 0; k < 6; ++k) {
        int d = tid + k * 256;
        out[(long)r * DINNER + d] = (bf16)(v[k] * sc * w[d]);
    }
}

// ---------------- head: out = hn @ W_head^T ; loss += mean((out-y)^2) ----------------
__global__ __launch_bounds__(256) void k_head(const bf16* __restrict__ hn, const float* __restrict__ Wh,
                                              const float* __restrict__ y, float* __restrict__ out,
                                              float* __restrict__ loss) {
    __shared__ float sm[4 * 5];
    int r = blockIdx.x, tid = threadIdx.x;
    float acc[5] = {0.f, 0.f, 0.f, 0.f, 0.f};
#pragma unroll
    for (int k = 0; k < 3; ++k) {
        int d = tid + k * 256;
        float hv = (float)hn[r * DMODEL + d];
#pragma unroll
        for (int o = 0; o < 5; ++o) acc[o] += hv * Wh[o * DMODEL + d];
    }
#pragma unroll
    for (int o = 0; o < 5; ++o) {
#pragma unroll
        for (int off = 32; off; off >>= 1) acc[o] += __shfl_down(acc[o], off, 64);
    }
    if ((tid & 63) == 0) {
        int wid = tid >> 6;
#pragma unroll
        for (int o = 0; o < 5; ++o) sm[wid * 5 + o] = acc[o];
    }
    __syncthreads();
    if (tid == 0) {
        float ls = 0.f;
#pragma unroll
        for (int o = 0; o < 5; ++o) {
            float v = sm[o] + sm[5 + o] + sm[10 + o] + sm[15 + o];
            out[r * 5 + o] = v;
            float d = v - y[r * 5 + o];
            ls += d * d;
        }
        atomicAdd(loss, ls / (float)(ROWS * 5));
    }
}

extern "C" void kernel_launch(void* const* d_in, const int* in_sizes, int n_in,
                              void* d_out, int out_size, void* d_ws, size_t ws_size,
                              hipStream_t stream) {
    const float* x      = (const float*)d_in[0];
    const float* y      = (const float*)d_in[1];
    const float* W_emb  = (const float*)d_in[2];
    const float* b_emb  = (const float*)d_in[3];
    const float* W_in   = (const float*)d_in[4];
    const float* conv_w = (const float*)d_in[5];
    const float* conv_b = (const float*)d_in[6];
    const float* dt_bias= (const float*)d_in[7];
    const float* A_log  = (const float*)d_in[8];
    const float* Dp     = (const float*)d_in[9];
    const float* norm_w = (const float*)d_in[10];
    const float* W_out  = (const float*)d_in[11];
    const float* bnw    = (const float*)d_in[12];
    const float* nfw    = (const float*)d_in[13];
    const float* W_head = (const float*)d_in[14];

    char* ws = (char*)d_ws;
    float* hb  = (float*)ws;                 ws += (size_t)ROWS * DMODEL * 4;
    float* res = (float*)ws;                 ws += (size_t)ROWS * DMODEL * 4;
    bf16*  hnb = (bf16*)ws;                  ws += (size_t)ROWS * DMODEL * 2;
    float* zx  = (float*)ws;                 ws += (size_t)ROWS * NPAD * 4;
    float* co  = (float*)ws;                 ws += (size_t)ROWS * CONVDIM * 4;
    float* dtb = (float*)ws;                 ws += (size_t)ROWS * NHEADS * 4;
    float* ysb = (float*)ws;                 ws += (size_t)ROWS * DINNER * 4;
    bf16*  yfb = (bf16*)ws;                  ws += (size_t)ROWS * DINNER * 2;
    bf16*  Wib = (bf16*)ws;                  ws += (size_t)NPAD * DMODEL * 2;
    bf16*  Wob = (bf16*)ws;                  ws += (size_t)DMODEL * DINNER * 2;
    float* Pcb = (float*)ws;                 ws += (size_t)BATCH * NHEADS * NCH * 4;

    // Lbuf (chunk states, bf16, 4*24*16*64*128*2 = 25,165,824 B) aliases hb exactly:
    // hb is dead from k_add_rmsnorm (reads it) until k_gemm (out-proj) rewrites it.
    bf16* Lbuf = (bf16*)hb;

    float* out_p  = (float*)d_out;
    float* loss_p = out_p + (size_t)ROWS * 5;

    hipMemsetAsync(loss_p, 0, 4, stream);
    k_embed<<<ROWS * DMODEL / 256, 256, 0, stream>>>(x, W_emb, b_emb, hb, res);

    for (int l = 0; l < NLAYER; ++l) {
        k_cvt<<<NPAD * DMODEL / 256, 256, 0, stream>>>(W_in + (size_t)l * DINPROJ * DMODEL, Wib, DINPROJ, DMODEL);
        k_add_rmsnorm<<<ROWS, 256, 0, stream>>>(hb, res, bnw + l * DMODEL, hnb);
        dim3 g1(ROWS / 128, NPAD / 128);
        k_gemm<<<g1, 256, 0, stream>>>(hnb, Wib, zx, DMODEL, NPAD);
        k_conv<<<ROWS * CONVDIM / 256, 256, 0, stream>>>(zx, conv_w + (size_t)l * CONVDIM * 4, conv_b + l * CONVDIM, co);
        k_dt<<<ROWS * NHEADS / 256, 256, 0, stream>>>(zx, dt_bias + l * NHEADS, dtb);
        k_scanA<<<BATCH * NHEADS * NCH * 2, 256, 0, stream>>>(co, dtb, A_log + l * NHEADS, Lbuf, Pcb);
        k_scanB<<<BATCH * NHEADS * 4, 256, 0, stream>>>(Lbuf, Pcb);
        k_scanC<<<BATCH * NHEADS * NCH * 2, 256, 0, stream>>>(co, dtb, A_log + l * NHEADS, Dp + l * NHEADS, Lbuf, ysb);
        k_gated<<<ROWS, 256, 0, stream>>>(ysb, zx, norm_w + l * DINNER, yfb);
        k_cvt<<<DMODEL * DINNER / 256, 256, 0, stream>>>(W_out + (size_t)l * DMODEL * DINNER, Wob, DMODEL, DINNER);
        dim3 g2(ROWS / 128, DMODEL / 128);
        k_gemm<<<g2, 256, 0, stream>>>(yfb, Wob, hb, DINNER, DMODEL);
    }

    k_add_rmsnorm<<<ROWS, 256, 0, stream>>>(hb, res, nfw, hnb);
    k_head<<<ROWS, 256, 0, stream>>>(hnb, W_head, y, out_p, loss_p);
}

// Round 3
// 2799.198 us; speedup vs baseline: 4.1514x; 1.9858x over previous
//
#include <hip/hip_runtime.h>
#include <hip/hip_bf16.h>
#include <math.h>

#define BATCH 4
#define SEQ 2048
#define DMODEL 768
#define NLAYER 8
#define DINNER 1536
#define HEADDIM 64
#define NHEADS 24
#define DSTATE 128
#define CONVDIM 1792
#define DINPROJ 3352
#define NPAD 3456
#define ROWS (BATCH*SEQ)
#define EPS 1e-5f
#define QCH 128
#define NCH (SEQ/QCH)

typedef __bf16 bf16;
typedef bf16 bf16x8 __attribute__((ext_vector_type(8)));
typedef bf16 bf16x4 __attribute__((ext_vector_type(4)));
typedef float f32x4 __attribute__((ext_vector_type(4)));

#define GLD(src, dst) __builtin_amdgcn_global_load_lds( \
    (const __attribute__((address_space(1))) void*)(src), \
    (__attribute__((address_space(3))) void*)(dst), 16, 0, 0)

__device__ __forceinline__ float fsilu(float x) { return x / (1.f + __expf(-x)); }

// ---------------- embed ----------------
__global__ void k_embed(const float* __restrict__ x, const float* __restrict__ We,
                        const float* __restrict__ be, float* __restrict__ h,
                        float* __restrict__ res) {
    int idx = blockIdx.x * 256 + threadIdx.x;
    int d = idx % DMODEL; int bl = idx / DMODEL;
    float acc = be[d];
#pragma unroll
    for (int i = 0; i < 6; ++i) acc += x[bl * 6 + i] * We[d * 6 + i];
    h[idx] = acc;
    res[idx] = 0.f;
}

// ---------------- fused residual add + rmsnorm -> bf16 ----------------
__global__ __launch_bounds__(256) void k_add_rmsnorm(const float* __restrict__ hin,
                                                     float* __restrict__ res,
                                                     const float* __restrict__ w,
                                                     bf16* __restrict__ out) {
    __shared__ float sm[4];
    int r = blockIdx.x, tid = threadIdx.x;
    float v[3]; float ss = 0.f;
#pragma unroll
    for (int k = 0; k < 3; ++k) {
        int d = tid + k * 256;
        float t = res[r * DMODEL + d] + hin[r * DMODEL + d];
        res[r * DMODEL + d] = t; v[k] = t; ss += t * t;
    }
#pragma unroll
    for (int off = 32; off; off >>= 1) ss += __shfl_down(ss, off, 64);
    if ((tid & 63) == 0) sm[tid >> 6] = ss;
    __syncthreads();
    float tot = sm[0] + sm[1] + sm[2] + sm[3];
    float sc = rsqrtf(tot / (float)DMODEL + EPS);
#pragma unroll
    for (int k = 0; k < 3; ++k) {
        int d = tid + k * 256;
        out[r * DMODEL + d] = (bf16)(v[k] * sc * w[d]);
    }
}

// ---------------- weight f32 -> bf16 ----------------
__global__ void k_cvt(const float* __restrict__ src, bf16* __restrict__ dst, int nsrc, int K) {
    long idx = (long)blockIdx.x * 256 + threadIdx.x;
    int n = (int)(idx / K);
    dst[idx] = (n < nsrc) ? (bf16)src[idx] : (bf16)0.f;
}

// ---------------- bf16 MFMA GEMM: C[M,N] = A[M,K] @ B[N,K]^T ----------------
__global__ __launch_bounds__(256) void k_gemm(const bf16* __restrict__ A, const bf16* __restrict__ B,
                                              float* __restrict__ C, int K, int ldc) {
    __shared__ bf16 As[128 * 64];
    __shared__ bf16 Bs[128 * 64];
    const int tid = threadIdx.x;
    const int lane = tid & 63;
    const int w = tid >> 6;
    const int wm = w >> 1, wn = w & 1;
    const long rowA0 = (long)blockIdx.x * 128;
    const long rowB0 = (long)blockIdx.y * 128;
    const int srow = tid >> 3;
    const int scol = (tid & 7) * 8;
    f32x4 acc[4][4];
    const f32x4 vz = {0.f, 0.f, 0.f, 0.f};
#pragma unroll
    for (int i = 0; i < 4; ++i)
#pragma unroll
        for (int j = 0; j < 4; ++j) acc[i][j] = vz;

    const bf16* Ab = A + rowA0 * K;
    const bf16* Bb = B + rowB0 * K;
    for (int kt = 0; kt < K; kt += 64) {
#pragma unroll
        for (int j = 0; j < 4; ++j)
            GLD(Ab + (long)(j * 32 + srow) * K + kt + scol, &As[(j * 32 + w * 8) * 64]);
#pragma unroll
        for (int j = 0; j < 4; ++j)
            GLD(Bb + (long)(j * 32 + srow) * K + kt + scol, &Bs[(j * 32 + w * 8) * 64]);
        __syncthreads();
#pragma unroll
        for (int s = 0; s < 2; ++s) {
            bf16x8 af[4], bfr[4];
#pragma unroll
            for (int mi = 0; mi < 4; ++mi)
                af[mi] = *(const bf16x8*)&As[(wm * 64 + mi * 16 + (lane & 15)) * 64 + s * 32 + (lane >> 4) * 8];
#pragma unroll
            for (int ni = 0; ni < 4; ++ni)
                bfr[ni] = *(const bf16x8*)&Bs[(wn * 64 + ni * 16 + (lane & 15)) * 64 + s * 32 + (lane >> 4) * 8];
#pragma unroll
            for (int mi = 0; mi < 4; ++mi)
#pragma unroll
                for (int ni = 0; ni < 4; ++ni)
                    acc[mi][ni] = __builtin_amdgcn_mfma_f32_16x16x32_bf16(af[mi], bfr[ni], acc[mi][ni], 0, 0, 0);
        }
        __syncthreads();
    }
    const int crow = (lane >> 4) * 4;
    const int ccol = lane & 15;
#pragma unroll
    for (int mi = 0; mi < 4; ++mi)
#pragma unroll
        for (int ni = 0; ni < 4; ++ni) {
            long r0 = rowA0 + wm * 64 + mi * 16 + crow;
            long c0 = rowB0 + wn * 64 + ni * 16 + ccol;
#pragma unroll
            for (int j = 0; j < 4; ++j) C[(r0 + j) * ldc + c0] = acc[mi][ni][j];
        }
}

// ---------------- causal conv1d (k=4) + bias + silu -> bf16 ----------------
__global__ void k_conv(const float* __restrict__ zx, const float* __restrict__ cw,
                       const float* __restrict__ cb, bf16* __restrict__ co) {
    int idx = blockIdx.x * 256 + threadIdx.x;
    int c = idx % CONVDIM; int blt = idx / CONVDIM;
    int t = blt % SEQ;
    long bbase = (long)(blt - t) * NPAD;
    float acc = cb[c];
#pragma unroll
    for (int k = 0; k < 4; ++k) {
        int tt = t + k - 3;
        if (tt >= 0) acc += zx[bbase + (long)tt * NPAD + DINNER + c] * cw[c * 4 + k];
    }
    co[(long)blt * CONVDIM + c] = (bf16)fsilu(acc);
}

// ---------------- dt = softplus(raw + bias) ----------------
__global__ void k_dt(const float* __restrict__ zx, const float* __restrict__ dtb,
                     float* __restrict__ dt) {
    int idx = blockIdx.x * 256 + threadIdx.x;
    int hh = idx % NHEADS; int bl = idx / NHEADS;
    float v = zx[(long)bl * NPAD + DINNER + CONVDIM + hh] + dtb[hh];
    dt[idx] = (v > 15.f) ? v : log1pf(__expf(v));
}

// ---------------- per-chunk prep: cumsum S, Pc, chunk-contig dt/S, swizzled XT/XwT/BT ----------------
// grid 1536 = (b,h,c); 128 threads (thread = t within chunk)
__global__ __launch_bounds__(128) void k_prep(const bf16* __restrict__ cobf, const float* __restrict__ dtb,
                                              const float* __restrict__ Alog,
                                              float* __restrict__ Sarr, float* __restrict__ dtc,
                                              float* __restrict__ Pcb,
                                              bf16* __restrict__ XT, bf16* __restrict__ XwT,
                                              bf16* __restrict__ BT) {
    int blk = blockIdx.x;
    int b = blk / (NHEADS * NCH);
    int r = blk % (NHEADS * NCH);
    int h = r / NCH;
    int c = r % NCH;
    int tid = threadIdx.x;
    __shared__ float S_lds[128], dt_lds[128], wl_lds[128], wtot[2];
    __shared__ bf16 Xs[128][64];
    long grow = (long)(b * SEQ + c * QCH + tid);
    float dtv = dtb[grow * NHEADS + h];
    float Ah = -__expf(Alog[h]);
    float ps = dtv * Ah;
#pragma unroll
    for (int off = 1; off < 64; off <<= 1) {
        float o = __shfl_up(ps, off, 64);
        if ((tid & 63) >= off) ps += o;
    }
    if ((tid & 63) == 63) wtot[tid >> 6] = ps;
    __syncthreads();
    if (tid >= 64) ps += wtot[0];
    S_lds[tid] = ps; dt_lds[tid] = dtv;
    __syncthreads();
    float Sl = S_lds[127];
    wl_lds[tid] = __expf(Sl - ps) * dtv;
    Sarr[blk * QCH + tid] = ps;
    dtc[blk * QCH + tid] = dtv;
    if (tid == 127) Pcb[blk] = __expf(Sl);
    const bf16* xrow = cobf + grow * CONVDIM + h * HEADDIM;
#pragma unroll
    for (int j = 0; j < 8; ++j) *(bf16x8*)&Xs[tid][j * 8] = *(const bf16x8*)(xrow + j * 8);
    __syncthreads();
    int p = tid >> 1, hf = tid & 1;
    char* xtb = (char*)XT + (((long)blk) << 14);
    char* xwb = (char*)XwT + (((long)blk) << 14);
#pragma unroll
    for (int ub = 0; ub < 8; ++ub) {
        int u0 = hf * 64 + ub * 8;
        bf16x8 vx, vw;
#pragma unroll
        for (int k = 0; k < 8; ++k) {
            int u = u0 + k;
            bf16 xv = Xs[u][p];
            vx[k] = xv;
            vw[k] = (bf16)((float)xv * wl_lds[u]);
        }
        long off = (long)((p * 256 + u0 * 2) ^ ((p & 7) << 4));
        *(bf16x8*)(xtb + off) = vx;
        *(bf16x8*)(xwb + off) = vw;
    }
    if (h == 0) {
        char* btb = (char*)BT + (((long)(b * NCH + c)) << 15);
        const bf16* brow = cobf + (long)(b * SEQ + c * QCH + tid) * CONVDIM + DINNER;
        int nl = tid >> 1;
        for (int nb = 0; nb < 2; ++nb) {
            __syncthreads();
#pragma unroll
            for (int j = 0; j < 8; ++j) *(bf16x8*)&Xs[tid][j * 8] = *(const bf16x8*)(brow + nb * 64 + j * 8);
            __syncthreads();
            int n = nb * 64 + nl;
#pragma unroll
            for (int ub = 0; ub < 8; ++ub) {
                int u0 = hf * 64 + ub * 8;
                bf16x8 v;
#pragma unroll
                for (int k = 0; k < 8; ++k) v[k] = Xs[u0 + k][nl];
                long off = (long)((n * 256 + u0 * 2) ^ ((n & 7) << 4));
                *(bf16x8*)(btb + off) = v;
            }
        }
    }
}

// ---------------- chunk-local final state via MFMA: L[64,128] = XwT @ BT^T ----------------
// grid 1536 = (b,h,c); 256 threads (4 waves, each 64x32 of output)
__global__ __launch_bounds__(256) void k_stateL(const bf16* __restrict__ XwT, const bf16* __restrict__ BT,
                                                bf16* __restrict__ Lbuf) {
    __shared__ bf16 Xs[64 * 128];
    __shared__ bf16 Bs[128 * 128];
    int blk = blockIdx.x;
    int b = blk / (NHEADS * NCH);
    int r = blk % (NHEADS * NCH);
    int c = r % NCH;
    int bc = b * NCH + c;
    int tid = threadIdx.x, lane = tid & 63, wid = tid >> 6;
    const char* xw = (const char*)XwT + (((long)blk) << 14);
    const char* bt = (const char*)BT + (((long)bc) << 15);
#pragma unroll
    for (int i = 0; i < 4; ++i)
        GLD(xw + (long)(i * 256 + tid) * 16, (char*)Xs + (i * 256 + wid * 64) * 16);
#pragma unroll
    for (int i = 0; i < 8; ++i)
        GLD(bt + (long)(i * 256 + tid) * 16, (char*)Bs + (i * 256 + wid * 64) * 16);
    __syncthreads();
    f32x4 acc[4][2];
    const f32x4 vz = {0.f, 0.f, 0.f, 0.f};
#pragma unroll
    for (int mi = 0; mi < 4; ++mi)
#pragma unroll
        for (int ni = 0; ni < 2; ++ni) acc[mi][ni] = vz;
    const char* XsB = (const char*)Xs;
    const char* BsB = (const char*)Bs;
#pragma unroll
    for (int ks = 0; ks < 4; ++ks) {
        bf16x8 af[4], bfr[2];
#pragma unroll
        for (int mi = 0; mi < 4; ++mi) {
            int pp = mi * 16 + (lane & 15);
            af[mi] = *(const bf16x8*)(XsB + ((pp * 256 + ks * 64 + (lane >> 4) * 16) ^ ((pp & 7) << 4)));
        }
#pragma unroll
        for (int ni = 0; ni < 2; ++ni) {
            int n = wid * 32 + ni * 16 + (lane & 15);
            bfr[ni] = *(const bf16x8*)(BsB + ((n * 256 + ks * 64 + (lane >> 4) * 16) ^ ((n & 7) << 4)));
        }
#pragma unroll
        for (int mi = 0; mi < 4; ++mi)
#pragma unroll
            for (int ni = 0; ni < 2; ++ni)
                acc[mi][ni] = __builtin_amdgcn_mfma_f32_16x16x32_bf16(af[mi], bfr[ni], acc[mi][ni], 0, 0, 0);
    }
    char* lb = (char*)Lbuf + (((long)blk) << 14);
#pragma unroll
    for (int mi = 0; mi < 4; ++mi)
#pragma unroll
        for (int ni = 0; ni < 2; ++ni)
#pragma unroll
            for (int j = 0; j < 4; ++j) {
                int pp = mi * 16 + (lane >> 4) * 4 + j;
                int n = wid * 32 + ni * 16 + (lane & 15);
                *(bf16*)(lb + ((pp * 256 + n * 2) ^ ((pp & 7) << 4))) = (bf16)acc[mi][ni][j];
            }
}

// ---------------- Pass B: sequential inter-chunk combine (unchanged semantics) ----------------
__global__ __launch_bounds__(256) void k_scanB(bf16* __restrict__ Lbuf, const float* __restrict__ Pc) {
    int bh = blockIdx.x >> 2;
    int q = blockIdx.x & 3;
    int off = (q * 256 + threadIdx.x) * 8;
    long base = ((long)bh * NCH) << 13;
    float s[8] = {0.f};
#pragma unroll
    for (int c = 0; c < NCH; ++c) {
        bf16* p = Lbuf + base + ((long)c << 13) + off;
        bf16x8 L = *(bf16x8*)p;
        bf16x8 I;
#pragma unroll
        for (int k = 0; k < 8; ++k) I[k] = (bf16)s[k];
        float P = Pc[bh * NCH + c];
#pragma unroll
        for (int k = 0; k < 8; ++k) s[k] = P * s[k] + (float)L[k];
        *(bf16x8*)p = I;
    }
}

// ---------------- chunk Y via MFMA: G=C.B^T, mask, Yinter=e^S C.I^T, Yintra=MG.X, +D x ----------------
// grid 1536 = (b,h,c); 512 threads (8 waves)
__global__ __launch_bounds__(512) void k_chunkY(const bf16* __restrict__ cobf,
                                                const float* __restrict__ Sarr, const float* __restrict__ dtc,
                                                const float* __restrict__ Dp,
                                                const bf16* __restrict__ XT, const bf16* __restrict__ Lbuf,
                                                float* __restrict__ ysb) {
    __shared__ bf16 Cs[128 * 128];
    __shared__ bf16 Bs[128 * 128];   // becomes MG after G phase
    __shared__ bf16 Xts[64 * 128];
    __shared__ bf16 Is[64 * 128];
    __shared__ float S_lds[128], dt_lds[128];
    int blk = blockIdx.x;
    int b = blk / (NHEADS * NCH);
    int r = blk % (NHEADS * NCH);
    int h = r / NCH;
    int c = r % NCH;
    int tid = threadIdx.x, lane = tid & 63, wid = tid >> 6;
    long brow0 = (long)b * SEQ + c * QCH;
    const char* cob = (const char*)cobf;
#pragma unroll
    for (int i = 0; i < 4; ++i) {
        int trow = i * 32 + wid * 4 + (lane >> 4);
        int blk16 = lane & 15;
        const char* rp = cob + (brow0 + trow) * (CONVDIM * 2);
        int sb = (blk16 ^ (trow & 7)) << 4;
        GLD(rp + (DINNER + DSTATE) * 2 + sb, (char*)Cs + (i * 32 + wid * 4) * 256);
        GLD(rp + DINNER * 2 + sb, (char*)Bs + (i * 32 + wid * 4) * 256);
    }
    const char* xt = (const char*)XT + (((long)blk) << 14);
    const char* ib = (const char*)Lbuf + (((long)blk) << 14);
#pragma unroll
    for (int i = 0; i < 2; ++i) {
        GLD(xt + (long)(i * 512 + tid) * 16, (char*)Xts + (i * 512 + wid * 64) * 16);
        GLD(ib + (long)(i * 512 + tid) * 16, (char*)Is + (i * 512 + wid * 64) * 16);
    }
    if (tid < 128) { S_lds[tid] = Sarr[blk * QCH + tid]; dt_lds[tid] = dtc[blk * QCH + tid]; }
    float Dh = Dp[h];
    __syncthreads();
    const char* CsB = (const char*)Cs;
    char* BsB = (char*)Bs;
    const char* IsB = (const char*)Is;
    const char* XtB = (const char*)Xts;
    const f32x4 vz = {0.f, 0.f, 0.f, 0.f};
    // ---- G phase: waves 2x4, wave tile 64x32 ----
    int wmG = wid >> 2, wnG = wid & 3;
    f32x4 accg[4][2];
#pragma unroll
    for (int mi = 0; mi < 4; ++mi)
#pragma unroll
        for (int ni = 0; ni < 2; ++ni) accg[mi][ni] = vz;
#pragma unroll
    for (int ks = 0; ks < 4; ++ks) {
        bf16x8 af[4], bfr[2];
#pragma unroll
        for (int mi = 0; mi < 4; ++mi) {
            int t = wmG * 64 + mi * 16 + (lane & 15);
            af[mi] = *(const bf16x8*)(CsB + ((t * 256 + ks * 64 + (lane >> 4) * 16) ^ ((t & 7) << 4)));
        }
#pragma unroll
        for (int ni = 0; ni < 2; ++ni) {
            int u = wnG * 32 + ni * 16 + (lane & 15);
            bfr[ni] = *(const bf16x8*)(BsB + ((u * 256 + ks * 64 + (lane >> 4) * 16) ^ ((u & 7) << 4)));
        }
#pragma unroll
        for (int mi = 0; mi < 4; ++mi)
#pragma unroll
            for (int ni = 0; ni < 2; ++ni)
                accg[mi][ni] = __builtin_amdgcn_mfma_f32_16x16x32_bf16(af[mi], bfr[ni], accg[mi][ni], 0, 0, 0);
    }
    __syncthreads();
    // ---- mask: MG[t,u] = (u<=t) ? G*exp(S_t-S_u)*dt_u : 0 ; write into Bs ----
#pragma unroll
    for (int mi = 0; mi < 4; ++mi) {
#pragma unroll
        for (int j = 0; j < 4; ++j) {
            int t = wmG * 64 + mi * 16 + (lane >> 4) * 4 + j;
            float St = S_lds[t];
#pragma unroll
            for (int ni = 0; ni < 2; ++ni) {
                int u = wnG * 32 + ni * 16 + (lane & 15);
                float v = 0.f;
                if (u <= t) v = accg[mi][ni][j] * __expf(St - S_lds[u]) * dt_lds[u];
                *(bf16*)(BsB + ((t * 256 + u * 2) ^ ((t & 7) << 4))) = (bf16)v;
            }
        }
    }
    __syncthreads();
    // ---- Y phase: waves 4x2, wave tile 32x32 ----
    int wmY = wid >> 1, wnY = wid & 1;
    f32x4 accy[2][2];
#pragma unroll
    for (int mi = 0; mi < 2; ++mi)
#pragma unroll
        for (int ni = 0; ni < 2; ++ni) accy[mi][ni] = vz;
    // Yinter = C @ I^T
#pragma unroll
    for (int ks = 0; ks < 4; ++ks) {
        bf16x8 af[2], bfr[2];
#pragma unroll
        for (int mi = 0; mi < 2; ++mi) {
            int t = wmY * 32 + mi * 16 + (lane & 15);
            af[mi] = *(const bf16x8*)(CsB + ((t * 256 + ks * 64 + (lane >> 4) * 16) ^ ((t & 7) << 4)));
        }
#pragma unroll
        for (int ni = 0; ni < 2; ++ni) {
            int pp = wnY * 32 + ni * 16 + (lane & 15);
            bfr[ni] = *(const bf16x8*)(IsB + ((pp * 256 + ks * 64 + (lane >> 4) * 16) ^ ((pp & 7) << 4)));
        }
#pragma unroll
        for (int mi = 0; mi < 2; ++mi)
#pragma unroll
            for (int ni = 0; ni < 2; ++ni)
                accy[mi][ni] = __builtin_amdgcn_mfma_f32_16x16x32_bf16(af[mi], bfr[ni], accy[mi][ni], 0, 0, 0);
    }
    // scale rows by exp(S_t)
#pragma unroll
    for (int mi = 0; mi < 2; ++mi)
#pragma unroll
        for (int j = 0; j < 4; ++j) {
            int t = wmY * 32 + mi * 16 + (lane >> 4) * 4 + j;
            float e = __expf(S_lds[t]);
#pragma unroll
            for (int ni = 0; ni < 2; ++ni) accy[mi][ni][j] *= e;
        }
    // Yintra += MG @ XT^T
#pragma unroll
    for (int ks = 0; ks < 4; ++ks) {
        bf16x8 af[2], bfr[2];
#pragma unroll
        for (int mi = 0; mi < 2; ++mi) {
            int t = wmY * 32 + mi * 16 + (lane & 15);
            af[mi] = *(const bf16x8*)(BsB + ((t * 256 + ks * 64 + (lane >> 4) * 16) ^ ((t & 7) << 4)));
        }
#pragma unroll
        for (int ni = 0; ni < 2; ++ni) {
            int pp = wnY * 32 + ni * 16 + (lane & 15);
            bfr[ni] = *(const bf16x8*)(XtB + ((pp * 256 + ks * 64 + (lane >> 4) * 16) ^ ((pp & 7) << 4)));
        }
#pragma unroll
        for (int mi = 0; mi < 2; ++mi)
#pragma unroll
            for (int ni = 0; ni < 2; ++ni)
                accy[mi][ni] = __builtin_amdgcn_mfma_f32_16x16x32_bf16(af[mi], bfr[ni], accy[mi][ni], 0, 0, 0);
    }
    // epilogue: + D*x, store
#pragma unroll
    for (int mi = 0; mi < 2; ++mi)
#pragma unroll
        for (int ni = 0; ni < 2; ++ni)
#pragma unroll
            for (int j = 0; j < 4; ++j) {
                int t = wmY * 32 + mi * 16 + (lane >> 4) * 4 + j;
                int pp = wnY * 32 + ni * 16 + (lane & 15);
                float xv = (float)*(const bf16*)(XtB + ((pp * 256 + t * 2) ^ ((pp & 7) << 4)));
                ysb[(brow0 + t) * DINNER + h * HEADDIM + pp] = accy[mi][ni][j] + Dh * xv;
            }
}

// ---------------- gated rmsnorm ----------------
__global__ __launch_bounds__(256) void k_gated(const float* __restrict__ ys, const float* __restrict__ zx,
                                               const float* __restrict__ w, bf16* __restrict__ out) {
    __shared__ float sm[4];
    int r = blockIdx.x, tid = threadIdx.x;
    float v[6]; float ss = 0.f;
#pragma unroll
    for (int k = 0; k < 6; ++k) {
        int d = tid + k * 256;
        float z = zx[(long)r * NPAD + d];
        float t = ys[(long)r * DINNER + d] * fsilu(z);
        v[k] = t; ss += t * t;
    }
#pragma unroll
    for (int off = 32; off; off >>= 1) ss += __shfl_down(ss, off, 64);
    if ((tid & 63) == 0) sm[tid >> 6] = ss;
    __syncthreads();
    float tot = sm[0] + sm[1] + sm[2] + sm[3];
    float sc = rsqrtf(tot / (float)DINNER + EPS);
#pragma unroll
    for (int k = 0; k < 6; ++k) {
        int d = tid + k * 256;
        out[(long)r * DINNER + d] = (bf16)(v[k] * sc * w[d]);
    }
}

// ---------------- head ----------------
__global__ __launch_bounds__(256) void k_head(const bf16* __restrict__ hn, const float* __restrict__ Wh,
                                              const float* __restrict__ y, float* __restrict__ out,
                                              float* __restrict__ loss) {
    __shared__ float sm[4 * 5];
    int r = blockIdx.x, tid = threadIdx.x;
    float acc[5] = {0.f, 0.f, 0.f, 0.f, 0.f};
#pragma unroll
    for (int k = 0; k < 3; ++k) {
        int d = tid + k * 256;
        float hv = (float)hn[r * DMODEL + d];
#pragma unroll
        for (int o = 0; o < 5; ++o) acc[o] += hv * Wh[o * DMODEL + d];
    }
#pragma unroll
    for (int o = 0; o < 5; ++o) {
#pragma unroll
        for (int off = 32; off; off >>= 1) acc[o] += __shfl_down(acc[o], off, 64);
    }
    if ((tid & 63) == 0) {
        int wid = tid >> 6;
#pragma unroll
        for (int o = 0; o < 5; ++o) sm[wid * 5 + o] = acc[o];
    }
    __syncthreads();
    if (tid == 0) {
        float ls = 0.f;
#pragma unroll
        for (int o = 0; o < 5; ++o) {
            float v = sm[o] + sm[5 + o] + sm[10 + o] + sm[15 + o];
            out[r * 5 + o] = v;
            float d = v - y[r * 5 + o];
            ls += d * d;
        }
        atomicAdd(loss, ls / (float)(ROWS * 5));
    }
}

extern "C" void kernel_launch(void* const* d_in, const int* in_sizes, int n_in,
                              void* d_out, int out_size, void* d_ws, size_t ws_size,
                              hipStream_t stream) {
    const float* x      = (const float*)d_in[0];
    const float* y      = (const float*)d_in[1];
    const float* W_emb  = (const float*)d_in[2];
    const float* b_emb  = (const float*)d_in[3];
    const float* W_in   = (const float*)d_in[4];
    const float* conv_w = (const float*)d_in[5];
    const float* conv_b = (const float*)d_in[6];
    const float* dt_bias= (const float*)d_in[7];
    const float* A_log  = (const float*)d_in[8];
    const float* Dp     = (const float*)d_in[9];
    const float* norm_w = (const float*)d_in[10];
    const float* W_out  = (const float*)d_in[11];
    const float* bnw    = (const float*)d_in[12];
    const float* nfw    = (const float*)d_in[13];
    const float* W_head = (const float*)d_in[14];

    char* ws = (char*)d_ws;
    float* hb   = (float*)ws;  ws += (size_t)ROWS * DMODEL * 4;
    float* res  = (float*)ws;  ws += (size_t)ROWS * DMODEL * 4;
    bf16*  hnb  = (bf16*)ws;   ws += (size_t)ROWS * DMODEL * 2;
    float* zx   = (float*)ws;  ws += (size_t)ROWS * NPAD * 4;
    bf16*  cobf = (bf16*)ws;   ws += (size_t)ROWS * CONVDIM * 2;
    float* dtb  = (float*)ws;  ws += (size_t)ROWS * NHEADS * 4;
    float* ysb  = (float*)ws;  ws += (size_t)ROWS * DINNER * 4;
    bf16*  yfb  = (bf16*)ws;   ws += (size_t)ROWS * DINNER * 2;
    bf16*  Wib  = (bf16*)ws;   ws += (size_t)NPAD * DMODEL * 2;
    bf16*  Wob  = (bf16*)ws;   ws += (size_t)DMODEL * DINNER * 2;
    float* Pcb  = (float*)ws;  ws += (size_t)BATCH * NHEADS * NCH * 4;
    float* Sarr = (float*)ws;  ws += (size_t)BATCH * NHEADS * NCH * QCH * 4;
    float* dtc  = (float*)ws;  ws += (size_t)BATCH * NHEADS * NCH * QCH * 4;
    bf16*  XT   = (bf16*)ws;   ws += (size_t)BATCH * NHEADS * NCH * 8192 * 2;
    bf16*  BT   = (bf16*)ws;   ws += (size_t)BATCH * NCH * 16384 * 2;

    // Aliases: Lbuf (25.2MB) <-> hb (dead between add_rmsnorm and out-proj GEMM);
    // XwT (25.2MB) <-> yfb (dead between out-proj GEMM and k_gated).
    bf16* Lbuf = (bf16*)hb;
    bf16* XwT  = (bf16*)yfb;

    float* out_p  = (float*)d_out;
    float* loss_p = out_p + (size_t)ROWS * 5;

    hipMemsetAsync(loss_p, 0, 4, stream);
    k_embed<<<ROWS * DMODEL / 256, 256, 0, stream>>>(x, W_emb, b_emb, hb, res);

    const int NBHC = BATCH * NHEADS * NCH;   // 1536
    for (int l = 0; l < NLAYER; ++l) {
        k_cvt<<<NPAD * DMODEL / 256, 256, 0, stream>>>(W_in + (size_t)l * DINPROJ * DMODEL, Wib, DINPROJ, DMODEL);
        k_add_rmsnorm<<<ROWS, 256, 0, stream>>>(hb, res, bnw + l * DMODEL, hnb);
        dim3 g1(ROWS / 128, NPAD / 128);
        k_gemm<<<g1, 256, 0, stream>>>(hnb, Wib, zx, DMODEL, NPAD);
        k_conv<<<ROWS * CONVDIM / 256, 256, 0, stream>>>(zx, conv_w + (size_t)l * CONVDIM * 4, conv_b + l * CONVDIM, cobf);
        k_dt<<<ROWS * NHEADS / 256, 256, 0, stream>>>(zx, dt_bias + l * NHEADS, dtb);
        k_prep<<<NBHC, 128, 0, stream>>>(cobf, dtb, A_log + l * NHEADS, Sarr, dtc, Pcb, XT, XwT, BT);
        k_stateL<<<NBHC, 256, 0, stream>>>(XwT, BT, Lbuf);
        k_scanB<<<BATCH * NHEADS * 4, 256, 0, stream>>>(Lbuf, Pcb);
        k_chunkY<<<NBHC, 512, 0, stream>>>(cobf, Sarr, dtc, Dp + l * NHEADS, XT, Lbuf, ysb);
        k_gated<<<ROWS, 256, 0, stream>>>(ysb, zx, norm_w + l * DINNER, yfb);
        k_cvt<<<DMODEL * DINNER / 256, 256, 0, stream>>>(W_out + (size_t)l * DMODEL * DINNER, Wob, DMODEL, DINNER);
        dim3 g2(ROWS / 128, DMODEL / 128);
        k_gemm<<<g2, 256, 0, stream>>>(yfb, Wob, hb, DINNER, DMODEL);
    }

    k_add_rmsnorm<<<ROWS, 256, 0, stream>>>(hb, res, nfw, hnb);
    k_head<<<ROWS, 256, 0, stream>>>(hnb, W_head, y, out_p, loss_p);
}

// Round 4
// 2660.119 us; speedup vs baseline: 4.3685x; 1.0523x over previous
//
#include <hip/hip_runtime.h>
#include <hip/hip_bf16.h>
#include <math.h>

#define BATCH 4
#define SEQ 2048
#define DMODEL 768
#define NLAYER 8
#define DINNER 1536
#define HEADDIM 64
#define NHEADS 24
#define DSTATE 128
#define CONVDIM 1792
#define DINPROJ 3352
#define NPAD 3456
#define ROWS (BATCH*SEQ)
#define EPS 1e-5f
#define QCH 128
#define NCH (SEQ/QCH)

typedef __bf16 bf16;
typedef bf16 bf16x8 __attribute__((ext_vector_type(8)));
typedef bf16 bf16x4 __attribute__((ext_vector_type(4)));
typedef float f32x4 __attribute__((ext_vector_type(4)));

#define GLD(src, dst) __builtin_amdgcn_global_load_lds( \
    (const __attribute__((address_space(1))) void*)(src), \
    (__attribute__((address_space(3))) void*)(dst), 16, 0, 0)

__device__ __forceinline__ float fsilu(float x) { return x / (1.f + __expf(-x)); }

// ---------------- embed ----------------
__global__ void k_embed(const float* __restrict__ x, const float* __restrict__ We,
                        const float* __restrict__ be, float* __restrict__ h,
                        float* __restrict__ res) {
    int idx = blockIdx.x * 256 + threadIdx.x;
    int d = idx % DMODEL; int bl = idx / DMODEL;
    float acc = be[d];
#pragma unroll
    for (int i = 0; i < 6; ++i) acc += x[bl * 6 + i] * We[d * 6 + i];
    h[idx] = acc;
    res[idx] = 0.f;
}

// ---------------- fused residual add + rmsnorm -> bf16 ----------------
__global__ __launch_bounds__(256) void k_add_rmsnorm(const float* __restrict__ hin,
                                                     float* __restrict__ res,
                                                     const float* __restrict__ w,
                                                     bf16* __restrict__ out) {
    __shared__ float sm[4];
    int r = blockIdx.x, tid = threadIdx.x;
    float v[3]; float ss = 0.f;
#pragma unroll
    for (int k = 0; k < 3; ++k) {
        int d = tid + k * 256;
        float t = res[r * DMODEL + d] + hin[r * DMODEL + d];
        res[r * DMODEL + d] = t; v[k] = t; ss += t * t;
    }
#pragma unroll
    for (int off = 32; off; off >>= 1) ss += __shfl_down(ss, off, 64);
    if ((tid & 63) == 0) sm[tid >> 6] = ss;
    __syncthreads();
    float tot = sm[0] + sm[1] + sm[2] + sm[3];
    float sc = rsqrtf(tot / (float)DMODEL + EPS);
#pragma unroll
    for (int k = 0; k < 3; ++k) {
        int d = tid + k * 256;
        out[r * DMODEL + d] = (bf16)(v[k] * sc * w[d]);
    }
}

// ---------------- batched weight conversions (all layers at once) ----------------
__global__ void k_cvt_in(const float* __restrict__ src, bf16* __restrict__ dst) {
    int idx = blockIdx.x * 256 + threadIdx.x;          // NLAYER*NPAD*DMODEL
    int l = idx / (NPAD * DMODEL);
    int rem = idx % (NPAD * DMODEL);
    int n = rem / DMODEL;
    int d = rem % DMODEL;
    dst[idx] = (n < DINPROJ) ? (bf16)src[(long)l * DINPROJ * DMODEL + n * DMODEL + d] : (bf16)0.f;
}
__global__ void k_cvt_out(const float* __restrict__ src, bf16* __restrict__ dst) {
    int idx = blockIdx.x * 256 + threadIdx.x;          // NLAYER*DMODEL*DINNER
    dst[idx] = (bf16)src[idx];
}

// ---------------- bf16 MFMA GEMM: C[M,N] = A[M,K] @ B[N,K]^T (templated output) ----------------
template <typename OT>
__global__ __launch_bounds__(256) void k_gemm(const bf16* __restrict__ A, const bf16* __restrict__ B,
                                              OT* __restrict__ C, int K, int ldc) {
    __shared__ bf16 As[128 * 64];
    __shared__ bf16 Bs[128 * 64];
    const int tid = threadIdx.x;
    const int lane = tid & 63;
    const int w = tid >> 6;
    const int wm = w >> 1, wn = w & 1;
    const long rowA0 = (long)blockIdx.x * 128;
    const long rowB0 = (long)blockIdx.y * 128;
    const int srow = tid >> 3;
    const int scol = (tid & 7) * 8;
    f32x4 acc[4][4];
    const f32x4 vz = {0.f, 0.f, 0.f, 0.f};
#pragma unroll
    for (int i = 0; i < 4; ++i)
#pragma unroll
        for (int j = 0; j < 4; ++j) acc[i][j] = vz;

    const bf16* Ab = A + rowA0 * K;
    const bf16* Bb = B + rowB0 * K;
    for (int kt = 0; kt < K; kt += 64) {
#pragma unroll
        for (int j = 0; j < 4; ++j)
            GLD(Ab + (long)(j * 32 + srow) * K + kt + scol, &As[(j * 32 + w * 8) * 64]);
#pragma unroll
        for (int j = 0; j < 4; ++j)
            GLD(Bb + (long)(j * 32 + srow) * K + kt + scol, &Bs[(j * 32 + w * 8) * 64]);
        __syncthreads();
#pragma unroll
        for (int s = 0; s < 2; ++s) {
            bf16x8 af[4], bfr[4];
#pragma unroll
            for (int mi = 0; mi < 4; ++mi)
                af[mi] = *(const bf16x8*)&As[(wm * 64 + mi * 16 + (lane & 15)) * 64 + s * 32 + (lane >> 4) * 8];
#pragma unroll
            for (int ni = 0; ni < 4; ++ni)
                bfr[ni] = *(const bf16x8*)&Bs[(wn * 64 + ni * 16 + (lane & 15)) * 64 + s * 32 + (lane >> 4) * 8];
#pragma unroll
            for (int mi = 0; mi < 4; ++mi)
#pragma unroll
                for (int ni = 0; ni < 4; ++ni)
                    acc[mi][ni] = __builtin_amdgcn_mfma_f32_16x16x32_bf16(af[mi], bfr[ni], acc[mi][ni], 0, 0, 0);
        }
        __syncthreads();
    }
    const int crow = (lane >> 4) * 4;
    const int ccol = lane & 15;
#pragma unroll
    for (int mi = 0; mi < 4; ++mi)
#pragma unroll
        for (int ni = 0; ni < 4; ++ni) {
            long r0 = rowA0 + wm * 64 + mi * 16 + crow;
            long c0 = rowB0 + wn * 64 + ni * 16 + ccol;
#pragma unroll
            for (int j = 0; j < 4; ++j) C[(r0 + j) * ldc + c0] = (OT)acc[mi][ni][j];
        }
}

// ---------------- causal conv1d (k=4) + bias + silu, bf16 in/out, 8 ch/thread ----------------
__global__ void k_conv(const bf16* __restrict__ zx, const float* __restrict__ cw,
                       const float* __restrict__ cb, bf16* __restrict__ co) {
    int idx = blockIdx.x * 256 + threadIdx.x;   // ROWS * 224
    int c8 = idx % 224; int blt = idx / 224;
    int t = blt % SEQ;
    int c0 = c8 * 8;
    long bbase = (long)(blt - t) * NPAD;
    float cwa[8][4];
#pragma unroll
    for (int j = 0; j < 8; ++j) {
        float4 tv = *(const float4*)(cw + (c0 + j) * 4);
        cwa[j][0] = tv.x; cwa[j][1] = tv.y; cwa[j][2] = tv.z; cwa[j][3] = tv.w;
    }
    float acc[8];
#pragma unroll
    for (int j = 0; j < 8; ++j) acc[j] = cb[c0 + j];
#pragma unroll
    for (int k = 0; k < 4; ++k) {
        int tt = t + k - 3;
        if (tt >= 0) {
            bf16x8 v = *(const bf16x8*)(zx + bbase + (long)tt * NPAD + DINNER + c0);
#pragma unroll
            for (int j = 0; j < 8; ++j) acc[j] += (float)v[j] * cwa[j][k];
        }
    }
    bf16x8 o;
#pragma unroll
    for (int j = 0; j < 8; ++j) o[j] = (bf16)fsilu(acc[j]);
    *(bf16x8*)(co + (long)blt * CONVDIM + c0) = o;
}

// ---------------- dt = softplus(raw + bias) ----------------
__global__ void k_dt(const bf16* __restrict__ zx, const float* __restrict__ dtb,
                     float* __restrict__ dt) {
    int idx = blockIdx.x * 256 + threadIdx.x;
    int hh = idx % NHEADS; int bl = idx / NHEADS;
    float v = (float)zx[(long)bl * NPAD + DINNER + CONVDIM + hh] + dtb[hh];
    dt[idx] = (v > 15.f) ? v : log1pf(__expf(v));
}

// ---------------- per-chunk prep: cumsum S, Pc, chunk-contig dt/S, swizzled XT/XwT/BT ----------------
__global__ __launch_bounds__(128) void k_prep(const bf16* __restrict__ cobf, const float* __restrict__ dtb,
                                              const float* __restrict__ Alog,
                                              float* __restrict__ Sarr, float* __restrict__ dtc,
                                              float* __restrict__ Pcb,
                                              bf16* __restrict__ XT, bf16* __restrict__ XwT,
                                              bf16* __restrict__ BT) {
    int blk = blockIdx.x;
    int b = blk / (NHEADS * NCH);
    int r = blk % (NHEADS * NCH);
    int h = r / NCH;
    int c = r % NCH;
    int tid = threadIdx.x;
    __shared__ float S_lds[128], dt_lds[128], wl_lds[128], wtot[2];
    __shared__ bf16 Xs[128][64];
    long grow = (long)(b * SEQ + c * QCH + tid);
    float dtv = dtb[grow * NHEADS + h];
    float Ah = -__expf(Alog[h]);
    float ps = dtv * Ah;
#pragma unroll
    for (int off = 1; off < 64; off <<= 1) {
        float o = __shfl_up(ps, off, 64);
        if ((tid & 63) >= off) ps += o;
    }
    if ((tid & 63) == 63) wtot[tid >> 6] = ps;
    __syncthreads();
    if (tid >= 64) ps += wtot[0];
    S_lds[tid] = ps; dt_lds[tid] = dtv;
    __syncthreads();
    float Sl = S_lds[127];
    wl_lds[tid] = __expf(Sl - ps) * dtv;
    Sarr[blk * QCH + tid] = ps;
    dtc[blk * QCH + tid] = dtv;
    if (tid == 127) Pcb[blk] = __expf(Sl);
    const bf16* xrow = cobf + grow * CONVDIM + h * HEADDIM;
#pragma unroll
    for (int j = 0; j < 8; ++j) *(bf16x8*)&Xs[tid][j * 8] = *(const bf16x8*)(xrow + j * 8);
    __syncthreads();
    int p = tid >> 1, hf = tid & 1;
    char* xtb = (char*)XT + (((long)blk) << 14);
    char* xwb = (char*)XwT + (((long)blk) << 14);
#pragma unroll
    for (int ub = 0; ub < 8; ++ub) {
        int u0 = hf * 64 + ub * 8;
        bf16x8 vx, vw;
#pragma unroll
        for (int k = 0; k < 8; ++k) {
            int u = u0 + k;
            bf16 xv = Xs[u][p];
            vx[k] = xv;
            vw[k] = (bf16)((float)xv * wl_lds[u]);
        }
        long off = (long)((p * 256 + u0 * 2) ^ ((p & 7) << 4));
        *(bf16x8*)(xtb + off) = vx;
        *(bf16x8*)(xwb + off) = vw;
    }
    if (h == 0) {
        char* btb = (char*)BT + (((long)(b * NCH + c)) << 15);
        const bf16* brow = cobf + (long)(b * SEQ + c * QCH + tid) * CONVDIM + DINNER;
        int nl = tid >> 1;
        for (int nb = 0; nb < 2; ++nb) {
            __syncthreads();
#pragma unroll
            for (int j = 0; j < 8; ++j) *(bf16x8*)&Xs[tid][j * 8] = *(const bf16x8*)(brow + nb * 64 + j * 8);
            __syncthreads();
            int n = nb * 64 + nl;
#pragma unroll
            for (int ub = 0; ub < 8; ++ub) {
                int u0 = hf * 64 + ub * 8;
                bf16x8 v;
#pragma unroll
                for (int k = 0; k < 8; ++k) v[k] = Xs[u0 + k][nl];
                long off = (long)((n * 256 + u0 * 2) ^ ((n & 7) << 4));
                *(bf16x8*)(btb + off) = v;
            }
        }
    }
}

// ---------------- chunk-local final state via MFMA: L[64,128] = XwT @ BT^T ----------------
__global__ __launch_bounds__(256) void k_stateL(const bf16* __restrict__ XwT, const bf16* __restrict__ BT,
                                                bf16* __restrict__ Lbuf) {
    __shared__ bf16 Xs[64 * 128];
    __shared__ bf16 Bs[128 * 128];
    int blk = blockIdx.x;
    int b = blk / (NHEADS * NCH);
    int r = blk % (NHEADS * NCH);
    int c = r % NCH;
    int bc = b * NCH + c;
    int tid = threadIdx.x, lane = tid & 63, wid = tid >> 6;
    const char* xw = (const char*)XwT + (((long)blk) << 14);
    const char* bt = (const char*)BT + (((long)bc) << 15);
#pragma unroll
    for (int i = 0; i < 4; ++i)
        GLD(xw + (long)(i * 256 + tid) * 16, (char*)Xs + (i * 256 + wid * 64) * 16);
#pragma unroll
    for (int i = 0; i < 8; ++i)
        GLD(bt + (long)(i * 256 + tid) * 16, (char*)Bs + (i * 256 + wid * 64) * 16);
    __syncthreads();
    f32x4 acc[4][2];
    const f32x4 vz = {0.f, 0.f, 0.f, 0.f};
#pragma unroll
    for (int mi = 0; mi < 4; ++mi)
#pragma unroll
        for (int ni = 0; ni < 2; ++ni) acc[mi][ni] = vz;
    const char* XsB = (const char*)Xs;
    const char* BsB = (const char*)Bs;
#pragma unroll
    for (int ks = 0; ks < 4; ++ks) {
        bf16x8 af[4], bfr[2];
#pragma unroll
        for (int mi = 0; mi < 4; ++mi) {
            int pp = mi * 16 + (lane & 15);
            af[mi] = *(const bf16x8*)(XsB + ((pp * 256 + ks * 64 + (lane >> 4) * 16) ^ ((pp & 7) << 4)));
        }
#pragma unroll
        for (int ni = 0; ni < 2; ++ni) {
            int n = wid * 32 + ni * 16 + (lane & 15);
            bfr[ni] = *(const bf16x8*)(BsB + ((n * 256 + ks * 64 + (lane >> 4) * 16) ^ ((n & 7) << 4)));
        }
#pragma unroll
        for (int mi = 0; mi < 4; ++mi)
#pragma unroll
            for (int ni = 0; ni < 2; ++ni)
                acc[mi][ni] = __builtin_amdgcn_mfma_f32_16x16x32_bf16(af[mi], bfr[ni], acc[mi][ni], 0, 0, 0);
    }
    char* lb = (char*)Lbuf + (((long)blk) << 14);
#pragma unroll
    for (int mi = 0; mi < 4; ++mi)
#pragma unroll
        for (int ni = 0; ni < 2; ++ni)
#pragma unroll
            for (int j = 0; j < 4; ++j) {
                int pp = mi * 16 + (lane >> 4) * 4 + j;
                int n = wid * 32 + ni * 16 + (lane & 15);
                *(bf16*)(lb + ((pp * 256 + n * 2) ^ ((pp & 7) << 4))) = (bf16)acc[mi][ni][j];
            }
}

// ---------------- Pass B: sequential inter-chunk combine ----------------
__global__ __launch_bounds__(256) void k_scanB(bf16* __restrict__ Lbuf, const float* __restrict__ Pc) {
    int bh = blockIdx.x >> 2;
    int q = blockIdx.x & 3;
    int off = (q * 256 + threadIdx.x) * 8;
    long base = ((long)bh * NCH) << 13;
    float s[8] = {0.f};
#pragma unroll
    for (int c = 0; c < NCH; ++c) {
        bf16* p = Lbuf + base + ((long)c << 13) + off;
        bf16x8 L = *(bf16x8*)p;
        bf16x8 I;
#pragma unroll
        for (int k = 0; k < 8; ++k) I[k] = (bf16)s[k];
        float P = Pc[bh * NCH + c];
#pragma unroll
        for (int k = 0; k < 8; ++k) s[k] = P * s[k] + (float)L[k];
        *(bf16x8*)p = I;
    }
}

// ---------------- chunk Y via MFMA ----------------
__global__ __launch_bounds__(512) void k_chunkY(const bf16* __restrict__ cobf,
                                                const float* __restrict__ Sarr, const float* __restrict__ dtc,
                                                const float* __restrict__ Dp,
                                                const bf16* __restrict__ XT, const bf16* __restrict__ Lbuf,
                                                float* __restrict__ ysb) {
    __shared__ bf16 Cs[128 * 128];
    __shared__ bf16 Bs[128 * 128];
    __shared__ bf16 Xts[64 * 128];
    __shared__ bf16 Is[64 * 128];
    __shared__ float S_lds[128], dt_lds[128];
    int blk = blockIdx.x;
    int b = blk / (NHEADS * NCH);
    int r = blk % (NHEADS * NCH);
    int h = r / NCH;
    int c = r % NCH;
    int tid = threadIdx.x, lane = tid & 63, wid = tid >> 6;
    long brow0 = (long)b * SEQ + c * QCH;
    const char* cob = (const char*)cobf;
#pragma unroll
    for (int i = 0; i < 4; ++i) {
        int trow = i * 32 + wid * 4 + (lane >> 4);
        int blk16 = lane & 15;
        const char* rp = cob + (brow0 + trow) * (CONVDIM * 2);
        int sb = (blk16 ^ (trow & 7)) << 4;
        GLD(rp + (DINNER + DSTATE) * 2 + sb, (char*)Cs + (i * 32 + wid * 4) * 256);
        GLD(rp + DINNER * 2 + sb, (char*)Bs + (i * 32 + wid * 4) * 256);
    }
    const char* xt = (const char*)XT + (((long)blk) << 14);
    const char* ib = (const char*)Lbuf + (((long)blk) << 14);
#pragma unroll
    for (int i = 0; i < 2; ++i) {
        GLD(xt + (long)(i * 512 + tid) * 16, (char*)Xts + (i * 512 + wid * 64) * 16);
        GLD(ib + (long)(i * 512 + tid) * 16, (char*)Is + (i * 512 + wid * 64) * 16);
    }
    if (tid < 128) { S_lds[tid] = Sarr[blk * QCH + tid]; dt_lds[tid] = dtc[blk * QCH + tid]; }
    float Dh = Dp[h];
    __syncthreads();
    const char* CsB = (const char*)Cs;
    char* BsB = (char*)Bs;
    const char* IsB = (const char*)Is;
    const char* XtB = (const char*)Xts;
    const f32x4 vz = {0.f, 0.f, 0.f, 0.f};
    int wmG = wid >> 2, wnG = wid & 3;
    f32x4 accg[4][2];
#pragma unroll
    for (int mi = 0; mi < 4; ++mi)
#pragma unroll
        for (int ni = 0; ni < 2; ++ni) accg[mi][ni] = vz;
#pragma unroll
    for (int ks = 0; ks < 4; ++ks) {
        bf16x8 af[4], bfr[2];
#pragma unroll
        for (int mi = 0; mi < 4; ++mi) {
            int t = wmG * 64 + mi * 16 + (lane & 15);
            af[mi] = *(const bf16x8*)(CsB + ((t * 256 + ks * 64 + (lane >> 4) * 16) ^ ((t & 7) << 4)));
        }
#pragma unroll
        for (int ni = 0; ni < 2; ++ni) {
            int u = wnG * 32 + ni * 16 + (lane & 15);
            bfr[ni] = *(const bf16x8*)(BsB + ((u * 256 + ks * 64 + (lane >> 4) * 16) ^ ((u & 7) << 4)));
        }
#pragma unroll
        for (int mi = 0; mi < 4; ++mi)
#pragma unroll
            for (int ni = 0; ni < 2; ++ni)
                accg[mi][ni] = __builtin_amdgcn_mfma_f32_16x16x32_bf16(af[mi], bfr[ni], accg[mi][ni], 0, 0, 0);
    }
    __syncthreads();
#pragma unroll
    for (int mi = 0; mi < 4; ++mi) {
#pragma unroll
        for (int j = 0; j < 4; ++j) {
            int t = wmG * 64 + mi * 16 + (lane >> 4) * 4 + j;
            float St = S_lds[t];
#pragma unroll
            for (int ni = 0; ni < 2; ++ni) {
                int u = wnG * 32 + ni * 16 + (lane & 15);
                float v = 0.f;
                if (u <= t) v = accg[mi][ni][j] * __expf(St - S_lds[u]) * dt_lds[u];
                *(bf16*)(BsB + ((t * 256 + u * 2) ^ ((t & 7) << 4))) = (bf16)v;
            }
        }
    }
    __syncthreads();
    int wmY = wid >> 1, wnY = wid & 1;
    f32x4 accy[2][2];
#pragma unroll
    for (int mi = 0; mi < 2; ++mi)
#pragma unroll
        for (int ni = 0; ni < 2; ++ni) accy[mi][ni] = vz;
#pragma unroll
    for (int ks = 0; ks < 4; ++ks) {
        bf16x8 af[2], bfr[2];
#pragma unroll
        for (int mi = 0; mi < 2; ++mi) {
            int t = wmY * 32 + mi * 16 + (lane & 15);
            af[mi] = *(const bf16x8*)(CsB + ((t * 256 + ks * 64 + (lane >> 4) * 16) ^ ((t & 7) << 4)));
        }
#pragma unroll
        for (int ni = 0; ni < 2; ++ni) {
            int pp = wnY * 32 + ni * 16 + (lane & 15);
            bfr[ni] = *(const bf16x8*)(IsB + ((pp * 256 + ks * 64 + (lane >> 4) * 16) ^ ((pp & 7) << 4)));
        }
#pragma unroll
        for (int mi = 0; mi < 2; ++mi)
#pragma unroll
            for (int ni = 0; ni < 2; ++ni)
                accy[mi][ni] = __builtin_amdgcn_mfma_f32_16x16x32_bf16(af[mi], bfr[ni], accy[mi][ni], 0, 0, 0);
    }
#pragma unroll
    for (int mi = 0; mi < 2; ++mi)
#pragma unroll
        for (int j = 0; j < 4; ++j) {
            int t = wmY * 32 + mi * 16 + (lane >> 4) * 4 + j;
            float e = __expf(S_lds[t]);
#pragma unroll
            for (int ni = 0; ni < 2; ++ni) accy[mi][ni][j] *= e;
        }
#pragma unroll
    for (int ks = 0; ks < 4; ++ks) {
        bf16x8 af[2], bfr[2];
#pragma unroll
        for (int mi = 0; mi < 2; ++mi) {
            int t = wmY * 32 + mi * 16 + (lane & 15);
            af[mi] = *(const bf16x8*)(BsB + ((t * 256 + ks * 64 + (lane >> 4) * 16) ^ ((t & 7) << 4)));
        }
#pragma unroll
        for (int ni = 0; ni < 2; ++ni) {
            int pp = wnY * 32 + ni * 16 + (lane & 15);
            bfr[ni] = *(const bf16x8*)(XtB + ((pp * 256 + ks * 64 + (lane >> 4) * 16) ^ ((pp & 7) << 4)));
        }
#pragma unroll
        for (int mi = 0; mi < 2; ++mi)
#pragma unroll
            for (int ni = 0; ni < 2; ++ni)
                accy[mi][ni] = __builtin_amdgcn_mfma_f32_16x16x32_bf16(af[mi], bfr[ni], accy[mi][ni], 0, 0, 0);
    }
#pragma unroll
    for (int mi = 0; mi < 2; ++mi)
#pragma unroll
        for (int ni = 0; ni < 2; ++ni)
#pragma unroll
            for (int j = 0; j < 4; ++j) {
                int t = wmY * 32 + mi * 16 + (lane >> 4) * 4 + j;
                int pp = wnY * 32 + ni * 16 + (lane & 15);
                float xv = (float)*(const bf16*)(XtB + ((pp * 256 + t * 2) ^ ((pp & 7) << 4)));
                ysb[(brow0 + t) * DINNER + h * HEADDIM + pp] = accy[mi][ni][j] + Dh * xv;
            }
}

// ---------------- gated rmsnorm ----------------
__global__ __launch_bounds__(256) void k_gated(const float* __restrict__ ys, const bf16* __restrict__ zx,
                                               const float* __restrict__ w, bf16* __restrict__ out) {
    __shared__ float sm[4];
    int r = blockIdx.x, tid = threadIdx.x;
    float v[6]; float ss = 0.f;
#pragma unroll
    for (int k = 0; k < 6; ++k) {
        int d = tid + k * 256;
        float z = (float)zx[(long)r * NPAD + d];
        float t = ys[(long)r * DINNER + d] * fsilu(z);
        v[k] = t; ss += t * t;
    }
#pragma unroll
    for (int off = 32; off; off >>= 1) ss += __shfl_down(ss, off, 64);
    if ((tid & 63) == 0) sm[tid >> 6] = ss;
    __syncthreads();
    float tot = sm[0] + sm[1] + sm[2] + sm[3];
    float sc = rsqrtf(tot / (float)DINNER + EPS);
#pragma unroll
    for (int k = 0; k < 6; ++k) {
        int d = tid + k * 256;
        out[(long)r * DINNER + d] = (bf16)(v[k] * sc * w[d]);
    }
}

// ---------------- head: 32 rows/block, 1 atomic/block ----------------
__global__ __launch_bounds__(256) void k_head(const bf16* __restrict__ hn, const float* __restrict__ Wh,
                                              const float* __restrict__ y, float* __restrict__ out,
                                              float* __restrict__ loss) {
    __shared__ float sl[4];
    int tid = threadIdx.x, lane = tid & 63, wid = tid >> 6;
    float wv[5][12];
#pragma unroll
    for (int o = 0; o < 5; ++o)
#pragma unroll
        for (int j = 0; j < 12; ++j) wv[o][j] = Wh[o * DMODEL + lane * 12 + j];
    float lsum = 0.f;
#pragma unroll
    for (int rr = 0; rr < 8; ++rr) {
        long r = (long)blockIdx.x * 32 + wid * 8 + rr;
        const bf16* hp = hn + r * DMODEL + lane * 12;
        float hv[12];
#pragma unroll
        for (int q = 0; q < 3; ++q) {
            bf16x4 v4 = *(const bf16x4*)(hp + q * 4);
#pragma unroll
            for (int j = 0; j < 4; ++j) hv[q * 4 + j] = (float)v4[j];
        }
        float acc[5];
#pragma unroll
        for (int o = 0; o < 5; ++o) {
            float a = 0.f;
#pragma unroll
            for (int j = 0; j < 12; ++j) a += hv[j] * wv[o][j];
            acc[o] = a;
        }
#pragma unroll
        for (int o = 0; o < 5; ++o)
#pragma unroll
            for (int m = 32; m; m >>= 1) acc[o] += __shfl_xor(acc[o], m, 64);
        if (lane == 0) {
#pragma unroll
            for (int o = 0; o < 5; ++o) {
                out[r * 5 + o] = acc[o];
                float d = acc[o] - y[r * 5 + o];
                lsum += d * d;
            }
        }
    }
    if (lane == 0) sl[wid] = lsum;
    __syncthreads();
    if (tid == 0) atomicAdd(loss, (sl[0] + sl[1] + sl[2] + sl[3]) * (1.f / ((float)ROWS * 5.f)));
}

extern "C" void kernel_launch(void* const* d_in, const int* in_sizes, int n_in,
                              void* d_out, int out_size, void* d_ws, size_t ws_size,
                              hipStream_t stream) {
    const float* x      = (const float*)d_in[0];
    const float* y      = (const float*)d_in[1];
    const float* W_emb  = (const float*)d_in[2];
    const float* b_emb  = (const float*)d_in[3];
    const float* W_in   = (const float*)d_in[4];
    const float* conv_w = (const float*)d_in[5];
    const float* conv_b = (const float*)d_in[6];
    const float* dt_bias= (const float*)d_in[7];
    const float* A_log  = (const float*)d_in[8];
    const float* Dp     = (const float*)d_in[9];
    const float* norm_w = (const float*)d_in[10];
    const float* W_out  = (const float*)d_in[11];
    const float* bnw    = (const float*)d_in[12];
    const float* nfw    = (const float*)d_in[13];
    const float* W_head = (const float*)d_in[14];

    char* ws = (char*)d_ws;
    float* hb   = (float*)ws;  ws += (size_t)ROWS * DMODEL * 4;
    float* res  = (float*)ws;  ws += (size_t)ROWS * DMODEL * 4;
    bf16*  hnb  = (bf16*)ws;   ws += (size_t)ROWS * DMODEL * 2;
    bf16*  zx   = (bf16*)ws;   ws += (size_t)ROWS * NPAD * 2;
    bf16*  cobf = (bf16*)ws;   ws += (size_t)ROWS * CONVDIM * 2;
    float* dtb  = (float*)ws;  ws += (size_t)ROWS * NHEADS * 4;
    float* ysb  = (float*)ws;  ws += (size_t)ROWS * DINNER * 4;
    bf16*  yfb  = (bf16*)ws;   ws += (size_t)ROWS * DINNER * 2;
    bf16*  Wib  = (bf16*)ws;   ws += (size_t)NLAYER * NPAD * DMODEL * 2;
    bf16*  Wob  = (bf16*)ws;   ws += (size_t)NLAYER * DMODEL * DINNER * 2;
    float* Pcb  = (float*)ws;  ws += (size_t)BATCH * NHEADS * NCH * 4;
    float* Sarr = (float*)ws;  ws += (size_t)BATCH * NHEADS * NCH * QCH * 4;
    float* dtc  = (float*)ws;  ws += (size_t)BATCH * NHEADS * NCH * QCH * 4;
    bf16*  XT   = (bf16*)ws;   ws += (size_t)BATCH * NHEADS * NCH * 8192 * 2;
    bf16*  BT   = (bf16*)ws;   ws += (size_t)BATCH * NCH * 16384 * 2;

    bf16* Lbuf = (bf16*)hb;   // 25.2MB alias, dead window between add_rmsnorm and out-proj
    bf16* XwT  = (bf16*)yfb;  // alias, dead window between out-proj and k_gated

    float* out_p  = (float*)d_out;
    float* loss_p = out_p + (size_t)ROWS * 5;

    hipMemsetAsync(loss_p, 0, 4, stream);
    k_embed<<<ROWS * DMODEL / 256, 256, 0, stream>>>(x, W_emb, b_emb, hb, res);
    k_cvt_in<<<NLAYER * NPAD * DMODEL / 256, 256, 0, stream>>>(W_in, Wib);
    k_cvt_out<<<NLAYER * DMODEL * DINNER / 256, 256, 0, stream>>>(W_out, Wob);

    const int NBHC = BATCH * NHEADS * NCH;   // 1536
    for (int l = 0; l < NLAYER; ++l) {
        k_add_rmsnorm<<<ROWS, 256, 0, stream>>>(hb, res, bnw + l * DMODEL, hnb);
        dim3 g1(ROWS / 128, NPAD / 128);
        k_gemm<bf16><<<g1, 256, 0, stream>>>(hnb, Wib + (size_t)l * NPAD * DMODEL, zx, DMODEL, NPAD);
        k_conv<<<ROWS * 224 / 256, 256, 0, stream>>>(zx, conv_w + (size_t)l * CONVDIM * 4, conv_b + l * CONVDIM, cobf);
        k_dt<<<ROWS * NHEADS / 256, 256, 0, stream>>>(zx, dt_bias + l * NHEADS, dtb);
        k_prep<<<NBHC, 128, 0, stream>>>(cobf, dtb, A_log + l * NHEADS, Sarr, dtc, Pcb, XT, XwT, BT);
        k_stateL<<<NBHC, 256, 0, stream>>>(XwT, BT, Lbuf);
        k_scanB<<<BATCH * NHEADS * 4, 256, 0, stream>>>(Lbuf, Pcb);
        k_chunkY<<<NBHC, 512, 0, stream>>>(cobf, Sarr, dtc, Dp + l * NHEADS, XT, Lbuf, ysb);
        k_gated<<<ROWS, 256, 0, stream>>>(ysb, zx, norm_w + l * DINNER, yfb);
        dim3 g2(ROWS / 128, DMODEL / 128);
        k_gemm<float><<<g2, 256, 0, stream>>>(yfb, Wob + (size_t)l * DMODEL * DINNER, hb, DINNER, DMODEL);
    }

    k_add_rmsnorm<<<ROWS, 256, 0, stream>>>(hb, res, nfw, hnb);
    k_head<<<256, 256, 0, stream>>>(hnb, W_head, y, out_p, loss_p);
}

// Round 5
// 2522.951 us; speedup vs baseline: 4.6060x; 1.0544x over previous
//
#include <hip/hip_runtime.h>
#include <hip/hip_bf16.h>
#include <math.h>

#define BATCH 4
#define SEQ 2048
#define DMODEL 768
#define NLAYER 8
#define DINNER 1536
#define HEADDIM 64
#define NHEADS 24
#define DSTATE 128
#define CONVDIM 1792
#define DINPROJ 3352
#define NPAD 3456
#define ROWS (BATCH*SEQ)
#define EPS 1e-5f
#define QCH 128
#define NCH (SEQ/QCH)

typedef __bf16 bf16;
typedef bf16 bf16x8 __attribute__((ext_vector_type(8)));
typedef bf16 bf16x4 __attribute__((ext_vector_type(4)));
typedef float f32x4 __attribute__((ext_vector_type(4)));

#define GLD(src, dst) __builtin_amdgcn_global_load_lds( \
    (const __attribute__((address_space(1))) void*)(src), \
    (__attribute__((address_space(3))) void*)(dst), 16, 0, 0)

__device__ __forceinline__ float fsilu(float x) { return x / (1.f + __expf(-x)); }

// ---------------- embed ----------------
__global__ void k_embed(const float* __restrict__ x, const float* __restrict__ We,
                        const float* __restrict__ be, float* __restrict__ h,
                        float* __restrict__ res) {
    int idx = blockIdx.x * 256 + threadIdx.x;
    int d = idx % DMODEL; int bl = idx / DMODEL;
    float acc = be[d];
#pragma unroll
    for (int i = 0; i < 6; ++i) acc += x[bl * 6 + i] * We[d * 6 + i];
    h[idx] = acc;
    res[idx] = 0.f;
}

// ---------------- fused residual add + rmsnorm -> bf16 ----------------
__global__ __launch_bounds__(256) void k_add_rmsnorm(const float* __restrict__ hin,
                                                     float* __restrict__ res,
                                                     const float* __restrict__ w,
                                                     bf16* __restrict__ out) {
    __shared__ float sm[4];
    int r = blockIdx.x, tid = threadIdx.x;
    float v[3]; float ss = 0.f;
#pragma unroll
    for (int k = 0; k < 3; ++k) {
        int d = tid + k * 256;
        float t = res[r * DMODEL + d] + hin[r * DMODEL + d];
        res[r * DMODEL + d] = t; v[k] = t; ss += t * t;
    }
#pragma unroll
    for (int off = 32; off; off >>= 1) ss += __shfl_down(ss, off, 64);
    if ((tid & 63) == 0) sm[tid >> 6] = ss;
    __syncthreads();
    float tot = sm[0] + sm[1] + sm[2] + sm[3];
    float sc = rsqrtf(tot / (float)DMODEL + EPS);
#pragma unroll
    for (int k = 0; k < 3; ++k) {
        int d = tid + k * 256;
        out[r * DMODEL + d] = (bf16)(v[k] * sc * w[d]);
    }
}

// ---------------- batched weight conversions ----------------
__global__ void k_cvt_in(const float* __restrict__ src, bf16* __restrict__ dst) {
    int idx = blockIdx.x * 256 + threadIdx.x;
    int l = idx / (NPAD * DMODEL);
    int rem = idx % (NPAD * DMODEL);
    int n = rem / DMODEL;
    int d = rem % DMODEL;
    dst[idx] = (n < DINPROJ) ? (bf16)src[(long)l * DINPROJ * DMODEL + n * DMODEL + d] : (bf16)0.f;
}
__global__ void k_cvt_out(const float* __restrict__ src, bf16* __restrict__ dst) {
    int idx = blockIdx.x * 256 + threadIdx.x;
    dst[idx] = (bf16)src[idx];
}

// ---------------- bf16 MFMA GEMM: C[M,N] = A[M,K] @ B[N,K]^T ----------------
// 128xBN tile, BK=64, double-buffered 2-phase, XOR-swizzled LDS (T2 both-sides).
template <typename OT, int BN>
__global__ __launch_bounds__(256) void k_gemm(const bf16* __restrict__ A, const bf16* __restrict__ B,
                                              OT* __restrict__ C, int K, int ldc) {
    constexpr int nWn = BN / 64;            // 2 (BN=128) or 1 (BN=64)
    constexpr int nWm = 4 / nWn;            // 2 or 4
    constexpr int WMR = 128 / nWm;          // 64 or 32
    constexpr int MI = WMR / 16;            // 4 or 2
    constexpr int NI = 4;                   // 64/16
    __shared__ bf16 As[2][128 * 64];
    __shared__ bf16 Bs[2][BN * 64];
    const int tid = threadIdx.x;
    const int lane = tid & 63;
    const int w = tid >> 6;
    const int wm = w / nWn, wn = w % nWn;
    const long rowA0 = (long)blockIdx.x * 128;
    const long rowB0 = (long)blockIdx.y * BN;
    const int srow = tid >> 3;                          // 0..31
    const int scol = ((tid & 7) ^ (srow & 7)) * 8;      // pre-swizzled k-offset (T2 source side)
    const bf16* Ab = A + rowA0 * K + scol;
    const bf16* Bb = B + rowB0 * K + scol;

    f32x4 acc[MI][NI];
    const f32x4 vz = {0.f, 0.f, 0.f, 0.f};
#pragma unroll
    for (int mi = 0; mi < MI; ++mi)
#pragma unroll
        for (int ni = 0; ni < NI; ++ni) acc[mi][ni] = vz;

    auto stage = [&](int buf, int kt) {
#pragma unroll
        for (int j = 0; j < 4; ++j)
            GLD(Ab + (long)(j * 32 + srow) * K + kt, &As[buf][(j * 32 + w * 8) * 64]);
#pragma unroll
        for (int j = 0; j < BN / 32; ++j)
            GLD(Bb + (long)(j * 32 + srow) * K + kt, &Bs[buf][(j * 32 + w * 8) * 64]);
    };
    auto compute = [&](int buf) {
        const char* AsB = (const char*)As[buf];
        const char* BsB = (const char*)Bs[buf];
#pragma unroll
        for (int s = 0; s < 2; ++s) {
            bf16x8 af[MI], bfr[NI];
#pragma unroll
            for (int mi = 0; mi < MI; ++mi) {
                int r = wm * WMR + mi * 16 + (lane & 15);
                af[mi] = *(const bf16x8*)(AsB + r * 128 + ((s * 64 + (lane >> 4) * 16) ^ ((r & 7) << 4)));
            }
#pragma unroll
            for (int ni = 0; ni < NI; ++ni) {
                int r = wn * 64 + ni * 16 + (lane & 15);
                bfr[ni] = *(const bf16x8*)(BsB + r * 128 + ((s * 64 + (lane >> 4) * 16) ^ ((r & 7) << 4)));
            }
#pragma unroll
            for (int mi = 0; mi < MI; ++mi)
#pragma unroll
                for (int ni = 0; ni < NI; ++ni)
                    acc[mi][ni] = __builtin_amdgcn_mfma_f32_16x16x32_bf16(af[mi], bfr[ni], acc[mi][ni], 0, 0, 0);
        }
    };

    stage(0, 0);
    __syncthreads();                 // vmcnt(0) drain: buf0 ready
    int cur = 0;
    for (int kt = 64; kt < K; kt += 64) {
        stage(cur ^ 1, kt);          // issue next-tile loads BEFORE compute (latency hides under MFMA)
        compute(cur);
        __syncthreads();             // drains vmcnt: next buf ready; cur buf fully consumed
        cur ^= 1;
    }
    compute(cur);

    const int crow = (lane >> 4) * 4;
    const int ccol = lane & 15;
#pragma unroll
    for (int mi = 0; mi < MI; ++mi)
#pragma unroll
        for (int ni = 0; ni < NI; ++ni) {
            long r0 = rowA0 + wm * WMR + mi * 16 + crow;
            long c0 = rowB0 + wn * 64 + ni * 16 + ccol;
#pragma unroll
            for (int j = 0; j < 4; ++j) C[(r0 + j) * ldc + c0] = (OT)acc[mi][ni][j];
        }
}

// ---------------- causal conv1d (k=4) + bias + silu, bf16 in/out ----------------
__global__ void k_conv(const bf16* __restrict__ zx, const float* __restrict__ cw,
                       const float* __restrict__ cb, bf16* __restrict__ co) {
    int idx = blockIdx.x * 256 + threadIdx.x;   // ROWS * 224
    int c8 = idx % 224; int blt = idx / 224;
    int t = blt % SEQ;
    int c0 = c8 * 8;
    long bbase = (long)(blt - t) * NPAD;
    float cwa[8][4];
#pragma unroll
    for (int j = 0; j < 8; ++j) {
        float4 tv = *(const float4*)(cw + (c0 + j) * 4);
        cwa[j][0] = tv.x; cwa[j][1] = tv.y; cwa[j][2] = tv.z; cwa[j][3] = tv.w;
    }
    float acc[8];
#pragma unroll
    for (int j = 0; j < 8; ++j) acc[j] = cb[c0 + j];
#pragma unroll
    for (int k = 0; k < 4; ++k) {
        int tt = t + k - 3;
        if (tt >= 0) {
            bf16x8 v = *(const bf16x8*)(zx + bbase + (long)tt * NPAD + DINNER + c0);
#pragma unroll
            for (int j = 0; j < 8; ++j) acc[j] += (float)v[j] * cwa[j][k];
        }
    }
    bf16x8 o;
#pragma unroll
    for (int j = 0; j < 8; ++j) o[j] = (bf16)fsilu(acc[j]);
    *(bf16x8*)(co + (long)blt * CONVDIM + c0) = o;
}

// ---------------- dt = softplus(raw + bias) ----------------
__global__ void k_dt(const bf16* __restrict__ zx, const float* __restrict__ dtb,
                     float* __restrict__ dt) {
    int idx = blockIdx.x * 256 + threadIdx.x;
    int hh = idx % NHEADS; int bl = idx / NHEADS;
    float v = (float)zx[(long)bl * NPAD + DINNER + CONVDIM + hh] + dtb[hh];
    dt[idx] = (v > 15.f) ? v : log1pf(__expf(v));
}

// ---------------- per-chunk prep ----------------
__global__ __launch_bounds__(128) void k_prep(const bf16* __restrict__ cobf, const float* __restrict__ dtb,
                                              const float* __restrict__ Alog,
                                              float* __restrict__ Sarr, float* __restrict__ dtc,
                                              float* __restrict__ Pcb,
                                              bf16* __restrict__ XT, bf16* __restrict__ XwT,
                                              bf16* __restrict__ BT) {
    int blk = blockIdx.x;
    int b = blk / (NHEADS * NCH);
    int r = blk % (NHEADS * NCH);
    int h = r / NCH;
    int c = r % NCH;
    int tid = threadIdx.x;
    __shared__ float S_lds[128], dt_lds[128], wl_lds[128], wtot[2];
    __shared__ bf16 Xs[128][64];
    long grow = (long)(b * SEQ + c * QCH + tid);
    float dtv = dtb[grow * NHEADS + h];
    float Ah = -__expf(Alog[h]);
    float ps = dtv * Ah;
#pragma unroll
    for (int off = 1; off < 64; off <<= 1) {
        float o = __shfl_up(ps, off, 64);
        if ((tid & 63) >= off) ps += o;
    }
    if ((tid & 63) == 63) wtot[tid >> 6] = ps;
    __syncthreads();
    if (tid >= 64) ps += wtot[0];
    S_lds[tid] = ps; dt_lds[tid] = dtv;
    __syncthreads();
    float Sl = S_lds[127];
    wl_lds[tid] = __expf(Sl - ps) * dtv;
    Sarr[blk * QCH + tid] = ps;
    dtc[blk * QCH + tid] = dtv;
    if (tid == 127) Pcb[blk] = __expf(Sl);
    const bf16* xrow = cobf + grow * CONVDIM + h * HEADDIM;
#pragma unroll
    for (int j = 0; j < 8; ++j) *(bf16x8*)&Xs[tid][j * 8] = *(const bf16x8*)(xrow + j * 8);
    __syncthreads();
    int p = tid >> 1, hf = tid & 1;
    char* xtb = (char*)XT + (((long)blk) << 14);
    char* xwb = (char*)XwT + (((long)blk) << 14);
#pragma unroll
    for (int ub = 0; ub < 8; ++ub) {
        int u0 = hf * 64 + ub * 8;
        bf16x8 vx, vw;
#pragma unroll
        for (int k = 0; k < 8; ++k) {
            int u = u0 + k;
            bf16 xv = Xs[u][p];
            vx[k] = xv;
            vw[k] = (bf16)((float)xv * wl_lds[u]);
        }
        long off = (long)((p * 256 + u0 * 2) ^ ((p & 7) << 4));
        *(bf16x8*)(xtb + off) = vx;
        *(bf16x8*)(xwb + off) = vw;
    }
    if (h == 0) {
        char* btb = (char*)BT + (((long)(b * NCH + c)) << 15);
        const bf16* brow = cobf + (long)(b * SEQ + c * QCH + tid) * CONVDIM + DINNER;
        int nl = tid >> 1;
        for (int nb = 0; nb < 2; ++nb) {
            __syncthreads();
#pragma unroll
            for (int j = 0; j < 8; ++j) *(bf16x8*)&Xs[tid][j * 8] = *(const bf16x8*)(brow + nb * 64 + j * 8);
            __syncthreads();
            int n = nb * 64 + nl;
#pragma unroll
            for (int ub = 0; ub < 8; ++ub) {
                int u0 = hf * 64 + ub * 8;
                bf16x8 v;
#pragma unroll
                for (int k = 0; k < 8; ++k) v[k] = Xs[u0 + k][nl];
                long off = (long)((n * 256 + u0 * 2) ^ ((n & 7) << 4));
                *(bf16x8*)(btb + off) = v;
            }
        }
    }
}

// ---------------- chunk-local final state via MFMA ----------------
__global__ __launch_bounds__(256) void k_stateL(const bf16* __restrict__ XwT, const bf16* __restrict__ BT,
                                                bf16* __restrict__ Lbuf) {
    __shared__ bf16 Xs[64 * 128];
    __shared__ bf16 Bs[128 * 128];
    int blk = blockIdx.x;
    int b = blk / (NHEADS * NCH);
    int r = blk % (NHEADS * NCH);
    int c = r % NCH;
    int bc = b * NCH + c;
    int tid = threadIdx.x, lane = tid & 63, wid = tid >> 6;
    const char* xw = (const char*)XwT + (((long)blk) << 14);
    const char* bt = (const char*)BT + (((long)bc) << 15);
#pragma unroll
    for (int i = 0; i < 4; ++i)
        GLD(xw + (long)(i * 256 + tid) * 16, (char*)Xs + (i * 256 + wid * 64) * 16);
#pragma unroll
    for (int i = 0; i < 8; ++i)
        GLD(bt + (long)(i * 256 + tid) * 16, (char*)Bs + (i * 256 + wid * 64) * 16);
    __syncthreads();
    f32x4 acc[4][2];
    const f32x4 vz = {0.f, 0.f, 0.f, 0.f};
#pragma unroll
    for (int mi = 0; mi < 4; ++mi)
#pragma unroll
        for (int ni = 0; ni < 2; ++ni) acc[mi][ni] = vz;
    const char* XsB = (const char*)Xs;
    const char* BsB = (const char*)Bs;
#pragma unroll
    for (int ks = 0; ks < 4; ++ks) {
        bf16x8 af[4], bfr[2];
#pragma unroll
        for (int mi = 0; mi < 4; ++mi) {
            int pp = mi * 16 + (lane & 15);
            af[mi] = *(const bf16x8*)(XsB + ((pp * 256 + ks * 64 + (lane >> 4) * 16) ^ ((pp & 7) << 4)));
        }
#pragma unroll
        for (int ni = 0; ni < 2; ++ni) {
            int n = wid * 32 + ni * 16 + (lane & 15);
            bfr[ni] = *(const bf16x8*)(BsB + ((n * 256 + ks * 64 + (lane >> 4) * 16) ^ ((n & 7) << 4)));
        }
#pragma unroll
        for (int mi = 0; mi < 4; ++mi)
#pragma unroll
            for (int ni = 0; ni < 2; ++ni)
                acc[mi][ni] = __builtin_amdgcn_mfma_f32_16x16x32_bf16(af[mi], bfr[ni], acc[mi][ni], 0, 0, 0);
    }
    char* lb = (char*)Lbuf + (((long)blk) << 14);
#pragma unroll
    for (int mi = 0; mi < 4; ++mi)
#pragma unroll
        for (int ni = 0; ni < 2; ++ni)
#pragma unroll
            for (int j = 0; j < 4; ++j) {
                int pp = mi * 16 + (lane >> 4) * 4 + j;
                int n = wid * 32 + ni * 16 + (lane & 15);
                *(bf16*)(lb + ((pp * 256 + n * 2) ^ ((pp & 7) << 4))) = (bf16)acc[mi][ni][j];
            }
}

// ---------------- Pass B: sequential inter-chunk combine ----------------
__global__ __launch_bounds__(256) void k_scanB(bf16* __restrict__ Lbuf, const float* __restrict__ Pc) {
    int bh = blockIdx.x >> 2;
    int q = blockIdx.x & 3;
    int off = (q * 256 + threadIdx.x) * 8;
    long base = ((long)bh * NCH) << 13;
    float s[8] = {0.f};
#pragma unroll
    for (int c = 0; c < NCH; ++c) {
        bf16* p = Lbuf + base + ((long)c << 13) + off;
        bf16x8 L = *(bf16x8*)p;
        bf16x8 I;
#pragma unroll
        for (int k = 0; k < 8; ++k) I[k] = (bf16)s[k];
        float P = Pc[bh * NCH + c];
#pragma unroll
        for (int k = 0; k < 8; ++k) s[k] = P * s[k] + (float)L[k];
        *(bf16x8*)p = I;
    }
}

// ---------------- chunk Y via MFMA ----------------
__global__ __launch_bounds__(512) void k_chunkY(const bf16* __restrict__ cobf,
                                                const float* __restrict__ Sarr, const float* __restrict__ dtc,
                                                const float* __restrict__ Dp,
                                                const bf16* __restrict__ XT, const bf16* __restrict__ Lbuf,
                                                float* __restrict__ ysb) {
    __shared__ bf16 Cs[128 * 128];
    __shared__ bf16 Bs[128 * 128];
    __shared__ bf16 Xts[64 * 128];
    __shared__ bf16 Is[64 * 128];
    __shared__ float S_lds[128], dt_lds[128];
    int blk = blockIdx.x;
    int b = blk / (NHEADS * NCH);
    int r = blk % (NHEADS * NCH);
    int h = r / NCH;
    int c = r % NCH;
    int tid = threadIdx.x, lane = tid & 63, wid = tid >> 6;
    long brow0 = (long)b * SEQ + c * QCH;
    const char* cob = (const char*)cobf;
#pragma unroll
    for (int i = 0; i < 4; ++i) {
        int trow = i * 32 + wid * 4 + (lane >> 4);
        int blk16 = lane & 15;
        const char* rp = cob + (brow0 + trow) * (CONVDIM * 2);
        int sb = (blk16 ^ (trow & 7)) << 4;
        GLD(rp + (DINNER + DSTATE) * 2 + sb, (char*)Cs + (i * 32 + wid * 4) * 256);
        GLD(rp + DINNER * 2 + sb, (char*)Bs + (i * 32 + wid * 4) * 256);
    }
    const char* xt = (const char*)XT + (((long)blk) << 14);
    const char* ib = (const char*)Lbuf + (((long)blk) << 14);
#pragma unroll
    for (int i = 0; i < 2; ++i) {
        GLD(xt + (long)(i * 512 + tid) * 16, (char*)Xts + (i * 512 + wid * 64) * 16);
        GLD(ib + (long)(i * 512 + tid) * 16, (char*)Is + (i * 512 + wid * 64) * 16);
    }
    if (tid < 128) { S_lds[tid] = Sarr[blk * QCH + tid]; dt_lds[tid] = dtc[blk * QCH + tid]; }
    float Dh = Dp[h];
    __syncthreads();
    const char* CsB = (const char*)Cs;
    char* BsB = (char*)Bs;
    const char* IsB = (const char*)Is;
    const char* XtB = (const char*)Xts;
    const f32x4 vz = {0.f, 0.f, 0.f, 0.f};
    int wmG = wid >> 2, wnG = wid & 3;
    f32x4 accg[4][2];
#pragma unroll
    for (int mi = 0; mi < 4; ++mi)
#pragma unroll
        for (int ni = 0; ni < 2; ++ni) accg[mi][ni] = vz;
#pragma unroll
    for (int ks = 0; ks < 4; ++ks) {
        bf16x8 af[4], bfr[2];
#pragma unroll
        for (int mi = 0; mi < 4; ++mi) {
            int t = wmG * 64 + mi * 16 + (lane & 15);
            af[mi] = *(const bf16x8*)(CsB + ((t * 256 + ks * 64 + (lane >> 4) * 16) ^ ((t & 7) << 4)));
        }
#pragma unroll
        for (int ni = 0; ni < 2; ++ni) {
            int u = wnG * 32 + ni * 16 + (lane & 15);
            bfr[ni] = *(const bf16x8*)(BsB + ((u * 256 + ks * 64 + (lane >> 4) * 16) ^ ((u & 7) << 4)));
        }
#pragma unroll
        for (int mi = 0; mi < 4; ++mi)
#pragma unroll
            for (int ni = 0; ni < 2; ++ni)
                accg[mi][ni] = __builtin_amdgcn_mfma_f32_16x16x32_bf16(af[mi], bfr[ni], accg[mi][ni], 0, 0, 0);
    }
    __syncthreads();
#pragma unroll
    for (int mi = 0; mi < 4; ++mi) {
#pragma unroll
        for (int j = 0; j < 4; ++j) {
            int t = wmG * 64 + mi * 16 + (lane >> 4) * 4 + j;
            float St = S_lds[t];
#pragma unroll
            for (int ni = 0; ni < 2; ++ni) {
                int u = wnG * 32 + ni * 16 + (lane & 15);
                float v = 0.f;
                if (u <= t) v = accg[mi][ni][j] * __expf(St - S_lds[u]) * dt_lds[u];
                *(bf16*)(BsB + ((t * 256 + u * 2) ^ ((t & 7) << 4))) = (bf16)v;
            }
        }
    }
    __syncthreads();
    int wmY = wid >> 1, wnY = wid & 1;
    f32x4 accy[2][2];
#pragma unroll
    for (int mi = 0; mi < 2; ++mi)
#pragma unroll
        for (int ni = 0; ni < 2; ++ni) accy[mi][ni] = vz;
#pragma unroll
    for (int ks = 0; ks < 4; ++ks) {
        bf16x8 af[2], bfr[2];
#pragma unroll
        for (int mi = 0; mi < 2; ++mi) {
            int t = wmY * 32 + mi * 16 + (lane & 15);
            af[mi] = *(const bf16x8*)(CsB + ((t * 256 + ks * 64 + (lane >> 4) * 16) ^ ((t & 7) << 4)));
        }
#pragma unroll
        for (int ni = 0; ni < 2; ++ni) {
            int pp = wnY * 32 + ni * 16 + (lane & 15);
            bfr[ni] = *(const bf16x8*)(IsB + ((pp * 256 + ks * 64 + (lane >> 4) * 16) ^ ((pp & 7) << 4)));
        }
#pragma unroll
        for (int mi = 0; mi < 2; ++mi)
#pragma unroll
            for (int ni = 0; ni < 2; ++ni)
                accy[mi][ni] = __builtin_amdgcn_mfma_f32_16x16x32_bf16(af[mi], bfr[ni], accy[mi][ni], 0, 0, 0);
    }
#pragma unroll
    for (int mi = 0; mi < 2; ++mi)
#pragma unroll
        for (int j = 0; j < 4; ++j) {
            int t = wmY * 32 + mi * 16 + (lane >> 4) * 4 + j;
            float e = __expf(S_lds[t]);
#pragma unroll
            for (int ni = 0; ni < 2; ++ni) accy[mi][ni][j] *= e;
        }
#pragma unroll
    for (int ks = 0; ks < 4; ++ks) {
        bf16x8 af[2], bfr[2];
#pragma unroll
        for (int mi = 0; mi < 2; ++mi) {
            int t = wmY * 32 + mi * 16 + (lane & 15);
            af[mi] = *(const bf16x8*)(BsB + ((t * 256 + ks * 64 + (lane >> 4) * 16) ^ ((t & 7) << 4)));
        }
#pragma unroll
        for (int ni = 0; ni < 2; ++ni) {
            int pp = wnY * 32 + ni * 16 + (lane & 15);
            bfr[ni] = *(const bf16x8*)(XtB + ((pp * 256 + ks * 64 + (lane >> 4) * 16) ^ ((pp & 7) << 4)));
        }
#pragma unroll
        for (int mi = 0; mi < 2; ++mi)
#pragma unroll
            for (int ni = 0; ni < 2; ++ni)
                accy[mi][ni] = __builtin_amdgcn_mfma_f32_16x16x32_bf16(af[mi], bfr[ni], accy[mi][ni], 0, 0, 0);
    }
#pragma unroll
    for (int mi = 0; mi < 2; ++mi)
#pragma unroll
        for (int ni = 0; ni < 2; ++ni)
#pragma unroll
            for (int j = 0; j < 4; ++j) {
                int t = wmY * 32 + mi * 16 + (lane >> 4) * 4 + j;
                int pp = wnY * 32 + ni * 16 + (lane & 15);
                float xv = (float)*(const bf16*)(XtB + ((pp * 256 + t * 2) ^ ((pp & 7) << 4)));
                ysb[(brow0 + t) * DINNER + h * HEADDIM + pp] = accy[mi][ni][j] + Dh * xv;
            }
}

// ---------------- gated rmsnorm ----------------
__global__ __launch_bounds__(256) void k_gated(const float* __restrict__ ys, const bf16* __restrict__ zx,
                                               const float* __restrict__ w, bf16* __restrict__ out) {
    __shared__ float sm[4];
    int r = blockIdx.x, tid = threadIdx.x;
    float v[6]; float ss = 0.f;
#pragma unroll
    for (int k = 0; k < 6; ++k) {
        int d = tid + k * 256;
        float z = (float)zx[(long)r * NPAD + d];
        float t = ys[(long)r * DINNER + d] * fsilu(z);
        v[k] = t; ss += t * t;
    }
#pragma unroll
    for (int off = 32; off; off >>= 1) ss += __shfl_down(ss, off, 64);
    if ((tid & 63) == 0) sm[tid >> 6] = ss;
    __syncthreads();
    float tot = sm[0] + sm[1] + sm[2] + sm[3];
    float sc = rsqrtf(tot / (float)DINNER + EPS);
#pragma unroll
    for (int k = 0; k < 6; ++k) {
        int d = tid + k * 256;
        out[(long)r * DINNER + d] = (bf16)(v[k] * sc * w[d]);
    }
}

// ---------------- head: 32 rows/block, 1 atomic/block ----------------
__global__ __launch_bounds__(256) void k_head(const bf16* __restrict__ hn, const float* __restrict__ Wh,
                                              const float* __restrict__ y, float* __restrict__ out,
                                              float* __restrict__ loss) {
    __shared__ float sl[4];
    int tid = threadIdx.x, lane = tid & 63, wid = tid >> 6;
    float wv[5][12];
#pragma unroll
    for (int o = 0; o < 5; ++o)
#pragma unroll
        for (int j = 0; j < 12; ++j) wv[o][j] = Wh[o * DMODEL + lane * 12 + j];
    float lsum = 0.f;
#pragma unroll
    for (int rr = 0; rr < 8; ++rr) {
        long r = (long)blockIdx.x * 32 + wid * 8 + rr;
        const bf16* hp = hn + r * DMODEL + lane * 12;
        float hv[12];
#pragma unroll
        for (int q = 0; q < 3; ++q) {
            bf16x4 v4 = *(const bf16x4*)(hp + q * 4);
#pragma unroll
            for (int j = 0; j < 4; ++j) hv[q * 4 + j] = (float)v4[j];
        }
        float acc[5];
#pragma unroll
        for (int o = 0; o < 5; ++o) {
            float a = 0.f;
#pragma unroll
            for (int j = 0; j < 12; ++j) a += hv[j] * wv[o][j];
            acc[o] = a;
        }
#pragma unroll
        for (int o = 0; o < 5; ++o)
#pragma unroll
            for (int m = 32; m; m >>= 1) acc[o] += __shfl_xor(acc[o], m, 64);
        if (lane == 0) {
#pragma unroll
            for (int o = 0; o < 5; ++o) {
                out[r * 5 + o] = acc[o];
                float d = acc[o] - y[r * 5 + o];
                lsum += d * d;
            }
        }
    }
    if (lane == 0) sl[wid] = lsum;
    __syncthreads();
    if (tid == 0) atomicAdd(loss, (sl[0] + sl[1] + sl[2] + sl[3]) * (1.f / ((float)ROWS * 5.f)));
}

extern "C" void kernel_launch(void* const* d_in, const int* in_sizes, int n_in,
                              void* d_out, int out_size, void* d_ws, size_t ws_size,
                              hipStream_t stream) {
    const float* x      = (const float*)d_in[0];
    const float* y      = (const float*)d_in[1];
    const float* W_emb  = (const float*)d_in[2];
    const float* b_emb  = (const float*)d_in[3];
    const float* W_in   = (const float*)d_in[4];
    const float* conv_w = (const float*)d_in[5];
    const float* conv_b = (const float*)d_in[6];
    const float* dt_bias= (const float*)d_in[7];
    const float* A_log  = (const float*)d_in[8];
    const float* Dp     = (const float*)d_in[9];
    const float* norm_w = (const float*)d_in[10];
    const float* W_out  = (const float*)d_in[11];
    const float* bnw    = (const float*)d_in[12];
    const float* nfw    = (const float*)d_in[13];
    const float* W_head = (const float*)d_in[14];

    char* ws = (char*)d_ws;
    float* hb   = (float*)ws;  ws += (size_t)ROWS * DMODEL * 4;
    float* res  = (float*)ws;  ws += (size_t)ROWS * DMODEL * 4;
    bf16*  hnb  = (bf16*)ws;   ws += (size_t)ROWS * DMODEL * 2;
    bf16*  zx   = (bf16*)ws;   ws += (size_t)ROWS * NPAD * 2;
    bf16*  cobf = (bf16*)ws;   ws += (size_t)ROWS * CONVDIM * 2;
    float* dtb  = (float*)ws;  ws += (size_t)ROWS * NHEADS * 4;
    float* ysb  = (float*)ws;  ws += (size_t)ROWS * DINNER * 4;
    bf16*  yfb  = (bf16*)ws;   ws += (size_t)ROWS * DINNER * 2;
    bf16*  Wib  = (bf16*)ws;   ws += (size_t)NLAYER * NPAD * DMODEL * 2;
    bf16*  Wob  = (bf16*)ws;   ws += (size_t)NLAYER * DMODEL * DINNER * 2;
    float* Pcb  = (float*)ws;  ws += (size_t)BATCH * NHEADS * NCH * 4;
    float* Sarr = (float*)ws;  ws += (size_t)BATCH * NHEADS * NCH * QCH * 4;
    float* dtc  = (float*)ws;  ws += (size_t)BATCH * NHEADS * NCH * QCH * 4;
    bf16*  XT   = (bf16*)ws;   ws += (size_t)BATCH * NHEADS * NCH * 8192 * 2;
    bf16*  BT   = (bf16*)ws;   ws += (size_t)BATCH * NCH * 16384 * 2;

    bf16* Lbuf = (bf16*)hb;   // alias, dead window between add_rmsnorm and out-proj
    bf16* XwT  = (bf16*)yfb;  // alias, dead window between out-proj and k_gated

    float* out_p  = (float*)d_out;
    float* loss_p = out_p + (size_t)ROWS * 5;

    hipMemsetAsync(loss_p, 0, 4, stream);
    k_embed<<<ROWS * DMODEL / 256, 256, 0, stream>>>(x, W_emb, b_emb, hb, res);
    k_cvt_in<<<NLAYER * NPAD * DMODEL / 256, 256, 0, stream>>>(W_in, Wib);
    k_cvt_out<<<NLAYER * DMODEL * DINNER / 256, 256, 0, stream>>>(W_out, Wob);

    const int NBHC = BATCH * NHEADS * NCH;   // 1536
    for (int l = 0; l < NLAYER; ++l) {
        k_add_rmsnorm<<<ROWS, 256, 0, stream>>>(hb, res, bnw + l * DMODEL, hnb);
        dim3 g1(ROWS / 128, NPAD / 128);
        k_gemm<bf16, 128><<<g1, 256, 0, stream>>>(hnb, Wib + (size_t)l * NPAD * DMODEL, zx, DMODEL, NPAD);
        k_conv<<<ROWS * 224 / 256, 256, 0, stream>>>(zx, conv_w + (size_t)l * CONVDIM * 4, conv_b + l * CONVDIM, cobf);
        k_dt<<<ROWS * NHEADS / 256, 256, 0, stream>>>(zx, dt_bias + l * NHEADS, dtb);
        k_prep<<<NBHC, 128, 0, stream>>>(cobf, dtb, A_log + l * NHEADS, Sarr, dtc, Pcb, XT, XwT, BT);
        k_stateL<<<NBHC, 256, 0, stream>>>(XwT, BT, Lbuf);
        k_scanB<<<BATCH * NHEADS * 4, 256, 0, stream>>>(Lbuf, Pcb);
        k_chunkY<<<NBHC, 512, 0, stream>>>(cobf, Sarr, dtc, Dp + l * NHEADS, XT, Lbuf, ysb);
        k_gated<<<ROWS, 256, 0, stream>>>(ysb, zx, norm_w + l * DINNER, yfb);
        dim3 g2(ROWS / 128, DMODEL / 64);
        k_gemm<float, 64><<<g2, 256, 0, stream>>>(yfb, Wob + (size_t)l * DMODEL * DINNER, hb, DINNER, DMODEL);
    }

    k_add_rmsnorm<<<ROWS, 256, 0, stream>>>(hb, res, nfw, hnb);
    k_head<<<256, 256, 0, stream>>>(hnb, W_head, y, out_p, loss_p);
}

// Round 6
// 2462.108 us; speedup vs baseline: 4.7198x; 1.0247x over previous
//
#include <hip/hip_runtime.h>
#include <hip/hip_bf16.h>
#include <math.h>

#define BATCH 4
#define SEQ 2048
#define DMODEL 768
#define NLAYER 8
#define DINNER 1536
#define HEADDIM 64
#define NHEADS 24
#define DSTATE 128
#define CONVDIM 1792
#define DINPROJ 3352
#define NPAD 3456
#define ROWS (BATCH*SEQ)
#define EPS 1e-5f
#define QCH 128
#define NCH (SEQ/QCH)

typedef __bf16 bf16;
typedef bf16 bf16x8 __attribute__((ext_vector_type(8)));
typedef bf16 bf16x4 __attribute__((ext_vector_type(4)));
typedef float f32x4 __attribute__((ext_vector_type(4)));

#define GLD(src, dst) __builtin_amdgcn_global_load_lds( \
    (const __attribute__((address_space(1))) void*)(src), \
    (__attribute__((address_space(3))) void*)(dst), 16, 0, 0)

__device__ __forceinline__ void bar_sync() {
    asm volatile("" ::: "memory");
    __builtin_amdgcn_s_barrier();
    asm volatile("" ::: "memory");
}

__device__ __forceinline__ float fsilu(float x) { return x / (1.f + __expf(-x)); }

// ---------------- embed ----------------
__global__ void k_embed(const float* __restrict__ x, const float* __restrict__ We,
                        const float* __restrict__ be, float* __restrict__ h,
                        float* __restrict__ res) {
    int idx = blockIdx.x * 256 + threadIdx.x;
    int d = idx % DMODEL; int bl = idx / DMODEL;
    float acc = be[d];
#pragma unroll
    for (int i = 0; i < 6; ++i) acc += x[bl * 6 + i] * We[d * 6 + i];
    h[idx] = acc;
    res[idx] = 0.f;
}

// ---------------- fused residual add + rmsnorm -> bf16 ----------------
__global__ __launch_bounds__(256) void k_add_rmsnorm(const float* __restrict__ hin,
                                                     float* __restrict__ res,
                                                     const float* __restrict__ w,
                                                     bf16* __restrict__ out) {
    __shared__ float sm[4];
    int r = blockIdx.x, tid = threadIdx.x;
    float v[3]; float ss = 0.f;
#pragma unroll
    for (int k = 0; k < 3; ++k) {
        int d = tid + k * 256;
        float t = res[r * DMODEL + d] + hin[r * DMODEL + d];
        res[r * DMODEL + d] = t; v[k] = t; ss += t * t;
    }
#pragma unroll
    for (int off = 32; off; off >>= 1) ss += __shfl_down(ss, off, 64);
    if ((tid & 63) == 0) sm[tid >> 6] = ss;
    __syncthreads();
    float tot = sm[0] + sm[1] + sm[2] + sm[3];
    float sc = rsqrtf(tot / (float)DMODEL + EPS);
#pragma unroll
    for (int k = 0; k < 3; ++k) {
        int d = tid + k * 256;
        out[r * DMODEL + d] = (bf16)(v[k] * sc * w[d]);
    }
}

// ---------------- batched weight conversions ----------------
__global__ void k_cvt_in(const float* __restrict__ src, bf16* __restrict__ dst) {
    int idx = blockIdx.x * 256 + threadIdx.x;
    int l = idx / (NPAD * DMODEL);
    int rem = idx % (NPAD * DMODEL);
    int n = rem / DMODEL;
    int d = rem % DMODEL;
    dst[idx] = (n < DINPROJ) ? (bf16)src[(long)l * DINPROJ * DMODEL + n * DMODEL + d] : (bf16)0.f;
}
__global__ void k_cvt_out(const float* __restrict__ src, bf16* __restrict__ dst) {
    int idx = blockIdx.x * 256 + threadIdx.x;
    dst[idx] = (bf16)src[idx];
}

// ---------------- bf16 MFMA GEMM: C[M,N] = A[M,K] @ B[N,K]^T ----------------
// BMxBN tile, BK=64, 2*BM/64... threads = BM*2. Double-buffered, counted-vmcnt
// raw-barrier pipeline (never drains to 0 in main loop), XOR-swizzled LDS.
template <typename OT, int BM, int BN>
__global__ __launch_bounds__(BM * 2) void k_gemm(const bf16* __restrict__ A, const bf16* __restrict__ B,
                                                 OT* __restrict__ C, int K, int ldc) {
    constexpr int NW  = BM / 32;         // waves (8 for 256, 4 for 128)
    constexpr int nWn = BN / 64;         // 2 or 1
    constexpr int nWm = NW / nWn;        // 4
    constexpr int WMR = BM / nWm;        // 64 or 32
    constexpr int MI  = WMR / 16;        // 4 or 2
    constexpr int NI  = 4;               // 64/16
    constexpr int RG  = BM / 4;          // rows per GLD
    constexpr int BG  = (4 * BN) / BM;   // B GLD count (=2)
    __shared__ bf16 As[2][BM * 64];
    __shared__ bf16 Bs[2][BN * 64];
    const int tid = threadIdx.x;
    const int lane = tid & 63;
    const int w = tid >> 6;
    const int wm = w / nWn, wn = w % nWn;
    const long rowA0 = (long)blockIdx.x * BM;
    const long rowB0 = (long)blockIdx.y * BN;
    const int srow = tid >> 3;                          // 0..BM/4-1
    const int scol = ((tid & 7) ^ (srow & 7)) * 8;      // pre-swizzled k-offset (T2 source side)
    const bf16* Ab = A + rowA0 * K + scol;
    const bf16* Bb = B + rowB0 * K + scol;

    f32x4 acc[MI][NI];
    const f32x4 vz = {0.f, 0.f, 0.f, 0.f};
#pragma unroll
    for (int mi = 0; mi < MI; ++mi)
#pragma unroll
        for (int ni = 0; ni < NI; ++ni) acc[mi][ni] = vz;

    auto stage = [&](int buf, int kt) {
#pragma unroll
        for (int j = 0; j < 4; ++j)
            GLD(Ab + (long)(j * RG + srow) * K + kt, &As[buf][(j * RG + w * 8) * 64]);
#pragma unroll
        for (int j = 0; j < BG; ++j)
            GLD(Bb + (long)(j * RG + srow) * K + kt, &Bs[buf][(j * RG + w * 8) * 64]);
    };
    auto compute = [&](int buf) {
        const char* AsB = (const char*)As[buf];
        const char* BsB = (const char*)Bs[buf];
#pragma unroll
        for (int s = 0; s < 2; ++s) {
            bf16x8 af[MI], bfr[NI];
#pragma unroll
            for (int mi = 0; mi < MI; ++mi) {
                int r = wm * WMR + mi * 16 + (lane & 15);
                af[mi] = *(const bf16x8*)(AsB + r * 128 + ((s * 64 + (lane >> 4) * 16) ^ ((r & 7) << 4)));
            }
#pragma unroll
            for (int ni = 0; ni < NI; ++ni) {
                int r = wn * 64 + ni * 16 + (lane & 15);
                bfr[ni] = *(const bf16x8*)(BsB + r * 128 + ((s * 64 + (lane >> 4) * 16) ^ ((r & 7) << 4)));
            }
#pragma unroll
            for (int mi = 0; mi < MI; ++mi)
#pragma unroll
                for (int ni = 0; ni < NI; ++ni)
                    acc[mi][ni] = __builtin_amdgcn_mfma_f32_16x16x32_bf16(af[mi], bfr[ni], acc[mi][ni], 0, 0, 0);
        }
    };

    // prologue: 2 tiles in flight; loop waits tile i with vmcnt(6) (tile i+1's
    // 6 loads stay outstanding), stages tile i+2 after the consume barrier.
    stage(0, 0);
    stage(1, 64);
    int cur = 0;
    for (int kt = 128; kt < K; kt += 64) {
        asm volatile("s_waitcnt vmcnt(6)" ::: "memory");
        bar_sync();                  // buf[cur] ready for all waves
        compute(cur);
        bar_sync();                  // all waves done reading buf[cur]
        stage(cur, kt);              // refill with tile kt (waited 2 iters later)
        cur ^= 1;
    }
    asm volatile("s_waitcnt vmcnt(6)" ::: "memory");
    bar_sync();
    compute(cur);
    asm volatile("s_waitcnt vmcnt(0)" ::: "memory");
    bar_sync();
    compute(cur ^ 1);

    const int crow = (lane >> 4) * 4;
    const int ccol = lane & 15;
#pragma unroll
    for (int mi = 0; mi < MI; ++mi)
#pragma unroll
        for (int ni = 0; ni < NI; ++ni) {
            long r0 = rowA0 + wm * WMR + mi * 16 + crow;
            long c0 = rowB0 + wn * 64 + ni * 16 + ccol;
#pragma unroll
            for (int j = 0; j < 4; ++j) C[(r0 + j) * ldc + c0] = (OT)acc[mi][ni][j];
        }
}

// ---------------- causal conv1d (k=4) + bias + silu, bf16 in/out ----------------
__global__ void k_conv(const bf16* __restrict__ zx, const float* __restrict__ cw,
                       const float* __restrict__ cb, bf16* __restrict__ co) {
    int idx = blockIdx.x * 256 + threadIdx.x;   // ROWS * 224
    int c8 = idx % 224; int blt = idx / 224;
    int t = blt % SEQ;
    int c0 = c8 * 8;
    long bbase = (long)(blt - t) * NPAD;
    float cwa[8][4];
#pragma unroll
    for (int j = 0; j < 8; ++j) {
        float4 tv = *(const float4*)(cw + (c0 + j) * 4);
        cwa[j][0] = tv.x; cwa[j][1] = tv.y; cwa[j][2] = tv.z; cwa[j][3] = tv.w;
    }
    float acc[8];
#pragma unroll
    for (int j = 0; j < 8; ++j) acc[j] = cb[c0 + j];
#pragma unroll
    for (int k = 0; k < 4; ++k) {
        int tt = t + k - 3;
        if (tt >= 0) {
            bf16x8 v = *(const bf16x8*)(zx + bbase + (long)tt * NPAD + DINNER + c0);
#pragma unroll
            for (int j = 0; j < 8; ++j) acc[j] += (float)v[j] * cwa[j][k];
        }
    }
    bf16x8 o;
#pragma unroll
    for (int j = 0; j < 8; ++j) o[j] = (bf16)fsilu(acc[j]);
    *(bf16x8*)(co + (long)blt * CONVDIM + c0) = o;
}

// ---------------- per-chunk prep (dt softplus folded in) ----------------
__global__ __launch_bounds__(128) void k_prep(const bf16* __restrict__ cobf, const bf16* __restrict__ zx,
                                              const float* __restrict__ dt_bias_l,
                                              const float* __restrict__ Alog,
                                              float* __restrict__ Sarr, float* __restrict__ dtc,
                                              float* __restrict__ Pcb,
                                              bf16* __restrict__ XT, bf16* __restrict__ XwT,
                                              bf16* __restrict__ BT) {
    int blk = blockIdx.x;
    int b = blk / (NHEADS * NCH);
    int r = blk % (NHEADS * NCH);
    int h = r / NCH;
    int c = r % NCH;
    int tid = threadIdx.x;
    __shared__ float S_lds[128], dt_lds[128], wl_lds[128], wtot[2];
    __shared__ bf16 Xs[128][64];
    long grow = (long)(b * SEQ + c * QCH + tid);
    float raw = (float)zx[grow * NPAD + DINNER + CONVDIM + h] + dt_bias_l[h];
    float dtv = (raw > 15.f) ? raw : log1pf(__expf(raw));
    float Ah = -__expf(Alog[h]);
    float ps = dtv * Ah;
#pragma unroll
    for (int off = 1; off < 64; off <<= 1) {
        float o = __shfl_up(ps, off, 64);
        if ((tid & 63) >= off) ps += o;
    }
    if ((tid & 63) == 63) wtot[tid >> 6] = ps;
    __syncthreads();
    if (tid >= 64) ps += wtot[0];
    S_lds[tid] = ps; dt_lds[tid] = dtv;
    __syncthreads();
    float Sl = S_lds[127];
    wl_lds[tid] = __expf(Sl - ps) * dtv;
    Sarr[blk * QCH + tid] = ps;
    dtc[blk * QCH + tid] = dtv;
    if (tid == 127) Pcb[blk] = __expf(Sl);
    const bf16* xrow = cobf + grow * CONVDIM + h * HEADDIM;
#pragma unroll
    for (int j = 0; j < 8; ++j) *(bf16x8*)&Xs[tid][j * 8] = *(const bf16x8*)(xrow + j * 8);
    __syncthreads();
    int p = tid >> 1, hf = tid & 1;
    char* xtb = (char*)XT + (((long)blk) << 14);
    char* xwb = (char*)XwT + (((long)blk) << 14);
#pragma unroll
    for (int ub = 0; ub < 8; ++ub) {
        int u0 = hf * 64 + ub * 8;
        bf16x8 vx, vw;
#pragma unroll
        for (int k = 0; k < 8; ++k) {
            int u = u0 + k;
            bf16 xv = Xs[u][p];
            vx[k] = xv;
            vw[k] = (bf16)((float)xv * wl_lds[u]);
        }
        long off = (long)((p * 256 + u0 * 2) ^ ((p & 7) << 4));
        *(bf16x8*)(xtb + off) = vx;
        *(bf16x8*)(xwb + off) = vw;
    }
    if (h == 0) {
        char* btb = (char*)BT + (((long)(b * NCH + c)) << 15);
        const bf16* brow = cobf + (long)(b * SEQ + c * QCH + tid) * CONVDIM + DINNER;
        int nl = tid >> 1;
        for (int nb = 0; nb < 2; ++nb) {
            __syncthreads();
#pragma unroll
            for (int j = 0; j < 8; ++j) *(bf16x8*)&Xs[tid][j * 8] = *(const bf16x8*)(brow + nb * 64 + j * 8);
            __syncthreads();
            int n = nb * 64 + nl;
#pragma unroll
            for (int ub = 0; ub < 8; ++ub) {
                int u0 = hf * 64 + ub * 8;
                bf16x8 v;
#pragma unroll
                for (int k = 0; k < 8; ++k) v[k] = Xs[u0 + k][nl];
                long off = (long)((n * 256 + u0 * 2) ^ ((n & 7) << 4));
                *(bf16x8*)(btb + off) = v;
            }
        }
    }
}

// ---------------- chunk-local final state via MFMA ----------------
__global__ __launch_bounds__(256) void k_stateL(const bf16* __restrict__ XwT, const bf16* __restrict__ BT,
                                                bf16* __restrict__ Lbuf) {
    __shared__ bf16 Xs[64 * 128];
    __shared__ bf16 Bs[128 * 128];
    int blk = blockIdx.x;
    int b = blk / (NHEADS * NCH);
    int r = blk % (NHEADS * NCH);
    int c = r % NCH;
    int bc = b * NCH + c;
    int tid = threadIdx.x, lane = tid & 63, wid = tid >> 6;
    const char* xw = (const char*)XwT + (((long)blk) << 14);
    const char* bt = (const char*)BT + (((long)bc) << 15);
#pragma unroll
    for (int i = 0; i < 4; ++i)
        GLD(xw + (long)(i * 256 + tid) * 16, (char*)Xs + (i * 256 + wid * 64) * 16);
#pragma unroll
    for (int i = 0; i < 8; ++i)
        GLD(bt + (long)(i * 256 + tid) * 16, (char*)Bs + (i * 256 + wid * 64) * 16);
    __syncthreads();
    f32x4 acc[4][2];
    const f32x4 vz = {0.f, 0.f, 0.f, 0.f};
#pragma unroll
    for (int mi = 0; mi < 4; ++mi)
#pragma unroll
        for (int ni = 0; ni < 2; ++ni) acc[mi][ni] = vz;
    const char* XsB = (const char*)Xs;
    const char* BsB = (const char*)Bs;
#pragma unroll
    for (int ks = 0; ks < 4; ++ks) {
        bf16x8 af[4], bfr[2];
#pragma unroll
        for (int mi = 0; mi < 4; ++mi) {
            int pp = mi * 16 + (lane & 15);
            af[mi] = *(const bf16x8*)(XsB + ((pp * 256 + ks * 64 + (lane >> 4) * 16) ^ ((pp & 7) << 4)));
        }
#pragma unroll
        for (int ni = 0; ni < 2; ++ni) {
            int n = wid * 32 + ni * 16 + (lane & 15);
            bfr[ni] = *(const bf16x8*)(BsB + ((n * 256 + ks * 64 + (lane >> 4) * 16) ^ ((n & 7) << 4)));
        }
#pragma unroll
        for (int mi = 0; mi < 4; ++mi)
#pragma unroll
            for (int ni = 0; ni < 2; ++ni)
                acc[mi][ni] = __builtin_amdgcn_mfma_f32_16x16x32_bf16(af[mi], bfr[ni], acc[mi][ni], 0, 0, 0);
    }
    char* lb = (char*)Lbuf + (((long)blk) << 14);
#pragma unroll
    for (int mi = 0; mi < 4; ++mi)
#pragma unroll
        for (int ni = 0; ni < 2; ++ni)
#pragma unroll
            for (int j = 0; j < 4; ++j) {
                int pp = mi * 16 + (lane >> 4) * 4 + j;
                int n = wid * 32 + ni * 16 + (lane & 15);
                *(bf16*)(lb + ((pp * 256 + n * 2) ^ ((pp & 7) << 4))) = (bf16)acc[mi][ni][j];
            }
}

// ---------------- Pass B: sequential inter-chunk combine ----------------
__global__ __launch_bounds__(256) void k_scanB(bf16* __restrict__ Lbuf, const float* __restrict__ Pc) {
    int bh = blockIdx.x >> 2;
    int q = blockIdx.x & 3;
    int off = (q * 256 + threadIdx.x) * 8;
    long base = ((long)bh * NCH) << 13;
    float s[8] = {0.f};
#pragma unroll
    for (int c = 0; c < NCH; ++c) {
        bf16* p = Lbuf + base + ((long)c << 13) + off;
        bf16x8 L = *(bf16x8*)p;
        bf16x8 I;
#pragma unroll
        for (int k = 0; k < 8; ++k) I[k] = (bf16)s[k];
        float P = Pc[bh * NCH + c];
#pragma unroll
        for (int k = 0; k < 8; ++k) s[k] = P * s[k] + (float)L[k];
        *(bf16x8*)p = I;
    }
}

// ---------------- chunk Y via MFMA ----------------
__global__ __launch_bounds__(512) void k_chunkY(const bf16* __restrict__ cobf,
                                                const float* __restrict__ Sarr, const float* __restrict__ dtc,
                                                const float* __restrict__ Dp,
                                                const bf16* __restrict__ XT, const bf16* __restrict__ Lbuf,
                                                float* __restrict__ ysb) {
    __shared__ bf16 Cs[128 * 128];
    __shared__ bf16 Bs[128 * 128];
    __shared__ bf16 Xts[64 * 128];
    __shared__ bf16 Is[64 * 128];
    __shared__ float S_lds[128], dt_lds[128];
    int blk = blockIdx.x;
    int b = blk / (NHEADS * NCH);
    int r = blk % (NHEADS * NCH);
    int h = r / NCH;
    int c = r % NCH;
    int tid = threadIdx.x, lane = tid & 63, wid = tid >> 6;
    long brow0 = (long)b * SEQ + c * QCH;
    const char* cob = (const char*)cobf;
#pragma unroll
    for (int i = 0; i < 4; ++i) {
        int trow = i * 32 + wid * 4 + (lane >> 4);
        int blk16 = lane & 15;
        const char* rp = cob + (brow0 + trow) * (CONVDIM * 2);
        int sb = (blk16 ^ (trow & 7)) << 4;
        GLD(rp + (DINNER + DSTATE) * 2 + sb, (char*)Cs + (i * 32 + wid * 4) * 256);
        GLD(rp + DINNER * 2 + sb, (char*)Bs + (i * 32 + wid * 4) * 256);
    }
    const char* xt = (const char*)XT + (((long)blk) << 14);
    const char* ib = (const char*)Lbuf + (((long)blk) << 14);
#pragma unroll
    for (int i = 0; i < 2; ++i) {
        GLD(xt + (long)(i * 512 + tid) * 16, (char*)Xts + (i * 512 + wid * 64) * 16);
        GLD(ib + (long)(i * 512 + tid) * 16, (char*)Is + (i * 512 + wid * 64) * 16);
    }
    if (tid < 128) { S_lds[tid] = Sarr[blk * QCH + tid]; dt_lds[tid] = dtc[blk * QCH + tid]; }
    float Dh = Dp[h];
    __syncthreads();
    const char* CsB = (const char*)Cs;
    char* BsB = (char*)Bs;
    const char* IsB = (const char*)Is;
    const char* XtB = (const char*)Xts;
    const f32x4 vz = {0.f, 0.f, 0.f, 0.f};
    int wmG = wid >> 2, wnG = wid & 3;
    f32x4 accg[4][2];
#pragma unroll
    for (int mi = 0; mi < 4; ++mi)
#pragma unroll
        for (int ni = 0; ni < 2; ++ni) accg[mi][ni] = vz;
#pragma unroll
    for (int ks = 0; ks < 4; ++ks) {
        bf16x8 af[4], bfr[2];
#pragma unroll
        for (int mi = 0; mi < 4; ++mi) {
            int t = wmG * 64 + mi * 16 + (lane & 15);
            af[mi] = *(const bf16x8*)(CsB + ((t * 256 + ks * 64 + (lane >> 4) * 16) ^ ((t & 7) << 4)));
        }
#pragma unroll
        for (int ni = 0; ni < 2; ++ni) {
            int u = wnG * 32 + ni * 16 + (lane & 15);
            bfr[ni] = *(const bf16x8*)(BsB + ((u * 256 + ks * 64 + (lane >> 4) * 16) ^ ((u & 7) << 4)));
        }
#pragma unroll
        for (int mi = 0; mi < 4; ++mi)
#pragma unroll
            for (int ni = 0; ni < 2; ++ni)
                accg[mi][ni] = __builtin_amdgcn_mfma_f32_16x16x32_bf16(af[mi], bfr[ni], accg[mi][ni], 0, 0, 0);
    }
    __syncthreads();
#pragma unroll
    for (int mi = 0; mi < 4; ++mi) {
#pragma unroll
        for (int j = 0; j < 4; ++j) {
            int t = wmG * 64 + mi * 16 + (lane >> 4) * 4 + j;
            float St = S_lds[t];
#pragma unroll
            for (int ni = 0; ni < 2; ++ni) {
                int u = wnG * 32 + ni * 16 + (lane & 15);
                float v = 0.f;
                if (u <= t) v = accg[mi][ni][j] * __expf(St - S_lds[u]) * dt_lds[u];
                *(bf16*)(BsB + ((t * 256 + u * 2) ^ ((t & 7) << 4))) = (bf16)v;
            }
        }
    }
    __syncthreads();
    int wmY = wid >> 1, wnY = wid & 1;
    f32x4 accy[2][2];
#pragma unroll
    for (int mi = 0; mi < 2; ++mi)
#pragma unroll
        for (int ni = 0; ni < 2; ++ni) accy[mi][ni] = vz;
#pragma unroll
    for (int ks = 0; ks < 4; ++ks) {
        bf16x8 af[2], bfr[2];
#pragma unroll
        for (int mi = 0; mi < 2; ++mi) {
            int t = wmY * 32 + mi * 16 + (lane & 15);
            af[mi] = *(const bf16x8*)(CsB + ((t * 256 + ks * 64 + (lane >> 4) * 16) ^ ((t & 7) << 4)));
        }
#pragma unroll
        for (int ni = 0; ni < 2; ++ni) {
            int pp = wnY * 32 + ni * 16 + (lane & 15);
            bfr[ni] = *(const bf16x8*)(IsB + ((pp * 256 + ks * 64 + (lane >> 4) * 16) ^ ((pp & 7) << 4)));
        }
#pragma unroll
        for (int mi = 0; mi < 2; ++mi)
#pragma unroll
            for (int ni = 0; ni < 2; ++ni)
                accy[mi][ni] = __builtin_amdgcn_mfma_f32_16x16x32_bf16(af[mi], bfr[ni], accy[mi][ni], 0, 0, 0);
    }
#pragma unroll
    for (int mi = 0; mi < 2; ++mi)
#pragma unroll
        for (int j = 0; j < 4; ++j) {
            int t = wmY * 32 + mi * 16 + (lane >> 4) * 4 + j;
            float e = __expf(S_lds[t]);
#pragma unroll
            for (int ni = 0; ni < 2; ++ni) accy[mi][ni][j] *= e;
        }
#pragma unroll
    for (int ks = 0; ks < 4; ++ks) {
        bf16x8 af[2], bfr[2];
#pragma unroll
        for (int mi = 0; mi < 2; ++mi) {
            int t = wmY * 32 + mi * 16 + (lane & 15);
            af[mi] = *(const bf16x8*)(BsB + ((t * 256 + ks * 64 + (lane >> 4) * 16) ^ ((t & 7) << 4)));
        }
#pragma unroll
        for (int ni = 0; ni < 2; ++ni) {
            int pp = wnY * 32 + ni * 16 + (lane & 15);
            bfr[ni] = *(const bf16x8*)(XtB + ((pp * 256 + ks * 64 + (lane >> 4) * 16) ^ ((pp & 7) << 4)));
        }
#pragma unroll
        for (int mi = 0; mi < 2; ++mi)
#pragma unroll
            for (int ni = 0; ni < 2; ++ni)
                accy[mi][ni] = __builtin_amdgcn_mfma_f32_16x16x32_bf16(af[mi], bfr[ni], accy[mi][ni], 0, 0, 0);
    }
#pragma unroll
    for (int mi = 0; mi < 2; ++mi)
#pragma unroll
        for (int ni = 0; ni < 2; ++ni)
#pragma unroll
            for (int j = 0; j < 4; ++j) {
                int t = wmY * 32 + mi * 16 + (lane >> 4) * 4 + j;
                int pp = wnY * 32 + ni * 16 + (lane & 15);
                float xv = (float)*(const bf16*)(XtB + ((pp * 256 + t * 2) ^ ((pp & 7) << 4)));
                ysb[(brow0 + t) * DINNER + h * HEADDIM + pp] = accy[mi][ni][j] + Dh * xv;
            }
}

// ---------------- gated rmsnorm ----------------
__global__ __launch_bounds__(256) void k_gated(const float* __restrict__ ys, const bf16* __restrict__ zx,
                                               const float* __restrict__ w, bf16* __restrict__ out) {
    __shared__ float sm[4];
    int r = blockIdx.x, tid = threadIdx.x;
    float v[6]; float ss = 0.f;
#pragma unroll
    for (int k = 0; k < 6; ++k) {
        int d = tid + k * 256;
        float z = (float)zx[(long)r * NPAD + d];
        float t = ys[(long)r * DINNER + d] * fsilu(z);
        v[k] = t; ss += t * t;
    }
#pragma unroll
    for (int off = 32; off; off >>= 1) ss += __shfl_down(ss, off, 64);
    if ((tid & 63) == 0) sm[tid >> 6] = ss;
    __syncthreads();
    float tot = sm[0] + sm[1] + sm[2] + sm[3];
    float sc = rsqrtf(tot / (float)DINNER + EPS);
#pragma unroll
    for (int k = 0; k < 6; ++k) {
        int d = tid + k * 256;
        out[(long)r * DINNER + d] = (bf16)(v[k] * sc * w[d]);
    }
}

// ---------------- head: 32 rows/block, 1 atomic/block ----------------
__global__ __launch_bounds__(256) void k_head(const bf16* __restrict__ hn, const float* __restrict__ Wh,
                                              const float* __restrict__ y, float* __restrict__ out,
                                              float* __restrict__ loss) {
    __shared__ float sl[4];
    int tid = threadIdx.x, lane = tid & 63, wid = tid >> 6;
    float wv[5][12];
#pragma unroll
    for (int o = 0; o < 5; ++o)
#pragma unroll
        for (int j = 0; j < 12; ++j) wv[o][j] = Wh[o * DMODEL + lane * 12 + j];
    float lsum = 0.f;
#pragma unroll
    for (int rr = 0; rr < 8; ++rr) {
        long r = (long)blockIdx.x * 32 + wid * 8 + rr;
        const bf16* hp = hn + r * DMODEL + lane * 12;
        float hv[12];
#pragma unroll
        for (int q = 0; q < 3; ++q) {
            bf16x4 v4 = *(const bf16x4*)(hp + q * 4);
#pragma unroll
            for (int j = 0; j < 4; ++j) hv[q * 4 + j] = (float)v4[j];
        }
        float acc[5];
#pragma unroll
        for (int o = 0; o < 5; ++o) {
            float a = 0.f;
#pragma unroll
            for (int j = 0; j < 12; ++j) a += hv[j] * wv[o][j];
            acc[o] = a;
        }
#pragma unroll
        for (int o = 0; o < 5; ++o)
#pragma unroll
            for (int m = 32; m; m >>= 1) acc[o] += __shfl_xor(acc[o], m, 64);
        if (lane == 0) {
#pragma unroll
            for (int o = 0; o < 5; ++o) {
                out[r * 5 + o] = acc[o];
                float d = acc[o] - y[r * 5 + o];
                lsum += d * d;
            }
        }
    }
    if (lane == 0) sl[wid] = lsum;
    __syncthreads();
    if (tid == 0) atomicAdd(loss, (sl[0] + sl[1] + sl[2] + sl[3]) * (1.f / ((float)ROWS * 5.f)));
}

extern "C" void kernel_launch(void* const* d_in, const int* in_sizes, int n_in,
                              void* d_out, int out_size, void* d_ws, size_t ws_size,
                              hipStream_t stream) {
    const float* x      = (const float*)d_in[0];
    const float* y      = (const float*)d_in[1];
    const float* W_emb  = (const float*)d_in[2];
    const float* b_emb  = (const float*)d_in[3];
    const float* W_in   = (const float*)d_in[4];
    const float* conv_w = (const float*)d_in[5];
    const float* conv_b = (const float*)d_in[6];
    const float* dt_bias= (const float*)d_in[7];
    const float* A_log  = (const float*)d_in[8];
    const float* Dp     = (const float*)d_in[9];
    const float* norm_w = (const float*)d_in[10];
    const float* W_out  = (const float*)d_in[11];
    const float* bnw    = (const float*)d_in[12];
    const float* nfw    = (const float*)d_in[13];
    const float* W_head = (const float*)d_in[14];

    char* ws = (char*)d_ws;
    float* hb   = (float*)ws;  ws += (size_t)ROWS * DMODEL * 4;
    float* res  = (float*)ws;  ws += (size_t)ROWS * DMODEL * 4;
    bf16*  hnb  = (bf16*)ws;   ws += (size_t)ROWS * DMODEL * 2;
    bf16*  zx   = (bf16*)ws;   ws += (size_t)ROWS * NPAD * 2;
    bf16*  cobf = (bf16*)ws;   ws += (size_t)ROWS * CONVDIM * 2;
    float* ysb  = (float*)ws;  ws += (size_t)ROWS * DINNER * 4;
    bf16*  yfb  = (bf16*)ws;   ws += (size_t)ROWS * DINNER * 2;
    bf16*  Wib  = (bf16*)ws;   ws += (size_t)NLAYER * NPAD * DMODEL * 2;
    bf16*  Wob  = (bf16*)ws;   ws += (size_t)NLAYER * DMODEL * DINNER * 2;
    float* Pcb  = (float*)ws;  ws += (size_t)BATCH * NHEADS * NCH * 4;
    float* Sarr = (float*)ws;  ws += (size_t)BATCH * NHEADS * NCH * QCH * 4;
    float* dtc  = (float*)ws;  ws += (size_t)BATCH * NHEADS * NCH * QCH * 4;
    bf16*  XT   = (bf16*)ws;   ws += (size_t)BATCH * NHEADS * NCH * 8192 * 2;
    bf16*  BT   = (bf16*)ws;   ws += (size_t)BATCH * NCH * 16384 * 2;

    bf16* Lbuf = (bf16*)hb;   // alias, dead window between add_rmsnorm and out-proj
    bf16* XwT  = (bf16*)yfb;  // alias, dead window between out-proj and k_gated

    float* out_p  = (float*)d_out;
    float* loss_p = out_p + (size_t)ROWS * 5;

    hipMemsetAsync(loss_p, 0, 4, stream);
    k_embed<<<ROWS * DMODEL / 256, 256, 0, stream>>>(x, W_emb, b_emb, hb, res);
    k_cvt_in<<<NLAYER * NPAD * DMODEL / 256, 256, 0, stream>>>(W_in, Wib);
    k_cvt_out<<<NLAYER * DMODEL * DINNER / 256, 256, 0, stream>>>(W_out, Wob);

    const int NBHC = BATCH * NHEADS * NCH;   // 1536
    for (int l = 0; l < NLAYER; ++l) {
        k_add_rmsnorm<<<ROWS, 256, 0, stream>>>(hb, res, bnw + l * DMODEL, hnb);
        dim3 g1(ROWS / 256, NPAD / 128);
        k_gemm<bf16, 256, 128><<<g1, 512, 0, stream>>>(hnb, Wib + (size_t)l * NPAD * DMODEL, zx, DMODEL, NPAD);
        k_conv<<<ROWS * 224 / 256, 256, 0, stream>>>(zx, conv_w + (size_t)l * CONVDIM * 4, conv_b + l * CONVDIM, cobf);
        k_prep<<<NBHC, 128, 0, stream>>>(cobf, zx, dt_bias + l * NHEADS, A_log + l * NHEADS, Sarr, dtc, Pcb, XT, XwT, BT);
        k_stateL<<<NBHC, 256, 0, stream>>>(XwT, BT, Lbuf);
        k_scanB<<<BATCH * NHEADS * 4, 256, 0, stream>>>(Lbuf, Pcb);
        k_chunkY<<<NBHC, 512, 0, stream>>>(cobf, Sarr, dtc, Dp + l * NHEADS, XT, Lbuf, ysb);
        k_gated<<<ROWS, 256, 0, stream>>>(ysb, zx, norm_w + l * DINNER, yfb);
        dim3 g2(ROWS / 128, DMODEL / 64);
        k_gemm<float, 128, 64><<<g2, 256, 0, stream>>>(yfb, Wob + (size_t)l * DMODEL * DINNER, hb, DINNER, DMODEL);
    }

    k_add_rmsnorm<<<ROWS, 256, 0, stream>>>(hb, res, nfw, hnb);
    k_head<<<256, 256, 0, stream>>>(hnb, W_head, y, out_p, loss_p);
}

// Round 7
// 2360.967 us; speedup vs baseline: 4.9220x; 1.0428x over previous
//
#include <hip/hip_runtime.h>
#include <hip/hip_bf16.h>
#include <math.h>

#define BATCH 4
#define SEQ 2048
#define DMODEL 768
#define NLAYER 8
#define DINNER 1536
#define HEADDIM 64
#define NHEADS 24
#define DSTATE 128
#define CONVDIM 1792
#define DINPROJ 3352
#define NPAD 3456
#define ROWS (BATCH*SEQ)
#define EPS 1e-5f
#define QCH 128
#define NCH (SEQ/QCH)

typedef __bf16 bf16;
typedef bf16 bf16x8 __attribute__((ext_vector_type(8)));
typedef bf16 bf16x4 __attribute__((ext_vector_type(4)));
typedef float f32x4 __attribute__((ext_vector_type(4)));

#define GLD(src, dst) __builtin_amdgcn_global_load_lds( \
    (const __attribute__((address_space(1))) void*)(src), \
    (__attribute__((address_space(3))) void*)(dst), 16, 0, 0)

__device__ __forceinline__ void bar_sync() {
    asm volatile("" ::: "memory");
    __builtin_amdgcn_s_barrier();
    asm volatile("" ::: "memory");
}

__device__ __forceinline__ float fsilu(float x) { return x / (1.f + __expf(-x)); }

// ---------------- embed: res = x @ W_emb^T + b_emb ----------------
__global__ void k_embed(const float* __restrict__ x, const float* __restrict__ We,
                        const float* __restrict__ be, float* __restrict__ res) {
    int idx = blockIdx.x * 256 + threadIdx.x;
    int d = idx % DMODEL; int bl = idx / DMODEL;
    float acc = be[d];
#pragma unroll
    for (int i = 0; i < 6; ++i) acc += x[bl * 6 + i] * We[d * 6 + i];
    res[idx] = acc;
}

// ---------------- read-only rmsnorm (residual pre-accumulated in res) ----------------
__global__ __launch_bounds__(256) void k_rmsnorm(const float* __restrict__ res,
                                                 const float* __restrict__ w,
                                                 bf16* __restrict__ out) {
    __shared__ float sm[4];
    int r = blockIdx.x, tid = threadIdx.x;
    float v[3]; float ss = 0.f;
#pragma unroll
    for (int k = 0; k < 3; ++k) {
        int d = tid + k * 256;
        float t = res[r * DMODEL + d];
        v[k] = t; ss += t * t;
    }
#pragma unroll
    for (int off = 32; off; off >>= 1) ss += __shfl_down(ss, off, 64);
    if ((tid & 63) == 0) sm[tid >> 6] = ss;
    __syncthreads();
    float tot = sm[0] + sm[1] + sm[2] + sm[3];
    float sc = rsqrtf(tot / (float)DMODEL + EPS);
#pragma unroll
    for (int k = 0; k < 3; ++k) {
        int d = tid + k * 256;
        out[r * DMODEL + d] = (bf16)(v[k] * sc * w[d]);
    }
}

// ---------------- batched weight conversions ----------------
__global__ void k_cvt_in(const float* __restrict__ src, bf16* __restrict__ dst) {
    int idx = blockIdx.x * 256 + threadIdx.x;
    int l = idx / (NPAD * DMODEL);
    int rem = idx % (NPAD * DMODEL);
    int n = rem / DMODEL;
    int d = rem % DMODEL;
    dst[idx] = (n < DINPROJ) ? (bf16)src[(long)l * DINPROJ * DMODEL + n * DMODEL + d] : (bf16)0.f;
}
__global__ void k_cvt_out(const float* __restrict__ src, bf16* __restrict__ dst) {
    int idx = blockIdx.x * 256 + threadIdx.x;
    dst[idx] = (bf16)src[idx];
}

// ---------------- bf16 MFMA GEMM: C[M,N] (=|+=) A[M,K] @ B[N,K]^T ----------------
// BMxBN tile, BK=64, counted-vmcnt depth-2 pipeline, XOR-swizzled LDS, 256 thr.
template <typename OT, int BM, int BN, bool ACC>
__global__ __launch_bounds__(256) void k_gemm(const bf16* __restrict__ A, const bf16* __restrict__ B,
                                              OT* __restrict__ C, int K, int ldc) {
    constexpr int nWn = BN / 64;         // 2 (BN=128) or 1 (BN=64)
    constexpr int nWm = 4 / nWn;         // 2 or 4
    constexpr int WMR = BM / nWm;        // 64 or 32
    constexpr int MI  = WMR / 16;        // 4 or 2
    constexpr int NI  = 4;
    constexpr int RG  = BM / 4;          // 32
    constexpr int BG  = BN / RG;         // 4 (BN=128) or 2 (BN=64)
    __shared__ bf16 As[2][BM * 64];
    __shared__ bf16 Bs[2][BN * 64];
    const int tid = threadIdx.x;
    const int lane = tid & 63;
    const int w = tid >> 6;
    const int wm = w / nWn, wn = w % nWn;
    const long rowA0 = (long)blockIdx.x * BM;
    const long rowB0 = (long)blockIdx.y * BN;
    const int srow = tid >> 3;                          // 0..31
    const int scol = ((tid & 7) ^ (srow & 7)) * 8;      // pre-swizzled k-offset
    const bf16* Ab = A + rowA0 * K + scol;
    const bf16* Bb = B + rowB0 * K + scol;

    f32x4 acc[MI][NI];
    const f32x4 vz = {0.f, 0.f, 0.f, 0.f};
#pragma unroll
    for (int mi = 0; mi < MI; ++mi)
#pragma unroll
        for (int ni = 0; ni < NI; ++ni) acc[mi][ni] = vz;

    auto stage = [&](int buf, int kt) {
#pragma unroll
        for (int j = 0; j < 4; ++j)
            GLD(Ab + (long)(j * RG + srow) * K + kt, &As[buf][(j * RG + w * 8) * 64]);
#pragma unroll
        for (int j = 0; j < BG; ++j)
            GLD(Bb + (long)(j * RG + srow) * K + kt, &Bs[buf][(j * RG + w * 8) * 64]);
    };
    auto waitv = [&]() {   // wait until only the newest stage's loads are outstanding
        if constexpr (BG == 4) asm volatile("s_waitcnt vmcnt(8)" ::: "memory");
        else                   asm volatile("s_waitcnt vmcnt(6)" ::: "memory");
    };
    auto compute = [&](int buf) {
        const char* AsB = (const char*)As[buf];
        const char* BsB = (const char*)Bs[buf];
#pragma unroll
        for (int s = 0; s < 2; ++s) {
            bf16x8 af[MI], bfr[NI];
#pragma unroll
            for (int mi = 0; mi < MI; ++mi) {
                int r = wm * WMR + mi * 16 + (lane & 15);
                af[mi] = *(const bf16x8*)(AsB + r * 128 + ((s * 64 + (lane >> 4) * 16) ^ ((r & 7) << 4)));
            }
#pragma unroll
            for (int ni = 0; ni < NI; ++ni) {
                int r = wn * 64 + ni * 16 + (lane & 15);
                bfr[ni] = *(const bf16x8*)(BsB + r * 128 + ((s * 64 + (lane >> 4) * 16) ^ ((r & 7) << 4)));
            }
#pragma unroll
            for (int mi = 0; mi < MI; ++mi)
#pragma unroll
                for (int ni = 0; ni < NI; ++ni)
                    acc[mi][ni] = __builtin_amdgcn_mfma_f32_16x16x32_bf16(af[mi], bfr[ni], acc[mi][ni], 0, 0, 0);
        }
    };

    stage(0, 0);
    stage(1, 64);
    int cur = 0;
    for (int kt = 128; kt < K; kt += 64) {
        waitv();                     // oldest tile landed; next tile stays in flight
        bar_sync();
        compute(cur);
        bar_sync();                  // all waves done reading buf[cur]
        stage(cur, kt);
        cur ^= 1;
    }
    waitv();
    bar_sync();
    compute(cur);
    asm volatile("s_waitcnt vmcnt(0)" ::: "memory");
    bar_sync();
    compute(cur ^ 1);

    const int crow = (lane >> 4) * 4;
    const int ccol = lane & 15;
#pragma unroll
    for (int mi = 0; mi < MI; ++mi)
#pragma unroll
        for (int ni = 0; ni < NI; ++ni) {
            long r0 = rowA0 + wm * WMR + mi * 16 + crow;
            long c0 = rowB0 + wn * 64 + ni * 16 + ccol;
#pragma unroll
            for (int j = 0; j < 4; ++j) {
                if constexpr (ACC) C[(r0 + j) * ldc + c0] += (OT)acc[mi][ni][j];
                else               C[(r0 + j) * ldc + c0]  = (OT)acc[mi][ni][j];
            }
        }
}

// ---------------- causal conv1d (k=4) + bias + silu, bf16 in/out ----------------
__global__ void k_conv(const bf16* __restrict__ zx, const float* __restrict__ cw,
                       const float* __restrict__ cb, bf16* __restrict__ co) {
    int idx = blockIdx.x * 256 + threadIdx.x;   // ROWS * 224
    int c8 = idx % 224; int blt = idx / 224;
    int t = blt % SEQ;
    int c0 = c8 * 8;
    long bbase = (long)(blt - t) * NPAD;
    float cwa[8][4];
#pragma unroll
    for (int j = 0; j < 8; ++j) {
        float4 tv = *(const float4*)(cw + (c0 + j) * 4);
        cwa[j][0] = tv.x; cwa[j][1] = tv.y; cwa[j][2] = tv.z; cwa[j][3] = tv.w;
    }
    float acc[8];
#pragma unroll
    for (int j = 0; j < 8; ++j) acc[j] = cb[c0 + j];
#pragma unroll
    for (int k = 0; k < 4; ++k) {
        int tt = t + k - 3;
        if (tt >= 0) {
            bf16x8 v = *(const bf16x8*)(zx + bbase + (long)tt * NPAD + DINNER + c0);
#pragma unroll
            for (int j = 0; j < 8; ++j) acc[j] += (float)v[j] * cwa[j][k];
        }
    }
    bf16x8 o;
#pragma unroll
    for (int j = 0; j < 8; ++j) o[j] = (bf16)fsilu(acc[j]);
    *(bf16x8*)(co + (long)blt * CONVDIM + c0) = o;
}

// ---------------- per-chunk prep (dt softplus folded in) ----------------
__global__ __launch_bounds__(128) void k_prep(const bf16* __restrict__ cobf, const bf16* __restrict__ zx,
                                              const float* __restrict__ dt_bias_l,
                                              const float* __restrict__ Alog,
                                              float* __restrict__ Sarr, float* __restrict__ dtc,
                                              float* __restrict__ Pcb,
                                              bf16* __restrict__ XT, bf16* __restrict__ XwT,
                                              bf16* __restrict__ BT) {
    int blk = blockIdx.x;
    int b = blk / (NHEADS * NCH);
    int r = blk % (NHEADS * NCH);
    int h = r / NCH;
    int c = r % NCH;
    int tid = threadIdx.x;
    __shared__ float S_lds[128], dt_lds[128], wl_lds[128], wtot[2];
    __shared__ bf16 Xs[128][64];
    long grow = (long)(b * SEQ + c * QCH + tid);
    float raw = (float)zx[grow * NPAD + DINNER + CONVDIM + h] + dt_bias_l[h];
    float dtv = (raw > 15.f) ? raw : log1pf(__expf(raw));
    float Ah = -__expf(Alog[h]);
    float ps = dtv * Ah;
#pragma unroll
    for (int off = 1; off < 64; off <<= 1) {
        float o = __shfl_up(ps, off, 64);
        if ((tid & 63) >= off) ps += o;
    }
    if ((tid & 63) == 63) wtot[tid >> 6] = ps;
    __syncthreads();
    if (tid >= 64) ps += wtot[0];
    S_lds[tid] = ps; dt_lds[tid] = dtv;
    __syncthreads();
    float Sl = S_lds[127];
    wl_lds[tid] = __expf(Sl - ps) * dtv;
    Sarr[blk * QCH + tid] = ps;
    dtc[blk * QCH + tid] = dtv;
    if (tid == 127) Pcb[blk] = __expf(Sl);
    const bf16* xrow = cobf + grow * CONVDIM + h * HEADDIM;
#pragma unroll
    for (int j = 0; j < 8; ++j) *(bf16x8*)&Xs[tid][j * 8] = *(const bf16x8*)(xrow + j * 8);
    __syncthreads();
    int p = tid >> 1, hf = tid & 1;
    char* xtb = (char*)XT + (((long)blk) << 14);
    char* xwb = (char*)XwT + (((long)blk) << 14);
#pragma unroll
    for (int ub = 0; ub < 8; ++ub) {
        int u0 = hf * 64 + ub * 8;
        bf16x8 vx, vw;
#pragma unroll
        for (int k = 0; k < 8; ++k) {
            int u = u0 + k;
            bf16 xv = Xs[u][p];
            vx[k] = xv;
            vw[k] = (bf16)((float)xv * wl_lds[u]);
        }
        long off = (long)((p * 256 + u0 * 2) ^ ((p & 7) << 4));
        *(bf16x8*)(xtb + off) = vx;
        *(bf16x8*)(xwb + off) = vw;
    }
    if (h == 0) {
        char* btb = (char*)BT + (((long)(b * NCH + c)) << 15);
        const bf16* brow = cobf + (long)(b * SEQ + c * QCH + tid) * CONVDIM + DINNER;
        int nl = tid >> 1;
        for (int nb = 0; nb < 2; ++nb) {
            __syncthreads();
#pragma unroll
            for (int j = 0; j < 8; ++j) *(bf16x8*)&Xs[tid][j * 8] = *(const bf16x8*)(brow + nb * 64 + j * 8);
            __syncthreads();
            int n = nb * 64 + nl;
#pragma unroll
            for (int ub = 0; ub < 8; ++ub) {
                int u0 = hf * 64 + ub * 8;
                bf16x8 v;
#pragma unroll
                for (int k = 0; k < 8; ++k) v[k] = Xs[u0 + k][nl];
                long off = (long)((n * 256 + u0 * 2) ^ ((n & 7) << 4));
                *(bf16x8*)(btb + off) = v;
            }
        }
    }
}

// ---------------- chunk-local final state via MFMA ----------------
__global__ __launch_bounds__(256) void k_stateL(const bf16* __restrict__ XwT, const bf16* __restrict__ BT,
                                                bf16* __restrict__ Lbuf) {
    __shared__ bf16 Xs[64 * 128];
    __shared__ bf16 Bs[128 * 128];
    int blk = blockIdx.x;
    int b = blk / (NHEADS * NCH);
    int r = blk % (NHEADS * NCH);
    int c = r % NCH;
    int bc = b * NCH + c;
    int tid = threadIdx.x, lane = tid & 63, wid = tid >> 6;
    const char* xw = (const char*)XwT + (((long)blk) << 14);
    const char* bt = (const char*)BT + (((long)bc) << 15);
#pragma unroll
    for (int i = 0; i < 4; ++i)
        GLD(xw + (long)(i * 256 + tid) * 16, (char*)Xs + (i * 256 + wid * 64) * 16);
#pragma unroll
    for (int i = 0; i < 8; ++i)
        GLD(bt + (long)(i * 256 + tid) * 16, (char*)Bs + (i * 256 + wid * 64) * 16);
    __syncthreads();
    f32x4 acc[4][2];
    const f32x4 vz = {0.f, 0.f, 0.f, 0.f};
#pragma unroll
    for (int mi = 0; mi < 4; ++mi)
#pragma unroll
        for (int ni = 0; ni < 2; ++ni) acc[mi][ni] = vz;
    const char* XsB = (const char*)Xs;
    const char* BsB = (const char*)Bs;
#pragma unroll
    for (int ks = 0; ks < 4; ++ks) {
        bf16x8 af[4], bfr[2];
#pragma unroll
        for (int mi = 0; mi < 4; ++mi) {
            int pp = mi * 16 + (lane & 15);
            af[mi] = *(const bf16x8*)(XsB + ((pp * 256 + ks * 64 + (lane >> 4) * 16) ^ ((pp & 7) << 4)));
        }
#pragma unroll
        for (int ni = 0; ni < 2; ++ni) {
            int n = wid * 32 + ni * 16 + (lane & 15);
            bfr[ni] = *(const bf16x8*)(BsB + ((n * 256 + ks * 64 + (lane >> 4) * 16) ^ ((n & 7) << 4)));
        }
#pragma unroll
        for (int mi = 0; mi < 4; ++mi)
#pragma unroll
            for (int ni = 0; ni < 2; ++ni)
                acc[mi][ni] = __builtin_amdgcn_mfma_f32_16x16x32_bf16(af[mi], bfr[ni], acc[mi][ni], 0, 0, 0);
    }
    char* lb = (char*)Lbuf + (((long)blk) << 14);
#pragma unroll
    for (int mi = 0; mi < 4; ++mi)
#pragma unroll
        for (int ni = 0; ni < 2; ++ni)
#pragma unroll
            for (int j = 0; j < 4; ++j) {
                int pp = mi * 16 + (lane >> 4) * 4 + j;
                int n = wid * 32 + ni * 16 + (lane & 15);
                *(bf16*)(lb + ((pp * 256 + n * 2) ^ ((pp & 7) << 4))) = (bf16)acc[mi][ni][j];
            }
}

// ---------------- Pass B: sequential inter-chunk combine ----------------
__global__ __launch_bounds__(256) void k_scanB(bf16* __restrict__ Lbuf, const float* __restrict__ Pc) {
    int bh = blockIdx.x >> 2;
    int q = blockIdx.x & 3;
    int off = (q * 256 + threadIdx.x) * 8;
    long base = ((long)bh * NCH) << 13;
    float s[8] = {0.f};
#pragma unroll
    for (int c = 0; c < NCH; ++c) {
        bf16* p = Lbuf + base + ((long)c << 13) + off;
        bf16x8 L = *(bf16x8*)p;
        bf16x8 I;
#pragma unroll
        for (int k = 0; k < 8; ++k) I[k] = (bf16)s[k];
        float P = Pc[bh * NCH + c];
#pragma unroll
        for (int k = 0; k < 8; ++k) s[k] = P * s[k] + (float)L[k];
        *(bf16x8*)p = I;
    }
}

// ---------------- chunk Y via MFMA -> bf16 ----------------
__global__ __launch_bounds__(512) void k_chunkY(const bf16* __restrict__ cobf,
                                                const float* __restrict__ Sarr, const float* __restrict__ dtc,
                                                const float* __restrict__ Dp,
                                                const bf16* __restrict__ XT, const bf16* __restrict__ Lbuf,
                                                bf16* __restrict__ ysb) {
    __shared__ bf16 Cs[128 * 128];
    __shared__ bf16 Bs[128 * 128];
    __shared__ bf16 Xts[64 * 128];
    __shared__ bf16 Is[64 * 128];
    __shared__ float S_lds[128], dt_lds[128];
    int blk = blockIdx.x;
    int b = blk / (NHEADS * NCH);
    int r = blk % (NHEADS * NCH);
    int h = r / NCH;
    int c = r % NCH;
    int tid = threadIdx.x, lane = tid & 63, wid = tid >> 6;
    long brow0 = (long)b * SEQ + c * QCH;
    const char* cob = (const char*)cobf;
#pragma unroll
    for (int i = 0; i < 4; ++i) {
        int trow = i * 32 + wid * 4 + (lane >> 4);
        int blk16 = lane & 15;
        const char* rp = cob + (brow0 + trow) * (CONVDIM * 2);
        int sb = (blk16 ^ (trow & 7)) << 4;
        GLD(rp + (DINNER + DSTATE) * 2 + sb, (char*)Cs + (i * 32 + wid * 4) * 256);
        GLD(rp + DINNER * 2 + sb, (char*)Bs + (i * 32 + wid * 4) * 256);
    }
    const char* xt = (const char*)XT + (((long)blk) << 14);
    const char* ib = (const char*)Lbuf + (((long)blk) << 14);
#pragma unroll
    for (int i = 0; i < 2; ++i) {
        GLD(xt + (long)(i * 512 + tid) * 16, (char*)Xts + (i * 512 + wid * 64) * 16);
        GLD(ib + (long)(i * 512 + tid) * 16, (char*)Is + (i * 512 + wid * 64) * 16);
    }
    if (tid < 128) { S_lds[tid] = Sarr[blk * QCH + tid]; dt_lds[tid] = dtc[blk * QCH + tid]; }
    float Dh = Dp[h];
    __syncthreads();
    const char* CsB = (const char*)Cs;
    char* BsB = (char*)Bs;
    const char* IsB = (const char*)Is;
    const char* XtB = (const char*)Xts;
    const f32x4 vz = {0.f, 0.f, 0.f, 0.f};
    int wmG = wid >> 2, wnG = wid & 3;
    f32x4 accg[4][2];
#pragma unroll
    for (int mi = 0; mi < 4; ++mi)
#pragma unroll
        for (int ni = 0; ni < 2; ++ni) accg[mi][ni] = vz;
#pragma unroll
    for (int ks = 0; ks < 4; ++ks) {
        bf16x8 af[4], bfr[2];
#pragma unroll
        for (int mi = 0; mi < 4; ++mi) {
            int t = wmG * 64 + mi * 16 + (lane & 15);
            af[mi] = *(const bf16x8*)(CsB + ((t * 256 + ks * 64 + (lane >> 4) * 16) ^ ((t & 7) << 4)));
        }
#pragma unroll
        for (int ni = 0; ni < 2; ++ni) {
            int u = wnG * 32 + ni * 16 + (lane & 15);
            bfr[ni] = *(const bf16x8*)(BsB + ((u * 256 + ks * 64 + (lane >> 4) * 16) ^ ((u & 7) << 4)));
        }
#pragma unroll
        for (int mi = 0; mi < 4; ++mi)
#pragma unroll
            for (int ni = 0; ni < 2; ++ni)
                accg[mi][ni] = __builtin_amdgcn_mfma_f32_16x16x32_bf16(af[mi], bfr[ni], accg[mi][ni], 0, 0, 0);
    }
    __syncthreads();
#pragma unroll
    for (int mi = 0; mi < 4; ++mi) {
#pragma unroll
        for (int j = 0; j < 4; ++j) {
            int t = wmG * 64 + mi * 16 + (lane >> 4) * 4 + j;
            float St = S_lds[t];
#pragma unroll
            for (int ni = 0; ni < 2; ++ni) {
                int u = wnG * 32 + ni * 16 + (lane & 15);
                float v = 0.f;
                if (u <= t) v = accg[mi][ni][j] * __expf(St - S_lds[u]) * dt_lds[u];
                *(bf16*)(BsB + ((t * 256 + u * 2) ^ ((t & 7) << 4))) = (bf16)v;
            }
        }
    }
    __syncthreads();
    int wmY = wid >> 1, wnY = wid & 1;
    f32x4 accy[2][2];
#pragma unroll
    for (int mi = 0; mi < 2; ++mi)
#pragma unroll
        for (int ni = 0; ni < 2; ++ni) accy[mi][ni] = vz;
#pragma unroll
    for (int ks = 0; ks < 4; ++ks) {
        bf16x8 af[2], bfr[2];
#pragma unroll
        for (int mi = 0; mi < 2; ++mi) {
            int t = wmY * 32 + mi * 16 + (lane & 15);
            af[mi] = *(const bf16x8*)(CsB + ((t * 256 + ks * 64 + (lane >> 4) * 16) ^ ((t & 7) << 4)));
        }
#pragma unroll
        for (int ni = 0; ni < 2; ++ni) {
            int pp = wnY * 32 + ni * 16 + (lane & 15);
            bfr[ni] = *(const bf16x8*)(IsB + ((pp * 256 + ks * 64 + (lane >> 4) * 16) ^ ((pp & 7) << 4)));
        }
#pragma unroll
        for (int mi = 0; mi < 2; ++mi)
#pragma unroll
            for (int ni = 0; ni < 2; ++ni)
                accy[mi][ni] = __builtin_amdgcn_mfma_f32_16x16x32_bf16(af[mi], bfr[ni], accy[mi][ni], 0, 0, 0);
    }
#pragma unroll
    for (int mi = 0; mi < 2; ++mi)
#pragma unroll
        for (int j = 0; j < 4; ++j) {
            int t = wmY * 32 + mi * 16 + (lane >> 4) * 4 + j;
            float e = __expf(S_lds[t]);
#pragma unroll
            for (int ni = 0; ni < 2; ++ni) accy[mi][ni][j] *= e;
        }
#pragma unroll
    for (int ks = 0; ks < 4; ++ks) {
        bf16x8 af[2], bfr[2];
#pragma unroll
        for (int mi = 0; mi < 2; ++mi) {
            int t = wmY * 32 + mi * 16 + (lane & 15);
            af[mi] = *(const bf16x8*)(BsB + ((t * 256 + ks * 64 + (lane >> 4) * 16) ^ ((t & 7) << 4)));
        }
#pragma unroll
        for (int ni = 0; ni < 2; ++ni) {
            int pp = wnY * 32 + ni * 16 + (lane & 15);
            bfr[ni] = *(const bf16x8*)(XtB + ((pp * 256 + ks * 64 + (lane >> 4) * 16) ^ ((pp & 7) << 4)));
        }
#pragma unroll
        for (int mi = 0; mi < 2; ++mi)
#pragma unroll
            for (int ni = 0; ni < 2; ++ni)
                accy[mi][ni] = __builtin_amdgcn_mfma_f32_16x16x32_bf16(af[mi], bfr[ni], accy[mi][ni], 0, 0, 0);
    }
#pragma unroll
    for (int mi = 0; mi < 2; ++mi)
#pragma unroll
        for (int ni = 0; ni < 2; ++ni)
#pragma unroll
            for (int j = 0; j < 4; ++j) {
                int t = wmY * 32 + mi * 16 + (lane >> 4) * 4 + j;
                int pp = wnY * 32 + ni * 16 + (lane & 15);
                float xv = (float)*(const bf16*)(XtB + ((pp * 256 + t * 2) ^ ((pp & 7) << 4)));
                ysb[(brow0 + t) * DINNER + h * HEADDIM + pp] = (bf16)(accy[mi][ni][j] + Dh * xv);
            }
}

// ---------------- gated rmsnorm ----------------
__global__ __launch_bounds__(256) void k_gated(const bf16* __restrict__ ys, const bf16* __restrict__ zx,
                                               const float* __restrict__ w, bf16* __restrict__ out) {
    __shared__ float sm[4];
    int r = blockIdx.x, tid = threadIdx.x;
    float v[6]; float ss = 0.f;
#pragma unroll
    for (int k = 0; k < 6; ++k) {
        int d = tid + k * 256;
        float z = (float)zx[(long)r * NPAD + d];
        float t = (float)ys[(long)r * DINNER + d] * fsilu(z);
        v[k] = t; ss += t * t;
    }
#pragma unroll
    for (int off = 32; off; off >>= 1) ss += __shfl_down(ss, off, 64);
    if ((tid & 63) == 0) sm[tid >> 6] = ss;
    __syncthreads();
    float tot = sm[0] + sm[1] + sm[2] + sm[3];
    float sc = rsqrtf(tot / (float)DINNER + EPS);
#pragma unroll
    for (int k = 0; k < 6; ++k) {
        int d = tid + k * 256;
        out[(long)r * DINNER + d] = (bf16)(v[k] * sc * w[d]);
    }
}

// ---------------- head: 32 rows/block, 1 atomic/block ----------------
__global__ __launch_bounds__(256) void k_head(const bf16* __restrict__ hn, const float* __restrict__ Wh,
                                              const float* __restrict__ y, float* __restrict__ out,
                                              float* __restrict__ loss) {
    __shared__ float sl[4];
    int tid = threadIdx.x, lane = tid & 63, wid = tid >> 6;
    float wv[5][12];
#pragma unroll
    for (int o = 0; o < 5; ++o)
#pragma unroll
        for (int j = 0; j < 12; ++j) wv[o][j] = Wh[o * DMODEL + lane * 12 + j];
    float lsum = 0.f;
#pragma unroll
    for (int rr = 0; rr < 8; ++rr) {
        long r = (long)blockIdx.x * 32 + wid * 8 + rr;
        const bf16* hp = hn + r * DMODEL + lane * 12;
        float hv[12];
#pragma unroll
        for (int q = 0; q < 3; ++q) {
            bf16x4 v4 = *(const bf16x4*)(hp + q * 4);
#pragma unroll
            for (int j = 0; j < 4; ++j) hv[q * 4 + j] = (float)v4[j];
        }
        float acc[5];
#pragma unroll
        for (int o = 0; o < 5; ++o) {
            float a = 0.f;
#pragma unroll
            for (int j = 0; j < 12; ++j) a += hv[j] * wv[o][j];
            acc[o] = a;
        }
#pragma unroll
        for (int o = 0; o < 5; ++o)
#pragma unroll
            for (int m = 32; m; m >>= 1) acc[o] += __shfl_xor(acc[o], m, 64);
        if (lane == 0) {
#pragma unroll
            for (int o = 0; o < 5; ++o) {
                out[r * 5 + o] = acc[o];
                float d = acc[o] - y[r * 5 + o];
                lsum += d * d;
            }
        }
    }
    if (lane == 0) sl[wid] = lsum;
    __syncthreads();
    if (tid == 0) atomicAdd(loss, (sl[0] + sl[1] + sl[2] + sl[3]) * (1.f / ((float)ROWS * 5.f)));
}

extern "C" void kernel_launch(void* const* d_in, const int* in_sizes, int n_in,
                              void* d_out, int out_size, void* d_ws, size_t ws_size,
                              hipStream_t stream) {
    const float* x      = (const float*)d_in[0];
    const float* y      = (const float*)d_in[1];
    const float* W_emb  = (const float*)d_in[2];
    const float* b_emb  = (const float*)d_in[3];
    const float* W_in   = (const float*)d_in[4];
    const float* conv_w = (const float*)d_in[5];
    const float* conv_b = (const float*)d_in[6];
    const float* dt_bias= (const float*)d_in[7];
    const float* A_log  = (const float*)d_in[8];
    const float* Dp     = (const float*)d_in[9];
    const float* norm_w = (const float*)d_in[10];
    const float* W_out  = (const float*)d_in[11];
    const float* bnw    = (const float*)d_in[12];
    const float* nfw    = (const float*)d_in[13];
    const float* W_head = (const float*)d_in[14];

    char* ws = (char*)d_ws;
    float* res  = (float*)ws;  ws += (size_t)ROWS * DMODEL * 4;
    bf16*  Lbuf = (bf16*)ws;   ws += (size_t)BATCH * NHEADS * NCH * 8192 * 2;
    bf16*  hnb  = (bf16*)ws;   ws += (size_t)ROWS * DMODEL * 2;
    bf16*  zx   = (bf16*)ws;   ws += (size_t)ROWS * NPAD * 2;
    bf16*  cobf = (bf16*)ws;   ws += (size_t)ROWS * CONVDIM * 2;
    bf16*  ysb  = (bf16*)ws;   ws += (size_t)ROWS * DINNER * 2;
    bf16*  yfb  = (bf16*)ws;   ws += (size_t)ROWS * DINNER * 2;
    bf16*  Wib  = (bf16*)ws;   ws += (size_t)NLAYER * NPAD * DMODEL * 2;
    bf16*  Wob  = (bf16*)ws;   ws += (size_t)NLAYER * DMODEL * DINNER * 2;
    float* Pcb  = (float*)ws;  ws += (size_t)BATCH * NHEADS * NCH * 4;
    float* Sarr = (float*)ws;  ws += (size_t)BATCH * NHEADS * NCH * QCH * 4;
    float* dtc  = (float*)ws;  ws += (size_t)BATCH * NHEADS * NCH * QCH * 4;
    bf16*  XT   = (bf16*)ws;   ws += (size_t)BATCH * NHEADS * NCH * 8192 * 2;
    bf16*  BT   = (bf16*)ws;   ws += (size_t)BATCH * NCH * 16384 * 2;

    bf16* XwT  = (bf16*)yfb;  // alias: XwT dead before k_gated writes yfb

    float* out_p  = (float*)d_out;
    float* loss_p = out_p + (size_t)ROWS * 5;

    hipMemsetAsync(loss_p, 0, 4, stream);
    k_embed<<<ROWS * DMODEL / 256, 256, 0, stream>>>(x, W_emb, b_emb, res);
    k_cvt_in<<<NLAYER * NPAD * DMODEL / 256, 256, 0, stream>>>(W_in, Wib);
    k_cvt_out<<<NLAYER * DMODEL * DINNER / 256, 256, 0, stream>>>(W_out, Wob);

    const int NBHC = BATCH * NHEADS * NCH;   // 1536
    for (int l = 0; l < NLAYER; ++l) {
        k_rmsnorm<<<ROWS, 256, 0, stream>>>(res, bnw + l * DMODEL, hnb);
        dim3 g1(ROWS / 128, NPAD / 128);
        k_gemm<bf16, 128, 128, false><<<g1, 256, 0, stream>>>(hnb, Wib + (size_t)l * NPAD * DMODEL, zx, DMODEL, NPAD);
        k_conv<<<ROWS * 224 / 256, 256, 0, stream>>>(zx, conv_w + (size_t)l * CONVDIM * 4, conv_b + l * CONVDIM, cobf);
        k_prep<<<NBHC, 128, 0, stream>>>(cobf, zx, dt_bias + l * NHEADS, A_log + l * NHEADS, Sarr, dtc, Pcb, XT, XwT, BT);
        k_stateL<<<NBHC, 256, 0, stream>>>(XwT, BT, Lbuf);
        k_scanB<<<BATCH * NHEADS * 4, 256, 0, stream>>>(Lbuf, Pcb);
        k_chunkY<<<NBHC, 512, 0, stream>>>(cobf, Sarr, dtc, Dp + l * NHEADS, XT, Lbuf, ysb);
        k_gated<<<ROWS, 256, 0, stream>>>(ysb, zx, norm_w + l * DINNER, yfb);
        dim3 g2(ROWS / 128, DMODEL / 64);
        k_gemm<float, 128, 64, true><<<g2, 256, 0, stream>>>(yfb, Wob + (size_t)l * DMODEL * DINNER, res, DINNER, DMODEL);
    }

    k_rmsnorm<<<ROWS, 256, 0, stream>>>(res, nfw, hnb);
    k_head<<<256, 256, 0, stream>>>(hnb, W_head, y, out_p, loss_p);
}

// Round 8
// 2196.354 us; speedup vs baseline: 5.2909x; 1.0749x over previous
//
#include <hip/hip_runtime.h>
#include <hip/hip_bf16.h>
#include <math.h>

#define BATCH 4
#define SEQ 2048
#define DMODEL 768
#define NLAYER 8
#define DINNER 1536
#define HEADDIM 64
#define NHEADS 24
#define DSTATE 128
#define CONVDIM 1792
#define DINPROJ 3352
#define NPAD 3456
#define ROWS (BATCH*SEQ)
#define EPS 1e-5f
#define QCH 128
#define NCH (SEQ/QCH)

typedef __bf16 bf16;
typedef bf16 bf16x8 __attribute__((ext_vector_type(8)));
typedef bf16 bf16x4 __attribute__((ext_vector_type(4)));
typedef float f32x4 __attribute__((ext_vector_type(4)));

#define GLD(src, dst) __builtin_amdgcn_global_load_lds( \
    (const __attribute__((address_space(1))) void*)(src), \
    (__attribute__((address_space(3))) void*)(dst), 16, 0, 0)

__device__ __forceinline__ void bar_sync() {
    asm volatile("" ::: "memory");
    __builtin_amdgcn_s_barrier();
    asm volatile("" ::: "memory");
}

__device__ __forceinline__ float fsilu(float x) { return x / (1.f + __expf(-x)); }

// ---------------- embed: res = x @ W_emb^T + b_emb ----------------
__global__ void k_embed(const float* __restrict__ x, const float* __restrict__ We,
                        const float* __restrict__ be, float* __restrict__ res) {
    int idx = blockIdx.x * 256 + threadIdx.x;
    int d = idx % DMODEL; int bl = idx / DMODEL;
    float acc = be[d];
#pragma unroll
    for (int i = 0; i < 6; ++i) acc += x[bl * 6 + i] * We[d * 6 + i];
    res[idx] = acc;
}

// ---------------- read-only rmsnorm ----------------
__global__ __launch_bounds__(256) void k_rmsnorm(const float* __restrict__ res,
                                                 const float* __restrict__ w,
                                                 bf16* __restrict__ out) {
    __shared__ float sm[4];
    int r = blockIdx.x, tid = threadIdx.x;
    float v[3]; float ss = 0.f;
#pragma unroll
    for (int k = 0; k < 3; ++k) {
        int d = tid + k * 256;
        float t = res[r * DMODEL + d];
        v[k] = t; ss += t * t;
    }
#pragma unroll
    for (int off = 32; off; off >>= 1) ss += __shfl_down(ss, off, 64);
    if ((tid & 63) == 0) sm[tid >> 6] = ss;
    __syncthreads();
    float tot = sm[0] + sm[1] + sm[2] + sm[3];
    float sc = rsqrtf(tot / (float)DMODEL + EPS);
#pragma unroll
    for (int k = 0; k < 3; ++k) {
        int d = tid + k * 256;
        out[r * DMODEL + d] = (bf16)(v[k] * sc * w[d]);
    }
}

// ---------------- batched weight conversions ----------------
__global__ void k_cvt_in(const float* __restrict__ src, bf16* __restrict__ dst) {
    int idx = blockIdx.x * 256 + threadIdx.x;
    int l = idx / (NPAD * DMODEL);
    int rem = idx % (NPAD * DMODEL);
    int n = rem / DMODEL;
    int d = rem % DMODEL;
    dst[idx] = (n < DINPROJ) ? (bf16)src[(long)l * DINPROJ * DMODEL + n * DMODEL + d] : (bf16)0.f;
}
__global__ void k_cvt_out(const float* __restrict__ src, bf16* __restrict__ dst) {
    int idx = blockIdx.x * 256 + threadIdx.x;
    dst[idx] = (bf16)src[idx];
}

// ---------------- bf16 MFMA GEMM: C[M,N] (=|+=) A[M,K] @ B[N,K]^T ----------------
template <typename OT, int BM, int BN, bool ACC>
__global__ __launch_bounds__(256) void k_gemm(const bf16* __restrict__ A, const bf16* __restrict__ B,
                                              OT* __restrict__ C, int K, int ldc) {
    constexpr int nWn = BN / 64;
    constexpr int nWm = 4 / nWn;
    constexpr int WMR = BM / nWm;
    constexpr int MI  = WMR / 16;
    constexpr int NI  = 4;
    constexpr int RG  = BM / 4;
    constexpr int BG  = BN / RG;
    __shared__ bf16 As[2][BM * 64];
    __shared__ bf16 Bs[2][BN * 64];
    const int tid = threadIdx.x;
    const int lane = tid & 63;
    const int w = tid >> 6;
    const int wm = w / nWn, wn = w % nWn;
    const long rowA0 = (long)blockIdx.x * BM;
    const long rowB0 = (long)blockIdx.y * BN;
    const int srow = tid >> 3;
    const int scol = ((tid & 7) ^ (srow & 7)) * 8;
    const bf16* Ab = A + rowA0 * K + scol;
    const bf16* Bb = B + rowB0 * K + scol;

    f32x4 acc[MI][NI];
    const f32x4 vz = {0.f, 0.f, 0.f, 0.f};
#pragma unroll
    for (int mi = 0; mi < MI; ++mi)
#pragma unroll
        for (int ni = 0; ni < NI; ++ni) acc[mi][ni] = vz;

    auto stage = [&](int buf, int kt) {
#pragma unroll
        for (int j = 0; j < 4; ++j)
            GLD(Ab + (long)(j * RG + srow) * K + kt, &As[buf][(j * RG + w * 8) * 64]);
#pragma unroll
        for (int j = 0; j < BG; ++j)
            GLD(Bb + (long)(j * RG + srow) * K + kt, &Bs[buf][(j * RG + w * 8) * 64]);
    };
    auto waitv = [&]() {
        if constexpr (BG == 4) asm volatile("s_waitcnt vmcnt(8)" ::: "memory");
        else                   asm volatile("s_waitcnt vmcnt(6)" ::: "memory");
    };
    auto compute = [&](int buf) {
        const char* AsB = (const char*)As[buf];
        const char* BsB = (const char*)Bs[buf];
#pragma unroll
        for (int s = 0; s < 2; ++s) {
            bf16x8 af[MI], bfr[NI];
#pragma unroll
            for (int mi = 0; mi < MI; ++mi) {
                int r = wm * WMR + mi * 16 + (lane & 15);
                af[mi] = *(const bf16x8*)(AsB + r * 128 + ((s * 64 + (lane >> 4) * 16) ^ ((r & 7) << 4)));
            }
#pragma unroll
            for (int ni = 0; ni < NI; ++ni) {
                int r = wn * 64 + ni * 16 + (lane & 15);
                bfr[ni] = *(const bf16x8*)(BsB + r * 128 + ((s * 64 + (lane >> 4) * 16) ^ ((r & 7) << 4)));
            }
#pragma unroll
            for (int mi = 0; mi < MI; ++mi)
#pragma unroll
                for (int ni = 0; ni < NI; ++ni)
                    acc[mi][ni] = __builtin_amdgcn_mfma_f32_16x16x32_bf16(af[mi], bfr[ni], acc[mi][ni], 0, 0, 0);
        }
    };

    stage(0, 0);
    stage(1, 64);
    int cur = 0;
    for (int kt = 128; kt < K; kt += 64) {
        waitv();
        bar_sync();
        compute(cur);
        bar_sync();
        stage(cur, kt);
        cur ^= 1;
    }
    waitv();
    bar_sync();
    compute(cur);
    asm volatile("s_waitcnt vmcnt(0)" ::: "memory");
    bar_sync();
    compute(cur ^ 1);

    const int crow = (lane >> 4) * 4;
    const int ccol = lane & 15;
#pragma unroll
    for (int mi = 0; mi < MI; ++mi)
#pragma unroll
        for (int ni = 0; ni < NI; ++ni) {
            long r0 = rowA0 + wm * WMR + mi * 16 + crow;
            long c0 = rowB0 + wn * 64 + ni * 16 + ccol;
#pragma unroll
            for (int j = 0; j < 4; ++j) {
                if constexpr (ACC) C[(r0 + j) * ldc + c0] += (OT)acc[mi][ni][j];
                else               C[(r0 + j) * ldc + c0]  = (OT)acc[mi][ni][j];
            }
        }
}

// ---------------- causal conv1d (k=4) + bias + silu, bf16 in/out ----------------
__global__ void k_conv(const bf16* __restrict__ zx, const float* __restrict__ cw,
                       const float* __restrict__ cb, bf16* __restrict__ co) {
    int idx = blockIdx.x * 256 + threadIdx.x;   // ROWS * 224
    int c8 = idx % 224; int blt = idx / 224;
    int t = blt % SEQ;
    int c0 = c8 * 8;
    long bbase = (long)(blt - t) * NPAD;
    float cwa[8][4];
#pragma unroll
    for (int j = 0; j < 8; ++j) {
        float4 tv = *(const float4*)(cw + (c0 + j) * 4);
        cwa[j][0] = tv.x; cwa[j][1] = tv.y; cwa[j][2] = tv.z; cwa[j][3] = tv.w;
    }
    float acc[8];
#pragma unroll
    for (int j = 0; j < 8; ++j) acc[j] = cb[c0 + j];
#pragma unroll
    for (int k = 0; k < 4; ++k) {
        int tt = t + k - 3;
        if (tt >= 0) {
            bf16x8 v = *(const bf16x8*)(zx + bbase + (long)tt * NPAD + DINNER + c0);
#pragma unroll
            for (int j = 0; j < 8; ++j) acc[j] += (float)v[j] * cwa[j][k];
        }
    }
    bf16x8 o;
#pragma unroll
    for (int j = 0; j < 8; ++j) o[j] = (bf16)fsilu(acc[j]);
    *(bf16x8*)(co + (long)blt * CONVDIM + c0) = o;
}

// ---------------- fused prep + stateL: scan math, XT global, XwT/BT in LDS, MFMA L ----------------
// grid NBHC, 256 threads (4 waves). Numerics bit-identical to prior prep->stateL.
__global__ __launch_bounds__(256) void k_prepL(const bf16* __restrict__ cobf, const bf16* __restrict__ zx,
                                               const float* __restrict__ dt_bias_l,
                                               const float* __restrict__ Alog,
                                               float* __restrict__ Sarr, float* __restrict__ dtc,
                                               float* __restrict__ Pcb,
                                               bf16* __restrict__ XT, bf16* __restrict__ Lbuf) {
    __shared__ float S_lds[128], wl_lds[128], wtot[2];
    __shared__ bf16 Xs[128][64];    // staging [t][64] (16 KB), reused for B halves
    __shared__ bf16 Xw[64 * 128];   // XwT swizzled (16 KB)
    __shared__ bf16 Bt[128 * 128];  // BT swizzled (32 KB)
    int blk = blockIdx.x;
    int b = blk / (NHEADS * NCH);
    int r = blk % (NHEADS * NCH);
    int h = r / NCH;
    int c = r % NCH;
    int tid = threadIdx.x, lane = tid & 63, wid = tid >> 6;
    long brow0 = (long)b * SEQ + c * QCH;
    // stage X chunk [128t][64p] via GLD (1024 x 16B)
#pragma unroll
    for (int i = 0; i < 4; ++i) {
        int idx = i * 256 + tid;
        GLD(cobf + (brow0 + (idx >> 3)) * CONVDIM + h * HEADDIM + (idx & 7) * 8,
            (char*)Xs + (i * 256 + wid * 64) * 16);
    }
    float ps = 0.f, dtv = 0.f;
    if (tid < 128) {
        float raw = (float)zx[(brow0 + tid) * NPAD + DINNER + CONVDIM + h] + dt_bias_l[h];
        dtv = (raw > 15.f) ? raw : log1pf(__expf(raw));
        float Ah = -__expf(Alog[h]);
        ps = dtv * Ah;
#pragma unroll
        for (int off = 1; off < 64; off <<= 1) {
            float o = __shfl_up(ps, off, 64);
            if ((tid & 63) >= off) ps += o;
        }
        if ((tid & 63) == 63) wtot[tid >> 6] = ps;
    }
    __syncthreads();
    if (tid < 128) {
        if (tid >= 64) ps += wtot[0];
        S_lds[tid] = ps;
    }
    __syncthreads();
    float Sl = S_lds[127];
    if (tid < 128) {
        wl_lds[tid] = __expf(Sl - ps) * dtv;
        Sarr[blk * QCH + tid] = ps;
        dtc[blk * QCH + tid] = dtv;
        if (tid == 127) Pcb[blk] = __expf(Sl);
    }
    __syncthreads();      // Xs + wl ready (syncthreads drains GLD)
    {
        int p = tid >> 2, q = tid & 3;
        char* xtb = (char*)XT + (((long)blk) << 14);
#pragma unroll
        for (int ub = 0; ub < 4; ++ub) {
            int u0 = q * 32 + ub * 8;
            bf16x8 vx, vw;
#pragma unroll
            for (int k = 0; k < 8; ++k) {
                int u = u0 + k;
                bf16 xv = Xs[u][p];
                vx[k] = xv;
                vw[k] = (bf16)((float)xv * wl_lds[u]);
            }
            long off = (long)((p * 256 + u0 * 2) ^ ((p & 7) << 4));
            *(bf16x8*)(xtb + off) = vx;
            *(bf16x8*)((char*)Xw + off) = vw;
        }
    }
    // B transpose into Bt, two 64-col halves, reusing Xs
#pragma unroll
    for (int nb = 0; nb < 2; ++nb) {
        __syncthreads();  // Xs readers done
#pragma unroll
        for (int i = 0; i < 4; ++i) {
            int idx = i * 256 + tid;
            GLD(cobf + (brow0 + (idx >> 3)) * CONVDIM + DINNER + nb * 64 + (idx & 7) * 8,
                (char*)Xs + (i * 256 + wid * 64) * 16);
        }
        __syncthreads();  // Xs ready
        int nl = tid >> 2, q = tid & 3;
        int n = nb * 64 + nl;
#pragma unroll
        for (int ub = 0; ub < 4; ++ub) {
            int u0 = q * 32 + ub * 8;
            bf16x8 v;
#pragma unroll
            for (int k = 0; k < 8; ++k) v[k] = Xs[u0 + k][nl];
            long off = (long)((n * 256 + u0 * 2) ^ ((n & 7) << 4));
            *(bf16x8*)((char*)Bt + off) = v;
        }
    }
    __syncthreads();      // Xw + Bt ready
    // L[p][n] = sum_u Xw[p][u] * B[u][n] via MFMA (A=Xw rows p, B=Bt rows n, k=u)
    f32x4 acc[4][2];
    const f32x4 vz = {0.f, 0.f, 0.f, 0.f};
#pragma unroll
    for (int mi = 0; mi < 4; ++mi)
#pragma unroll
        for (int ni = 0; ni < 2; ++ni) acc[mi][ni] = vz;
    const char* XwB = (const char*)Xw;
    const char* BtB = (const char*)Bt;
    __builtin_amdgcn_s_setprio(1);
#pragma unroll
    for (int ks = 0; ks < 4; ++ks) {
        bf16x8 af[4], bfr[2];
#pragma unroll
        for (int mi = 0; mi < 4; ++mi) {
            int pp = mi * 16 + (lane & 15);
            af[mi] = *(const bf16x8*)(XwB + ((pp * 256 + ks * 64 + (lane >> 4) * 16) ^ ((pp & 7) << 4)));
        }
#pragma unroll
        for (int ni = 0; ni < 2; ++ni) {
            int n = wid * 32 + ni * 16 + (lane & 15);
            bfr[ni] = *(const bf16x8*)(BtB + ((n * 256 + ks * 64 + (lane >> 4) * 16) ^ ((n & 7) << 4)));
        }
#pragma unroll
        for (int mi = 0; mi < 4; ++mi)
#pragma unroll
            for (int ni = 0; ni < 2; ++ni)
                acc[mi][ni] = __builtin_amdgcn_mfma_f32_16x16x32_bf16(af[mi], bfr[ni], acc[mi][ni], 0, 0, 0);
    }
    __builtin_amdgcn_s_setprio(0);
    char* lb = (char*)Lbuf + (((long)blk) << 14);
#pragma unroll
    for (int mi = 0; mi < 4; ++mi)
#pragma unroll
        for (int ni = 0; ni < 2; ++ni)
#pragma unroll
            for (int j = 0; j < 4; ++j) {
                int pp = mi * 16 + (lane >> 4) * 4 + j;
                int n = wid * 32 + ni * 16 + (lane & 15);
                *(bf16*)(lb + ((pp * 256 + n * 2) ^ ((pp & 7) << 4))) = (bf16)acc[mi][ni][j];
            }
}

// ---------------- Pass B: sequential inter-chunk combine ----------------
__global__ __launch_bounds__(256) void k_scanB(bf16* __restrict__ Lbuf, const float* __restrict__ Pc) {
    int bh = blockIdx.x >> 2;
    int q = blockIdx.x & 3;
    int off = (q * 256 + threadIdx.x) * 8;
    long base = ((long)bh * NCH) << 13;
    float s[8] = {0.f};
#pragma unroll
    for (int c = 0; c < NCH; ++c) {
        bf16* p = Lbuf + base + ((long)c << 13) + off;
        bf16x8 L = *(bf16x8*)p;
        bf16x8 I;
#pragma unroll
        for (int k = 0; k < 8; ++k) I[k] = (bf16)s[k];
        float P = Pc[bh * NCH + c];
#pragma unroll
        for (int k = 0; k < 8; ++k) s[k] = P * s[k] + (float)L[k];
        *(bf16x8*)p = I;
    }
}

// ---------------- chunk Y via MFMA -> bf16 ----------------
__global__ __launch_bounds__(512) void k_chunkY(const bf16* __restrict__ cobf,
                                                const float* __restrict__ Sarr, const float* __restrict__ dtc,
                                                const float* __restrict__ Dp,
                                                const bf16* __restrict__ XT, const bf16* __restrict__ Lbuf,
                                                bf16* __restrict__ ysb) {
    __shared__ bf16 Cs[128 * 128];
    __shared__ bf16 Bs[128 * 128];
    __shared__ bf16 Xts[64 * 128];
    __shared__ bf16 Is[64 * 128];
    __shared__ float S_lds[128], dt_lds[128];
    int blk = blockIdx.x;
    int b = blk / (NHEADS * NCH);
    int r = blk % (NHEADS * NCH);
    int h = r / NCH;
    int c = r % NCH;
    int tid = threadIdx.x, lane = tid & 63, wid = tid >> 6;
    long brow0 = (long)b * SEQ + c * QCH;
    const char* cob = (const char*)cobf;
#pragma unroll
    for (int i = 0; i < 4; ++i) {
        int trow = i * 32 + wid * 4 + (lane >> 4);
        int blk16 = lane & 15;
        const char* rp = cob + (brow0 + trow) * (CONVDIM * 2);
        int sb = (blk16 ^ (trow & 7)) << 4;
        GLD(rp + (DINNER + DSTATE) * 2 + sb, (char*)Cs + (i * 32 + wid * 4) * 256);
        GLD(rp + DINNER * 2 + sb, (char*)Bs + (i * 32 + wid * 4) * 256);
    }
    const char* xt = (const char*)XT + (((long)blk) << 14);
    const char* ib = (const char*)Lbuf + (((long)blk) << 14);
#pragma unroll
    for (int i = 0; i < 2; ++i) {
        GLD(xt + (long)(i * 512 + tid) * 16, (char*)Xts + (i * 512 + wid * 64) * 16);
        GLD(ib + (long)(i * 512 + tid) * 16, (char*)Is + (i * 512 + wid * 64) * 16);
    }
    if (tid < 128) { S_lds[tid] = Sarr[blk * QCH + tid]; dt_lds[tid] = dtc[blk * QCH + tid]; }
    float Dh = Dp[h];
    __syncthreads();
    const char* CsB = (const char*)Cs;
    char* BsB = (char*)Bs;
    const char* IsB = (const char*)Is;
    const char* XtB = (const char*)Xts;
    const f32x4 vz = {0.f, 0.f, 0.f, 0.f};
    int wmG = wid >> 2, wnG = wid & 3;
    f32x4 accg[4][2];
#pragma unroll
    for (int mi = 0; mi < 4; ++mi)
#pragma unroll
        for (int ni = 0; ni < 2; ++ni) accg[mi][ni] = vz;
#pragma unroll
    for (int ks = 0; ks < 4; ++ks) {
        bf16x8 af[4], bfr[2];
#pragma unroll
        for (int mi = 0; mi < 4; ++mi) {
            int t = wmG * 64 + mi * 16 + (lane & 15);
            af[mi] = *(const bf16x8*)(CsB + ((t * 256 + ks * 64 + (lane >> 4) * 16) ^ ((t & 7) << 4)));
        }
#pragma unroll
        for (int ni = 0; ni < 2; ++ni) {
            int u = wnG * 32 + ni * 16 + (lane & 15);
            bfr[ni] = *(const bf16x8*)(BsB + ((u * 256 + ks * 64 + (lane >> 4) * 16) ^ ((u & 7) << 4)));
        }
#pragma unroll
        for (int mi = 0; mi < 4; ++mi)
#pragma unroll
            for (int ni = 0; ni < 2; ++ni)
                accg[mi][ni] = __builtin_amdgcn_mfma_f32_16x16x32_bf16(af[mi], bfr[ni], accg[mi][ni], 0, 0, 0);
    }
    __syncthreads();
#pragma unroll
    for (int mi = 0; mi < 4; ++mi) {
#pragma unroll
        for (int j = 0; j < 4; ++j) {
            int t = wmG * 64 + mi * 16 + (lane >> 4) * 4 + j;
            float St = S_lds[t];
#pragma unroll
            for (int ni = 0; ni < 2; ++ni) {
                int u = wnG * 32 + ni * 16 + (lane & 15);
                float v = 0.f;
                if (u <= t) v = accg[mi][ni][j] * __expf(St - S_lds[u]) * dt_lds[u];
                *(bf16*)(BsB + ((t * 256 + u * 2) ^ ((t & 7) << 4))) = (bf16)v;
            }
        }
    }
    __syncthreads();
    int wmY = wid >> 1, wnY = wid & 1;
    f32x4 accy[2][2];
#pragma unroll
    for (int mi = 0; mi < 2; ++mi)
#pragma unroll
        for (int ni = 0; ni < 2; ++ni) accy[mi][ni] = vz;
#pragma unroll
    for (int ks = 0; ks < 4; ++ks) {
        bf16x8 af[2], bfr[2];
#pragma unroll
        for (int mi = 0; mi < 2; ++mi) {
            int t = wmY * 32 + mi * 16 + (lane & 15);
            af[mi] = *(const bf16x8*)(CsB + ((t * 256 + ks * 64 + (lane >> 4) * 16) ^ ((t & 7) << 4)));
        }
#pragma unroll
        for (int ni = 0; ni < 2; ++ni) {
            int pp = wnY * 32 + ni * 16 + (lane & 15);
            bfr[ni] = *(const bf16x8*)(IsB + ((pp * 256 + ks * 64 + (lane >> 4) * 16) ^ ((pp & 7) << 4)));
        }
#pragma unroll
        for (int mi = 0; mi < 2; ++mi)
#pragma unroll
            for (int ni = 0; ni < 2; ++ni)
                accy[mi][ni] = __builtin_amdgcn_mfma_f32_16x16x32_bf16(af[mi], bfr[ni], accy[mi][ni], 0, 0, 0);
    }
#pragma unroll
    for (int mi = 0; mi < 2; ++mi)
#pragma unroll
        for (int j = 0; j < 4; ++j) {
            int t = wmY * 32 + mi * 16 + (lane >> 4) * 4 + j;
            float e = __expf(S_lds[t]);
#pragma unroll
            for (int ni = 0; ni < 2; ++ni) accy[mi][ni][j] *= e;
        }
#pragma unroll
    for (int ks = 0; ks < 4; ++ks) {
        bf16x8 af[2], bfr[2];
#pragma unroll
        for (int mi = 0; mi < 2; ++mi) {
            int t = wmY * 32 + mi * 16 + (lane & 15);
            af[mi] = *(const bf16x8*)(BsB + ((t * 256 + ks * 64 + (lane >> 4) * 16) ^ ((t & 7) << 4)));
        }
#pragma unroll
        for (int ni = 0; ni < 2; ++ni) {
            int pp = wnY * 32 + ni * 16 + (lane & 15);
            bfr[ni] = *(const bf16x8*)(XtB + ((pp * 256 + ks * 64 + (lane >> 4) * 16) ^ ((pp & 7) << 4)));
        }
#pragma unroll
        for (int mi = 0; mi < 2; ++mi)
#pragma unroll
            for (int ni = 0; ni < 2; ++ni)
                accy[mi][ni] = __builtin_amdgcn_mfma_f32_16x16x32_bf16(af[mi], bfr[ni], accy[mi][ni], 0, 0, 0);
    }
#pragma unroll
    for (int mi = 0; mi < 2; ++mi)
#pragma unroll
        for (int ni = 0; ni < 2; ++ni)
#pragma unroll
            for (int j = 0; j < 4; ++j) {
                int t = wmY * 32 + mi * 16 + (lane >> 4) * 4 + j;
                int pp = wnY * 32 + ni * 16 + (lane & 15);
                float xv = (float)*(const bf16*)(XtB + ((pp * 256 + t * 2) ^ ((pp & 7) << 4)));
                ysb[(brow0 + t) * DINNER + h * HEADDIM + pp] = (bf16)(accy[mi][ni][j] + Dh * xv);
            }
}

// ---------------- gated rmsnorm ----------------
__global__ __launch_bounds__(256) void k_gated(const bf16* __restrict__ ys, const bf16* __restrict__ zx,
                                               const float* __restrict__ w, bf16* __restrict__ out) {
    __shared__ float sm[4];
    int r = blockIdx.x, tid = threadIdx.x;
    float v[6]; float ss = 0.f;
#pragma unroll
    for (int k = 0; k < 6; ++k) {
        int d = tid + k * 256;
        float z = (float)zx[(long)r * NPAD + d];
        float t = (float)ys[(long)r * DINNER + d] * fsilu(z);
        v[k] = t; ss += t * t;
    }
#pragma unroll
    for (int off = 32; off; off >>= 1) ss += __shfl_down(ss, off, 64);
    if ((tid & 63) == 0) sm[tid >> 6] = ss;
    __syncthreads();
    float tot = sm[0] + sm[1] + sm[2] + sm[3];
    float sc = rsqrtf(tot / (float)DINNER + EPS);
#pragma unroll
    for (int k = 0; k < 6; ++k) {
        int d = tid + k * 256;
        out[(long)r * DINNER + d] = (bf16)(v[k] * sc * w[d]);
    }
}

// ---------------- head: 32 rows/block, 1 atomic/block ----------------
__global__ __launch_bounds__(256) void k_head(const bf16* __restrict__ hn, const float* __restrict__ Wh,
                                              const float* __restrict__ y, float* __restrict__ out,
                                              float* __restrict__ loss) {
    __shared__ float sl[4];
    int tid = threadIdx.x, lane = tid & 63, wid = tid >> 6;
    float wv[5][12];
#pragma unroll
    for (int o = 0; o < 5; ++o)
#pragma unroll
        for (int j = 0; j < 12; ++j) wv[o][j] = Wh[o * DMODEL + lane * 12 + j];
    float lsum = 0.f;
#pragma unroll
    for (int rr = 0; rr < 8; ++rr) {
        long r = (long)blockIdx.x * 32 + wid * 8 + rr;
        const bf16* hp = hn + r * DMODEL + lane * 12;
        float hv[12];
#pragma unroll
        for (int q = 0; q < 3; ++q) {
            bf16x4 v4 = *(const bf16x4*)(hp + q * 4);
#pragma unroll
            for (int j = 0; j < 4; ++j) hv[q * 4 + j] = (float)v4[j];
        }
        float acc[5];
#pragma unroll
        for (int o = 0; o < 5; ++o) {
            float a = 0.f;
#pragma unroll
            for (int j = 0; j < 12; ++j) a += hv[j] * wv[o][j];
            acc[o] = a;
        }
#pragma unroll
        for (int o = 0; o < 5; ++o)
#pragma unroll
            for (int m = 32; m; m >>= 1) acc[o] += __shfl_xor(acc[o], m, 64);
        if (lane == 0) {
#pragma unroll
            for (int o = 0; o < 5; ++o) {
                out[r * 5 + o] = acc[o];
                float d = acc[o] - y[r * 5 + o];
                lsum += d * d;
            }
        }
    }
    if (lane == 0) sl[wid] = lsum;
    __syncthreads();
    if (tid == 0) atomicAdd(loss, (sl[0] + sl[1] + sl[2] + sl[3]) * (1.f / ((float)ROWS * 5.f)));
}

extern "C" void kernel_launch(void* const* d_in, const int* in_sizes, int n_in,
                              void* d_out, int out_size, void* d_ws, size_t ws_size,
                              hipStream_t stream) {
    const float* x      = (const float*)d_in[0];
    const float* y      = (const float*)d_in[1];
    const float* W_emb  = (const float*)d_in[2];
    const float* b_emb  = (const float*)d_in[3];
    const float* W_in   = (const float*)d_in[4];
    const float* conv_w = (const float*)d_in[5];
    const float* conv_b = (const float*)d_in[6];
    const float* dt_bias= (const float*)d_in[7];
    const float* A_log  = (const float*)d_in[8];
    const float* Dp     = (const float*)d_in[9];
    const float* norm_w = (const float*)d_in[10];
    const float* W_out  = (const float*)d_in[11];
    const float* bnw    = (const float*)d_in[12];
    const float* nfw    = (const float*)d_in[13];
    const float* W_head = (const float*)d_in[14];

    char* ws = (char*)d_ws;
    float* res  = (float*)ws;  ws += (size_t)ROWS * DMODEL * 4;
    bf16*  Lbuf = (bf16*)ws;   ws += (size_t)BATCH * NHEADS * NCH * 8192 * 2;
    bf16*  hnb  = (bf16*)ws;   ws += (size_t)ROWS * DMODEL * 2;
    bf16*  zx   = (bf16*)ws;   ws += (size_t)ROWS * NPAD * 2;
    bf16*  cobf = (bf16*)ws;   ws += (size_t)ROWS * CONVDIM * 2;
    bf16*  ysb  = (bf16*)ws;   ws += (size_t)ROWS * DINNER * 2;
    bf16*  yfb  = (bf16*)ws;   ws += (size_t)ROWS * DINNER * 2;
    bf16*  Wib  = (bf16*)ws;   ws += (size_t)NLAYER * NPAD * DMODEL * 2;
    bf16*  Wob  = (bf16*)ws;   ws += (size_t)NLAYER * DMODEL * DINNER * 2;
    float* Pcb  = (float*)ws;  ws += (size_t)BATCH * NHEADS * NCH * 4;
    float* Sarr = (float*)ws;  ws += (size_t)BATCH * NHEADS * NCH * QCH * 4;
    float* dtc  = (float*)ws;  ws += (size_t)BATCH * NHEADS * NCH * QCH * 4;
    bf16*  XT   = (bf16*)ws;   ws += (size_t)BATCH * NHEADS * NCH * 8192 * 2;

    float* out_p  = (float*)d_out;
    float* loss_p = out_p + (size_t)ROWS * 5;

    hipMemsetAsync(loss_p, 0, 4, stream);
    k_embed<<<ROWS * DMODEL / 256, 256, 0, stream>>>(x, W_emb, b_emb, res);
    k_cvt_in<<<NLAYER * NPAD * DMODEL / 256, 256, 0, stream>>>(W_in, Wib);
    k_cvt_out<<<NLAYER * DMODEL * DINNER / 256, 256, 0, stream>>>(W_out, Wob);

    const int NBHC = BATCH * NHEADS * NCH;   // 1536
    for (int l = 0; l < NLAYER; ++l) {
        k_rmsnorm<<<ROWS, 256, 0, stream>>>(res, bnw + l * DMODEL, hnb);
        dim3 g1(ROWS / 128, NPAD / 128);
        k_gemm<bf16, 128, 128, false><<<g1, 256, 0, stream>>>(hnb, Wib + (size_t)l * NPAD * DMODEL, zx, DMODEL, NPAD);
        k_conv<<<ROWS * 224 / 256, 256, 0, stream>>>(zx, conv_w + (size_t)l * CONVDIM * 4, conv_b + l * CONVDIM, cobf);
        k_prepL<<<NBHC, 256, 0, stream>>>(cobf, zx, dt_bias + l * NHEADS, A_log + l * NHEADS, Sarr, dtc, Pcb, XT, Lbuf);
        k_scanB<<<BATCH * NHEADS * 4, 256, 0, stream>>>(Lbuf, Pcb);
        k_chunkY<<<NBHC, 512, 0, stream>>>(cobf, Sarr, dtc, Dp + l * NHEADS, XT, Lbuf, ysb);
        k_gated<<<ROWS, 256, 0, stream>>>(ysb, zx, norm_w + l * DINNER, yfb);
        dim3 g2(ROWS / 128, DMODEL / 64);
        k_gemm<float, 128, 64, true><<<g2, 256, 0, stream>>>(yfb, Wob + (size_t)l * DMODEL * DINNER, res, DINNER, DMODEL);
    }

    k_rmsnorm<<<ROWS, 256, 0, stream>>>(res, nfw, hnb);
    k_head<<<256, 256, 0, stream>>>(hnb, W_head, y, out_p, loss_p);
}

// Round 9
// 1978.995 us; speedup vs baseline: 5.8720x; 1.1098x over previous
//
#include <hip/hip_runtime.h>
#include <hip/hip_bf16.h>
#include <math.h>

#define BATCH 4
#define SEQ 2048
#define DMODEL 768
#define NLAYER 8
#define DINNER 1536
#define HEADDIM 64
#define NHEADS 24
#define DSTATE 128
#define CONVDIM 1792
#define DINPROJ 3352
#define NPAD 3456
#define ROWS (BATCH*SEQ)
#define EPS 1e-5f
#define QCH 128
#define NCH (SEQ/QCH)

typedef __bf16 bf16;
typedef bf16 bf16x8 __attribute__((ext_vector_type(8)));
typedef bf16 bf16x4 __attribute__((ext_vector_type(4)));
typedef float f32x4 __attribute__((ext_vector_type(4)));

#define GLD(src, dst) __builtin_amdgcn_global_load_lds( \
    (const __attribute__((address_space(1))) void*)(src), \
    (__attribute__((address_space(3))) void*)(dst), 16, 0, 0)

__device__ __forceinline__ void bar_sync() {
    asm volatile("" ::: "memory");
    __builtin_amdgcn_s_barrier();
    asm volatile("" ::: "memory");
}

__device__ __forceinline__ float fsilu(float x) { return x / (1.f + __expf(-x)); }

// ---------------- embed: res = x @ W_emb^T + b_emb ----------------
__global__ void k_embed(const float* __restrict__ x, const float* __restrict__ We,
                        const float* __restrict__ be, float* __restrict__ res) {
    int idx = blockIdx.x * 256 + threadIdx.x;
    int d = idx % DMODEL; int bl = idx / DMODEL;
    float acc = be[d];
#pragma unroll
    for (int i = 0; i < 6; ++i) acc += x[bl * 6 + i] * We[d * 6 + i];
    res[idx] = acc;
}

// ---------------- read-only rmsnorm ----------------
__global__ __launch_bounds__(256) void k_rmsnorm(const float* __restrict__ res,
                                                 const float* __restrict__ w,
                                                 bf16* __restrict__ out) {
    __shared__ float sm[4];
    int r = blockIdx.x, tid = threadIdx.x;
    float v[3]; float ss = 0.f;
#pragma unroll
    for (int k = 0; k < 3; ++k) {
        int d = tid + k * 256;
        float t = res[r * DMODEL + d];
        v[k] = t; ss += t * t;
    }
#pragma unroll
    for (int off = 32; off; off >>= 1) ss += __shfl_down(ss, off, 64);
    if ((tid & 63) == 0) sm[tid >> 6] = ss;
    __syncthreads();
    float tot = sm[0] + sm[1] + sm[2] + sm[3];
    float sc = rsqrtf(tot / (float)DMODEL + EPS);
#pragma unroll
    for (int k = 0; k < 3; ++k) {
        int d = tid + k * 256;
        out[r * DMODEL + d] = (bf16)(v[k] * sc * w[d]);
    }
}

// ---------------- batched weight conversions ----------------
__global__ void k_cvt_in(const float* __restrict__ src, bf16* __restrict__ dst) {
    int idx = blockIdx.x * 256 + threadIdx.x;
    int l = idx / (NPAD * DMODEL);
    int rem = idx % (NPAD * DMODEL);
    int n = rem / DMODEL;
    int d = rem % DMODEL;
    dst[idx] = (n < DINPROJ) ? (bf16)src[(long)l * DINPROJ * DMODEL + n * DMODEL + d] : (bf16)0.f;
}
__global__ void k_cvt_out(const float* __restrict__ src, bf16* __restrict__ dst) {
    int idx = blockIdx.x * 256 + threadIdx.x;
    dst[idx] = (bf16)src[idx];
}

// ---------------- bf16 MFMA GEMM: C[M,N] (=|+=) A[M,K] @ B[N,K]^T ----------------
// counted-vmcnt depth-2 pipeline, XOR-swizzled LDS, XCD-chunked block swizzle.
template <typename OT, int BM, int BN, bool ACC>
__global__ __launch_bounds__(256) void k_gemm(const bf16* __restrict__ A, const bf16* __restrict__ B,
                                              OT* __restrict__ C, int K, int ldc) {
    constexpr int nWn = BN / 64;
    constexpr int nWm = 4 / nWn;
    constexpr int WMR = BM / nWm;
    constexpr int MI  = WMR / 16;
    constexpr int NI  = 4;
    constexpr int RG  = BM / 4;
    constexpr int BG  = BN / RG;
    __shared__ bf16 As[2][BM * 64];
    __shared__ bf16 Bs[2][BN * 64];
    const int tid = threadIdx.x;
    const int lane = tid & 63;
    const int w = tid >> 6;
    const int wm = w / nWn, wn = w % nWn;
    // XCD-chunked bijective swizzle (nwg % 8 == 0 for all our launches)
    int wg = blockIdx.x + blockIdx.y * gridDim.x;
    int cpx = (gridDim.x * gridDim.y) >> 3;
    int swz = (wg & 7) * cpx + (wg >> 3);
    int bx = swz % gridDim.x;
    int by = swz / gridDim.x;
    const long rowA0 = (long)bx * BM;
    const long rowB0 = (long)by * BN;
    const int srow = tid >> 3;
    const int scol = ((tid & 7) ^ (srow & 7)) * 8;
    const bf16* Ab = A + rowA0 * K + scol;
    const bf16* Bb = B + rowB0 * K + scol;

    f32x4 acc[MI][NI];
    const f32x4 vz = {0.f, 0.f, 0.f, 0.f};
#pragma unroll
    for (int mi = 0; mi < MI; ++mi)
#pragma unroll
        for (int ni = 0; ni < NI; ++ni) acc[mi][ni] = vz;

    auto stage = [&](int buf, int kt) {
#pragma unroll
        for (int j = 0; j < 4; ++j)
            GLD(Ab + (long)(j * RG + srow) * K + kt, &As[buf][(j * RG + w * 8) * 64]);
#pragma unroll
        for (int j = 0; j < BG; ++j)
            GLD(Bb + (long)(j * RG + srow) * K + kt, &Bs[buf][(j * RG + w * 8) * 64]);
    };
    auto waitv = [&]() {
        if constexpr (BG == 4) asm volatile("s_waitcnt vmcnt(8)" ::: "memory");
        else                   asm volatile("s_waitcnt vmcnt(6)" ::: "memory");
    };
    auto compute = [&](int buf) {
        const char* AsB = (const char*)As[buf];
        const char* BsB = (const char*)Bs[buf];
#pragma unroll
        for (int s = 0; s < 2; ++s) {
            bf16x8 af[MI], bfr[NI];
#pragma unroll
            for (int mi = 0; mi < MI; ++mi) {
                int r = wm * WMR + mi * 16 + (lane & 15);
                af[mi] = *(const bf16x8*)(AsB + r * 128 + ((s * 64 + (lane >> 4) * 16) ^ ((r & 7) << 4)));
            }
#pragma unroll
            for (int ni = 0; ni < NI; ++ni) {
                int r = wn * 64 + ni * 16 + (lane & 15);
                bfr[ni] = *(const bf16x8*)(BsB + r * 128 + ((s * 64 + (lane >> 4) * 16) ^ ((r & 7) << 4)));
            }
#pragma unroll
            for (int mi = 0; mi < MI; ++mi)
#pragma unroll
                for (int ni = 0; ni < NI; ++ni)
                    acc[mi][ni] = __builtin_amdgcn_mfma_f32_16x16x32_bf16(af[mi], bfr[ni], acc[mi][ni], 0, 0, 0);
        }
    };

    stage(0, 0);
    stage(1, 64);
    int cur = 0;
    for (int kt = 128; kt < K; kt += 64) {
        waitv();
        bar_sync();
        compute(cur);
        bar_sync();
        stage(cur, kt);
        cur ^= 1;
    }
    waitv();
    bar_sync();
    compute(cur);
    asm volatile("s_waitcnt vmcnt(0)" ::: "memory");
    bar_sync();
    compute(cur ^ 1);

    const int crow = (lane >> 4) * 4;
    const int ccol = lane & 15;
#pragma unroll
    for (int mi = 0; mi < MI; ++mi)
#pragma unroll
        for (int ni = 0; ni < NI; ++ni) {
            long r0 = rowA0 + wm * WMR + mi * 16 + crow;
            long c0 = rowB0 + wn * 64 + ni * 16 + ccol;
#pragma unroll
            for (int j = 0; j < 4; ++j) {
                if constexpr (ACC) C[(r0 + j) * ldc + c0] += (OT)acc[mi][ni][j];
                else               C[(r0 + j) * ldc + c0]  = (OT)acc[mi][ni][j];
            }
        }
}

// ---------------- slim conv for B/C channels only -> bc[ROWS][256] ----------------
__global__ void k_convBC(const bf16* __restrict__ zx, const float* __restrict__ cw,
                         const float* __restrict__ cb, bf16* __restrict__ bc) {
    int idx = blockIdx.x * 256 + threadIdx.x;   // ROWS * 32
    int c8 = idx & 31; int blt = idx >> 5;
    int t = blt % SEQ;
    int ch = DINNER + c8 * 8;                   // conv-space channel (B/C region)
    long bbase = (long)(blt - t) * NPAD;
    float cwa[8][4];
#pragma unroll
    for (int j = 0; j < 8; ++j) {
        float4 tv = *(const float4*)(cw + (ch + j) * 4);
        cwa[j][0] = tv.x; cwa[j][1] = tv.y; cwa[j][2] = tv.z; cwa[j][3] = tv.w;
    }
    float acc[8];
#pragma unroll
    for (int j = 0; j < 8; ++j) acc[j] = cb[ch + j];
#pragma unroll
    for (int k = 0; k < 4; ++k) {
        int tt = t + k - 3;
        if (tt >= 0) {
            bf16x8 v = *(const bf16x8*)(zx + bbase + (long)tt * NPAD + DINNER + ch);
#pragma unroll
            for (int j = 0; j < 8; ++j) acc[j] += (float)v[j] * cwa[j][k];
        }
    }
    bf16x8 o;
#pragma unroll
    for (int j = 0; j < 8; ++j) o[j] = (bf16)fsilu(acc[j]);
    *(bf16x8*)(bc + (long)blt * 256 + c8 * 8) = o;
}

// ---------------- fused conv(X) + prep + stateL ----------------
// grid NBHC, 256 threads. Conv for this head's 64 X-channels computed in-kernel
// (bit-identical f32 op order to the old k_conv), B from compact bc buffer.
__global__ __launch_bounds__(256) void k_prepL(const bf16* __restrict__ zx, const bf16* __restrict__ bc,
                                               const float* __restrict__ cw_l, const float* __restrict__ cb_l,
                                               const float* __restrict__ dt_bias_l,
                                               const float* __restrict__ Alog,
                                               float* __restrict__ Sarr, float* __restrict__ dtc,
                                               float* __restrict__ Pcb,
                                               bf16* __restrict__ XT, bf16* __restrict__ Lbuf) {
    __shared__ float S_lds[128], wl_lds[128], wtot[2];
    __shared__ bf16 Xs[136 * 64];   // raw zx X rows (chunk-3 .. +132), 17 KB; reused for B halves
    __shared__ bf16 Xw[64 * 128];   // XwT swizzled
    __shared__ bf16 Bt[128 * 128];  // BT swizzled
    int blk = blockIdx.x;
    int b = blk / (NHEADS * NCH);
    int r = blk % (NHEADS * NCH);
    int h = r / NCH;
    int c = r % NCH;
    int tid = threadIdx.x, lane = tid & 63, wid = tid >> 6;
    long brow0 = (long)b * SEQ + c * QCH;
    // stage raw X rows brow0-3 .. (131 rows, clamped); 1048 x 16B chunks
#pragma unroll
    for (int i = 0; i < 5; ++i) {
        int base = i * 256 + wid * 64;          // wave-uniform
        if (base < 1048) {
            int idx = base + lane;
            long g = brow0 - 3 + (idx >> 3);
            if (g < 0) g = 0;
            if (g > (long)ROWS - 1) g = (long)ROWS - 1;
            GLD(zx + g * NPAD + DINNER + h * HEADDIM + (idx & 7) * 8,
                (char*)Xs + (long)base * 16);
        }
    }
    float ps = 0.f, dtv = 0.f;
    if (tid < 128) {
        float raw = (float)zx[(brow0 + tid) * NPAD + DINNER + CONVDIM + h] + dt_bias_l[h];
        dtv = (raw > 15.f) ? raw : log1pf(__expf(raw));
        float Ah = -__expf(Alog[h]);
        ps = dtv * Ah;
#pragma unroll
        for (int off = 1; off < 64; off <<= 1) {
            float o = __shfl_up(ps, off, 64);
            if ((tid & 63) >= off) ps += o;
        }
        if ((tid & 63) == 63) wtot[tid >> 6] = ps;
    }
    __syncthreads();
    if (tid < 128) {
        if (tid >= 64) ps += wtot[0];
        S_lds[tid] = ps;
    }
    __syncthreads();
    float Sl = S_lds[127];
    if (tid < 128) {
        wl_lds[tid] = __expf(Sl - ps) * dtv;
        Sarr[blk * QCH + tid] = ps;
        dtc[blk * QCH + tid] = dtv;
        if (tid == 127) Pcb[blk] = __expf(Sl);
    }
    __syncthreads();      // Xs staged (vmcnt drained) + wl ready
    {
        int p = tid >> 2, q = tid & 3;
        float4 cwv = *(const float4*)(cw_l + (h * HEADDIM + p) * 4);
        float cbv = cb_l[h * HEADDIM + p];
        float cwa[4] = {cwv.x, cwv.y, cwv.z, cwv.w};
        char* xtb = (char*)XT + (((long)blk) << 14);
#pragma unroll
        for (int ub = 0; ub < 4; ++ub) {
            int u0 = q * 32 + ub * 8;
            bf16x8 vx, vw;
#pragma unroll
            for (int k = 0; k < 8; ++k) {
                int u = u0 + k;
                float a = cbv;
#pragma unroll
                for (int tt = 0; tt < 4; ++tt) {
                    if (c > 0 || u + tt >= 3)
                        a += (float)Xs[(u + tt) * 64 + p] * cwa[tt];
                }
                bf16 xb = (bf16)fsilu(a);
                vx[k] = xb;
                vw[k] = (bf16)((float)xb * wl_lds[u]);
            }
            long off = (long)((p * 256 + u0 * 2) ^ ((p & 7) << 4));
            *(bf16x8*)(xtb + off) = vx;
            *(bf16x8*)((char*)Xw + off) = vw;
        }
    }
    // B transpose into Bt from compact bc, two 64-col halves, reusing Xs
#pragma unroll
    for (int nb = 0; nb < 2; ++nb) {
        __syncthreads();  // Xs readers done
#pragma unroll
        for (int i = 0; i < 4; ++i) {
            int idx = i * 256 + tid;
            GLD(bc + (brow0 + (idx >> 3)) * 256 + nb * 64 + (idx & 7) * 8,
                (char*)Xs + (i * 256 + wid * 64) * 16);
        }
        __syncthreads();  // Xs ready
        int nl = tid >> 2, q = tid & 3;
        int n = nb * 64 + nl;
#pragma unroll
        for (int ub = 0; ub < 4; ++ub) {
            int u0 = q * 32 + ub * 8;
            bf16x8 v;
#pragma unroll
            for (int k = 0; k < 8; ++k) v[k] = Xs[(u0 + k) * 64 + nl];
            long off = (long)((n * 256 + u0 * 2) ^ ((n & 7) << 4));
            *(bf16x8*)((char*)Bt + off) = v;
        }
    }
    __syncthreads();      // Xw + Bt ready
    f32x4 acc[4][2];
    const f32x4 vz = {0.f, 0.f, 0.f, 0.f};
#pragma unroll
    for (int mi = 0; mi < 4; ++mi)
#pragma unroll
        for (int ni = 0; ni < 2; ++ni) acc[mi][ni] = vz;
    const char* XwB = (const char*)Xw;
    const char* BtB = (const char*)Bt;
    __builtin_amdgcn_s_setprio(1);
#pragma unroll
    for (int ks = 0; ks < 4; ++ks) {
        bf16x8 af[4], bfr[2];
#pragma unroll
        for (int mi = 0; mi < 4; ++mi) {
            int pp = mi * 16 + (lane & 15);
            af[mi] = *(const bf16x8*)(XwB + ((pp * 256 + ks * 64 + (lane >> 4) * 16) ^ ((pp & 7) << 4)));
        }
#pragma unroll
        for (int ni = 0; ni < 2; ++ni) {
            int n = wid * 32 + ni * 16 + (lane & 15);
            bfr[ni] = *(const bf16x8*)(BtB + ((n * 256 + ks * 64 + (lane >> 4) * 16) ^ ((n & 7) << 4)));
        }
#pragma unroll
        for (int mi = 0; mi < 4; ++mi)
#pragma unroll
            for (int ni = 0; ni < 2; ++ni)
                acc[mi][ni] = __builtin_amdgcn_mfma_f32_16x16x32_bf16(af[mi], bfr[ni], acc[mi][ni], 0, 0, 0);
    }
    __builtin_amdgcn_s_setprio(0);
    char* lb = (char*)Lbuf + (((long)blk) << 14);
#pragma unroll
    for (int mi = 0; mi < 4; ++mi)
#pragma unroll
        for (int ni = 0; ni < 2; ++ni)
#pragma unroll
            for (int j = 0; j < 4; ++j) {
                int pp = mi * 16 + (lane >> 4) * 4 + j;
                int n = wid * 32 + ni * 16 + (lane & 15);
                *(bf16*)(lb + ((pp * 256 + n * 2) ^ ((pp & 7) << 4))) = (bf16)acc[mi][ni][j];
            }
}

// ---------------- Pass B: sequential inter-chunk combine ----------------
__global__ __launch_bounds__(256) void k_scanB(bf16* __restrict__ Lbuf, const float* __restrict__ Pc) {
    int bh = blockIdx.x >> 2;
    int q = blockIdx.x & 3;
    int off = (q * 256 + threadIdx.x) * 8;
    long base = ((long)bh * NCH) << 13;
    float s[8] = {0.f};
#pragma unroll
    for (int c = 0; c < NCH; ++c) {
        bf16* p = Lbuf + base + ((long)c << 13) + off;
        bf16x8 L = *(bf16x8*)p;
        bf16x8 I;
#pragma unroll
        for (int k = 0; k < 8; ++k) I[k] = (bf16)s[k];
        float P = Pc[bh * NCH + c];
#pragma unroll
        for (int k = 0; k < 8; ++k) s[k] = P * s[k] + (float)L[k];
        *(bf16x8*)p = I;
    }
}

// ---------------- chunk Y via MFMA -> bf16 (bc source, counted-vmcnt pipeline) ----------------
__global__ __launch_bounds__(512) void k_chunkY(const bf16* __restrict__ bc,
                                                const float* __restrict__ Sarr, const float* __restrict__ dtc,
                                                const float* __restrict__ Dp,
                                                const bf16* __restrict__ XT, const bf16* __restrict__ Lbuf,
                                                bf16* __restrict__ ysb) {
    __shared__ bf16 Cs[128 * 128];
    __shared__ bf16 Bs[128 * 128];
    __shared__ bf16 Xts[64 * 128];
    __shared__ bf16 Is[64 * 128];
    __shared__ float S_lds[128], dt_lds[128];
    int blk = blockIdx.x;
    int b = blk / (NHEADS * NCH);
    int r = blk % (NHEADS * NCH);
    int h = r / NCH;
    int c = r % NCH;
    int tid = threadIdx.x, lane = tid & 63, wid = tid >> 6;
    long brow0 = (long)b * SEQ + c * QCH;
    const char* bcB = (const char*)bc;
    // Cs/Bs first (8 GLDs) ...
#pragma unroll
    for (int i = 0; i < 4; ++i) {
        int trow = i * 32 + wid * 4 + (lane >> 4);
        int blk16 = lane & 15;
        const char* rp = bcB + (brow0 + trow) * 512;
        int sb = (blk16 ^ (trow & 7)) << 4;
        GLD(rp + 256 + sb, (char*)Cs + (i * 32 + wid * 4) * 256);   // C cols 128..255
        GLD(rp + sb,       (char*)Bs + (i * 32 + wid * 4) * 256);   // B cols 0..127
    }
    // ... then Xts/Is (4 GLDs) — stay in flight across the first barrier
    const char* xt = (const char*)XT + (((long)blk) << 14);
    const char* ib = (const char*)Lbuf + (((long)blk) << 14);
#pragma unroll
    for (int i = 0; i < 2; ++i) {
        GLD(xt + (long)(i * 512 + tid) * 16, (char*)Xts + (i * 512 + wid * 64) * 16);
        GLD(ib + (long)(i * 512 + tid) * 16, (char*)Is + (i * 512 + wid * 64) * 16);
    }
    if (tid < 128) { S_lds[tid] = Sarr[blk * QCH + tid]; dt_lds[tid] = dtc[blk * QCH + tid]; }
    float Dh = Dp[h];
    asm volatile("s_waitcnt vmcnt(4) lgkmcnt(0)" ::: "memory");   // Cs/Bs + S_lds ready; Xts/Is in flight
    bar_sync();
    const char* CsB = (const char*)Cs;
    char* BsB = (char*)Bs;
    const char* IsB = (const char*)Is;
    const char* XtB = (const char*)Xts;
    const f32x4 vz = {0.f, 0.f, 0.f, 0.f};
    int wmG = wid >> 2, wnG = wid & 3;
    f32x4 accg[4][2];
#pragma unroll
    for (int mi = 0; mi < 4; ++mi)
#pragma unroll
        for (int ni = 0; ni < 2; ++ni) accg[mi][ni] = vz;
#pragma unroll
    for (int ks = 0; ks < 4; ++ks) {
        bf16x8 af[4], bfr[2];
#pragma unroll
        for (int mi = 0; mi < 4; ++mi) {
            int t = wmG * 64 + mi * 16 + (lane & 15);
            af[mi] = *(const bf16x8*)(CsB + ((t * 256 + ks * 64 + (lane >> 4) * 16) ^ ((t & 7) << 4)));
        }
#pragma unroll
        for (int ni = 0; ni < 2; ++ni) {
            int u = wnG * 32 + ni * 16 + (lane & 15);
            bfr[ni] = *(const bf16x8*)(BsB + ((u * 256 + ks * 64 + (lane >> 4) * 16) ^ ((u & 7) << 4)));
        }
#pragma unroll
        for (int mi = 0; mi < 4; ++mi)
#pragma unroll
            for (int ni = 0; ni < 2; ++ni)
                accg[mi][ni] = __builtin_amdgcn_mfma_f32_16x16x32_bf16(af[mi], bfr[ni], accg[mi][ni], 0, 0, 0);
    }
    bar_sync();           // all G reads of Bs retired (consumed by MFMAs above)
#pragma unroll
    for (int mi = 0; mi < 4; ++mi) {
#pragma unroll
        for (int j = 0; j < 4; ++j) {
            int t = wmG * 64 + mi * 16 + (lane >> 4) * 4 + j;
            float St = S_lds[t];
#pragma unroll
            for (int ni = 0; ni < 2; ++ni) {
                int u = wnG * 32 + ni * 16 + (lane & 15);
                float v = 0.f;
                if (u <= t) v = accg[mi][ni][j] * __expf(St - S_lds[u]) * dt_lds[u];
                *(bf16*)(BsB + ((t * 256 + u * 2) ^ ((t & 7) << 4))) = (bf16)v;
            }
        }
    }
    asm volatile("s_waitcnt vmcnt(0) lgkmcnt(0)" ::: "memory");   // Xts/Is landed; MG writes drained
    bar_sync();
    int wmY = wid >> 1, wnY = wid & 1;
    f32x4 accy[2][2];
#pragma unroll
    for (int mi = 0; mi < 2; ++mi)
#pragma unroll
        for (int ni = 0; ni < 2; ++ni) accy[mi][ni] = vz;
#pragma unroll
    for (int ks = 0; ks < 4; ++ks) {
        bf16x8 af[2], bfr[2];
#pragma unroll
        for (int mi = 0; mi < 2; ++mi) {
            int t = wmY * 32 + mi * 16 + (lane & 15);
            af[mi] = *(const bf16x8*)(CsB + ((t * 256 + ks * 64 + (lane >> 4) * 16) ^ ((t & 7) << 4)));
        }
#pragma unroll
        for (int ni = 0; ni < 2; ++ni) {
            int pp = wnY * 32 + ni * 16 + (lane & 15);
            bfr[ni] = *(const bf16x8*)(IsB + ((pp * 256 + ks * 64 + (lane >> 4) * 16) ^ ((pp & 7) << 4)));
        }
#pragma unroll
        for (int mi = 0; mi < 2; ++mi)
#pragma unroll
            for (int ni = 0; ni < 2; ++ni)
                accy[mi][ni] = __builtin_amdgcn_mfma_f32_16x16x32_bf16(af[mi], bfr[ni], accy[mi][ni], 0, 0, 0);
    }
#pragma unroll
    for (int mi = 0; mi < 2; ++mi)
#pragma unroll
        for (int j = 0; j < 4; ++j) {
            int t = wmY * 32 + mi * 16 + (lane >> 4) * 4 + j;
            float e = __expf(S_lds[t]);
#pragma unroll
            for (int ni = 0; ni < 2; ++ni) accy[mi][ni][j] *= e;
        }
#pragma unroll
    for (int ks = 0; ks < 4; ++ks) {
        bf16x8 af[2], bfr[2];
#pragma unroll
        for (int mi = 0; mi < 2; ++mi) {
            int t = wmY * 32 + mi * 16 + (lane & 15);
            af[mi] = *(const bf16x8*)(BsB + ((t * 256 + ks * 64 + (lane >> 4) * 16) ^ ((t & 7) << 4)));
        }
#pragma unroll
        for (int ni = 0; ni < 2; ++ni) {
            int pp = wnY * 32 + ni * 16 + (lane & 15);
            bfr[ni] = *(const bf16x8*)(XtB + ((pp * 256 + ks * 64 + (lane >> 4) * 16) ^ ((pp & 7) << 4)));
        }
#pragma unroll
        for (int mi = 0; mi < 2; ++mi)
#pragma unroll
            for (int ni = 0; ni < 2; ++ni)
                accy[mi][ni] = __builtin_amdgcn_mfma_f32_16x16x32_bf16(af[mi], bfr[ni], accy[mi][ni], 0, 0, 0);
    }
#pragma unroll
    for (int mi = 0; mi < 2; ++mi)
#pragma unroll
        for (int ni = 0; ni < 2; ++ni)
#pragma unroll
            for (int j = 0; j < 4; ++j) {
                int t = wmY * 32 + mi * 16 + (lane >> 4) * 4 + j;
                int pp = wnY * 32 + ni * 16 + (lane & 15);
                float xv = (float)*(const bf16*)(XtB + ((pp * 256 + t * 2) ^ ((pp & 7) << 4)));
                ysb[(brow0 + t) * DINNER + h * HEADDIM + pp] = (bf16)(accy[mi][ni][j] + Dh * xv);
            }
}

// ---------------- gated rmsnorm ----------------
__global__ __launch_bounds__(256) void k_gated(const bf16* __restrict__ ys, const bf16* __restrict__ zx,
                                               const float* __restrict__ w, bf16* __restrict__ out) {
    __shared__ float sm[4];
    int r = blockIdx.x, tid = threadIdx.x;
    float v[6]; float ss = 0.f;
#pragma unroll
    for (int k = 0; k < 6; ++k) {
        int d = tid + k * 256;
        float z = (float)zx[(long)r * NPAD + d];
        float t = (float)ys[(long)r * DINNER + d] * fsilu(z);
        v[k] = t; ss += t * t;
    }
#pragma unroll
    for (int off = 32; off; off >>= 1) ss += __shfl_down(ss, off, 64);
    if ((tid & 63) == 0) sm[tid >> 6] = ss;
    __syncthreads();
    float tot = sm[0] + sm[1] + sm[2] + sm[3];
    float sc = rsqrtf(tot / (float)DINNER + EPS);
#pragma unroll
    for (int k = 0; k < 6; ++k) {
        int d = tid + k * 256;
        out[(long)r * DINNER + d] = (bf16)(v[k] * sc * w[d]);
    }
}

// ---------------- head: 32 rows/block, 1 atomic/block ----------------
__global__ __launch_bounds__(256) void k_head(const bf16* __restrict__ hn, const float* __restrict__ Wh,
                                              const float* __restrict__ y, float* __restrict__ out,
                                              float* __restrict__ loss) {
    __shared__ float sl[4];
    int tid = threadIdx.x, lane = tid & 63, wid = tid >> 6;
    float wv[5][12];
#pragma unroll
    for (int o = 0; o < 5; ++o)
#pragma unroll
        for (int j = 0; j < 12; ++j) wv[o][j] = Wh[o * DMODEL + lane * 12 + j];
    float lsum = 0.f;
#pragma unroll
    for (int rr = 0; rr < 8; ++rr) {
        long r = (long)blockIdx.x * 32 + wid * 8 + rr;
        const bf16* hp = hn + r * DMODEL + lane * 12;
        float hv[12];
#pragma unroll
        for (int q = 0; q < 3; ++q) {
            bf16x4 v4 = *(const bf16x4*)(hp + q * 4);
#pragma unroll
            for (int j = 0; j < 4; ++j) hv[q * 4 + j] = (float)v4[j];
        }
        float acc[5];
#pragma unroll
        for (int o = 0; o < 5; ++o) {
            float a = 0.f;
#pragma unroll
            for (int j = 0; j < 12; ++j) a += hv[j] * wv[o][j];
            acc[o] = a;
        }
#pragma unroll
        for (int o = 0; o < 5; ++o)
#pragma unroll
            for (int m = 32; m; m >>= 1) acc[o] += __shfl_xor(acc[o], m, 64);
        if (lane == 0) {
#pragma unroll
            for (int o = 0; o < 5; ++o) {
                out[r * 5 + o] = acc[o];
                float d = acc[o] - y[r * 5 + o];
                lsum += d * d;
            }
        }
    }
    if (lane == 0) sl[wid] = lsum;
    __syncthreads();
    if (tid == 0) atomicAdd(loss, (sl[0] + sl[1] + sl[2] + sl[3]) * (1.f / ((float)ROWS * 5.f)));
}

extern "C" void kernel_launch(void* const* d_in, const int* in_sizes, int n_in,
                              void* d_out, int out_size, void* d_ws, size_t ws_size,
                              hipStream_t stream) {
    const float* x      = (const float*)d_in[0];
    const float* y      = (const float*)d_in[1];
    const float* W_emb  = (const float*)d_in[2];
    const float* b_emb  = (const float*)d_in[3];
    const float* W_in   = (const float*)d_in[4];
    const float* conv_w = (const float*)d_in[5];
    const float* conv_b = (const float*)d_in[6];
    const float* dt_bias= (const float*)d_in[7];
    const float* A_log  = (const float*)d_in[8];
    const float* Dp     = (const float*)d_in[9];
    const float* norm_w = (const float*)d_in[10];
    const float* W_out  = (const float*)d_in[11];
    const float* bnw    = (const float*)d_in[12];
    const float* nfw    = (const float*)d_in[13];
    const float* W_head = (const float*)d_in[14];

    char* ws = (char*)d_ws;
    float* res  = (float*)ws;  ws += (size_t)ROWS * DMODEL * 4;
    bf16*  Lbuf = (bf16*)ws;   ws += (size_t)BATCH * NHEADS * NCH * 8192 * 2;
    bf16*  hnb  = (bf16*)ws;   ws += (size_t)ROWS * DMODEL * 2;
    bf16*  zx   = (bf16*)ws;   ws += (size_t)ROWS * NPAD * 2;
    bf16*  bc   = (bf16*)ws;   ws += (size_t)ROWS * 256 * 2;
    bf16*  ysb  = (bf16*)ws;   ws += (size_t)ROWS * DINNER * 2;
    bf16*  yfb  = (bf16*)ws;   ws += (size_t)ROWS * DINNER * 2;
    bf16*  Wib  = (bf16*)ws;   ws += (size_t)NLAYER * NPAD * DMODEL * 2;
    bf16*  Wob  = (bf16*)ws;   ws += (size_t)NLAYER * DMODEL * DINNER * 2;
    float* Pcb  = (float*)ws;  ws += (size_t)BATCH * NHEADS * NCH * 4;
    float* Sarr = (float*)ws;  ws += (size_t)BATCH * NHEADS * NCH * QCH * 4;
    float* dtc  = (float*)ws;  ws += (size_t)BATCH * NHEADS * NCH * QCH * 4;
    bf16*  XT   = (bf16*)ws;   ws += (size_t)BATCH * NHEADS * NCH * 8192 * 2;

    float* out_p  = (float*)d_out;
    float* loss_p = out_p + (size_t)ROWS * 5;

    hipMemsetAsync(loss_p, 0, 4, stream);
    k_embed<<<ROWS * DMODEL / 256, 256, 0, stream>>>(x, W_emb, b_emb, res);
    k_cvt_in<<<NLAYER * NPAD * DMODEL / 256, 256, 0, stream>>>(W_in, Wib);
    k_cvt_out<<<NLAYER * DMODEL * DINNER / 256, 256, 0, stream>>>(W_out, Wob);

    const int NBHC = BATCH * NHEADS * NCH;   // 1536
    for (int l = 0; l < NLAYER; ++l) {
        const float* cw_l = conv_w + (size_t)l * CONVDIM * 4;
        const float* cb_l = conv_b + (size_t)l * CONVDIM;
        k_rmsnorm<<<ROWS, 256, 0, stream>>>(res, bnw + l * DMODEL, hnb);
        dim3 g1(ROWS / 128, NPAD / 128);
        k_gemm<bf16, 128, 128, false><<<g1, 256, 0, stream>>>(hnb, Wib + (size_t)l * NPAD * DMODEL, zx, DMODEL, NPAD);
        k_convBC<<<ROWS * 32 / 256, 256, 0, stream>>>(zx, cw_l, cb_l, bc);
        k_prepL<<<NBHC, 256, 0, stream>>>(zx, bc, cw_l, cb_l, dt_bias + l * NHEADS, A_log + l * NHEADS,
                                          Sarr, dtc, Pcb, XT, Lbuf);
        k_scanB<<<BATCH * NHEADS * 4, 256, 0, stream>>>(Lbuf, Pcb);
        k_chunkY<<<NBHC, 512, 0, stream>>>(bc, Sarr, dtc, Dp + l * NHEADS, XT, Lbuf, ysb);
        k_gated<<<ROWS, 256, 0, stream>>>(ysb, zx, norm_w + l * DINNER, yfb);
        dim3 g2(ROWS / 128, DMODEL / 64);
        k_gemm<float, 128, 64, true><<<g2, 256, 0, stream>>>(yfb, Wob + (size_t)l * DMODEL * DINNER, res, DINNER, DMODEL);
    }

    k_rmsnorm<<<ROWS, 256, 0, stream>>>(res, nfw, hnb);
    k_head<<<256, 256, 0, stream>>>(hnb, W_head, y, out_p, loss_p);
}

// Round 10
// 1740.925 us; speedup vs baseline: 6.6750x; 1.1367x over previous
//
#include <hip/hip_runtime.h>
#include <hip/hip_bf16.h>
#include <math.h>

#define BATCH 4
#define SEQ 2048
#define DMODEL 768
#define NLAYER 8
#define DINNER 1536
#define HEADDIM 64
#define NHEADS 24
#define DSTATE 128
#define CONVDIM 1792
#define DINPROJ 3352
#define NPAD 3456
#define NPADW 3584
#define ROWS (BATCH*SEQ)
#define EPS 1e-5f
#define QCH 128
#define NCH (SEQ/QCH)

typedef __bf16 bf16;
typedef bf16 bf16x8 __attribute__((ext_vector_type(8)));
typedef bf16 bf16x4 __attribute__((ext_vector_type(4)));
typedef float f32x4 __attribute__((ext_vector_type(4)));

#define GLD(src, dst) __builtin_amdgcn_global_load_lds( \
    (const __attribute__((address_space(1))) void*)(src), \
    (__attribute__((address_space(3))) void*)(dst), 16, 0, 0)

__device__ __forceinline__ void bar_sync() {
    asm volatile("" ::: "memory");
    __builtin_amdgcn_s_barrier();
    asm volatile("" ::: "memory");
}

__device__ __forceinline__ float fsilu(float x) { return x / (1.f + __expf(-x)); }

// ---------------- embed: res = x @ W_emb^T + b_emb ----------------
__global__ void k_embed(const float* __restrict__ x, const float* __restrict__ We,
                        const float* __restrict__ be, float* __restrict__ res) {
    int idx = blockIdx.x * 256 + threadIdx.x;
    int d = idx % DMODEL; int bl = idx / DMODEL;
    float acc = be[d];
#pragma unroll
    for (int i = 0; i < 6; ++i) acc += x[bl * 6 + i] * We[d * 6 + i];
    res[idx] = acc;
}

// ---------------- read-only rmsnorm ----------------
__global__ __launch_bounds__(256) void k_rmsnorm(const float* __restrict__ res,
                                                 const float* __restrict__ w,
                                                 bf16* __restrict__ out) {
    __shared__ float sm[4];
    int r = blockIdx.x, tid = threadIdx.x;
    float v[3]; float ss = 0.f;
#pragma unroll
    for (int k = 0; k < 3; ++k) {
        int d = tid + k * 256;
        float t = res[r * DMODEL + d];
        v[k] = t; ss += t * t;
    }
#pragma unroll
    for (int off = 32; off; off >>= 1) ss += __shfl_down(ss, off, 64);
    if ((tid & 63) == 0) sm[tid >> 6] = ss;
    __syncthreads();
    float tot = sm[0] + sm[1] + sm[2] + sm[3];
    float sc = rsqrtf(tot / (float)DMODEL + EPS);
#pragma unroll
    for (int k = 0; k < 3; ++k) {
        int d = tid + k * 256;
        out[r * DMODEL + d] = (bf16)(v[k] * sc * w[d]);
    }
}

// ---------------- batched weight conversions ----------------
__global__ void k_cvt_in(const float* __restrict__ src, bf16* __restrict__ dst) {
    int idx = blockIdx.x * 256 + threadIdx.x;          // NLAYER*NPADW*DMODEL
    int l = idx / (NPADW * DMODEL);
    int rem = idx % (NPADW * DMODEL);
    int n = rem / DMODEL;
    int d = rem % DMODEL;
    dst[idx] = (n < DINPROJ) ? (bf16)src[(long)l * DINPROJ * DMODEL + n * DMODEL + d] : (bf16)0.f;
}
__global__ void k_cvt_out(const float* __restrict__ src, bf16* __restrict__ dst) {
    int idx = blockIdx.x * 256 + threadIdx.x;
    dst[idx] = (bf16)src[idx];
}

// ---------------- bf16 MFMA GEMM: C[M,N] (=|+=) A[M,K] @ B[N,K]^T ----------------
// BMxBN tile, BK=64, TH threads (TH/64 waves), counted-vmcnt depth-2 pipeline,
// XOR-swizzled LDS. Store guard c<Nact for N not multiple of BN.
template <typename OT, int BM, int BN, int TH, bool ACC>
__global__ __launch_bounds__(TH) void k_gemm(const bf16* __restrict__ A, const bf16* __restrict__ B,
                                             OT* __restrict__ C, int K, int ldc, int Nact) {
    constexpr int NW  = TH / 64;
    constexpr int nWn = (BN / 64 < 4) ? BN / 64 : 4;
    constexpr int nWm = NW / nWn;
    constexpr int WMR = BM / nWm;
    constexpr int MI  = WMR / 16;
    constexpr int NI  = 4;
    constexpr int RG  = TH / 8;          // rows per GLD group
    constexpr int AG  = BM / RG;         // A GLD count per thread
    constexpr int BG  = BN / RG;         // B GLD count per thread
    __shared__ bf16 As[2][BM * 64];
    __shared__ bf16 Bs[2][BN * 64];
    const int tid = threadIdx.x;
    const int lane = tid & 63;
    const int w = tid >> 6;
    const int wm = w / nWn, wn = w % nWn;
    const long rowA0 = (long)blockIdx.x * BM;
    const long rowB0 = (long)blockIdx.y * BN;
    const int srow = tid >> 3;                          // 0..RG-1
    const int scol = ((tid & 7) ^ (srow & 7)) * 8;      // pre-swizzled k-offset
    const bf16* Ab = A + rowA0 * K + scol;
    const bf16* Bb = B + rowB0 * K + scol;

    f32x4 acc[MI][NI];
    const f32x4 vz = {0.f, 0.f, 0.f, 0.f};
#pragma unroll
    for (int mi = 0; mi < MI; ++mi)
#pragma unroll
        for (int ni = 0; ni < NI; ++ni) acc[mi][ni] = vz;

    auto stage = [&](int buf, int kt) {
#pragma unroll
        for (int j = 0; j < AG; ++j)
            GLD(Ab + (long)(j * RG + srow) * K + kt, &As[buf][(j * TH + w * 64) * 8]);
#pragma unroll
        for (int j = 0; j < BG; ++j)
            GLD(Bb + (long)(j * RG + srow) * K + kt, &Bs[buf][(j * TH + w * 64) * 8]);
    };
    auto waitv = [&]() {   // allow the newest stage's loads to stay outstanding
        if constexpr (AG + BG == 8) asm volatile("s_waitcnt vmcnt(8)" ::: "memory");
        else                        asm volatile("s_waitcnt vmcnt(6)" ::: "memory");
    };
    auto compute = [&](int buf) {
        const char* AsB = (const char*)As[buf];
        const char* BsB = (const char*)Bs[buf];
#pragma unroll
        for (int s = 0; s < 2; ++s) {
            bf16x8 af[MI], bfr[NI];
#pragma unroll
            for (int mi = 0; mi < MI; ++mi) {
                int r = wm * WMR + mi * 16 + (lane & 15);
                af[mi] = *(const bf16x8*)(AsB + r * 128 + ((s * 64 + (lane >> 4) * 16) ^ ((r & 7) << 4)));
            }
#pragma unroll
            for (int ni = 0; ni < NI; ++ni) {
                int r = wn * 64 + ni * 16 + (lane & 15);
                bfr[ni] = *(const bf16x8*)(BsB + r * 128 + ((s * 64 + (lane >> 4) * 16) ^ ((r & 7) << 4)));
            }
#pragma unroll
            for (int mi = 0; mi < MI; ++mi)
#pragma unroll
                for (int ni = 0; ni < NI; ++ni)
                    acc[mi][ni] = __builtin_amdgcn_mfma_f32_16x16x32_bf16(af[mi], bfr[ni], acc[mi][ni], 0, 0, 0);
        }
    };

    stage(0, 0);
    stage(1, 64);
    int cur = 0;
    for (int kt = 128; kt < K; kt += 64) {
        waitv();
        bar_sync();
        compute(cur);
        bar_sync();
        stage(cur, kt);
        cur ^= 1;
    }
    waitv();
    bar_sync();
    compute(cur);
    asm volatile("s_waitcnt vmcnt(0)" ::: "memory");
    bar_sync();
    compute(cur ^ 1);

    const int crow = (lane >> 4) * 4;
    const int ccol = lane & 15;
#pragma unroll
    for (int mi = 0; mi < MI; ++mi)
#pragma unroll
        for (int ni = 0; ni < NI; ++ni) {
            long r0 = rowA0 + wm * WMR + mi * 16 + crow;
            long c0 = rowB0 + wn * 64 + ni * 16 + ccol;
            if ((int)c0 < Nact) {
#pragma unroll
                for (int j = 0; j < 4; ++j) {
                    if constexpr (ACC) C[(r0 + j) * ldc + c0] += (OT)acc[mi][ni][j];
                    else               C[(r0 + j) * ldc + c0]  = (OT)acc[mi][ni][j];
                }
            }
        }
}

// ---------------- slim conv for B/C channels only -> bc[ROWS][256] ----------------
__global__ void k_convBC(const bf16* __restrict__ zx, const float* __restrict__ cw,
                         const float* __restrict__ cb, bf16* __restrict__ bc) {
    int idx = blockIdx.x * 256 + threadIdx.x;   // ROWS * 32
    int c8 = idx & 31; int blt = idx >> 5;
    int t = blt % SEQ;
    int ch = DINNER + c8 * 8;
    long bbase = (long)(blt - t) * NPAD;
    float cwa[8][4];
#pragma unroll
    for (int j = 0; j < 8; ++j) {
        float4 tv = *(const float4*)(cw + (ch + j) * 4);
        cwa[j][0] = tv.x; cwa[j][1] = tv.y; cwa[j][2] = tv.z; cwa[j][3] = tv.w;
    }
    float acc[8];
#pragma unroll
    for (int j = 0; j < 8; ++j) acc[j] = cb[ch + j];
#pragma unroll
    for (int k = 0; k < 4; ++k) {
        int tt = t + k - 3;
        if (tt >= 0) {
            bf16x8 v = *(const bf16x8*)(zx + bbase + (long)tt * NPAD + DINNER + ch);
#pragma unroll
            for (int j = 0; j < 8; ++j) acc[j] += (float)v[j] * cwa[j][k];
        }
    }
    bf16x8 o;
#pragma unroll
    for (int j = 0; j < 8; ++j) o[j] = (bf16)fsilu(acc[j]);
    *(bf16x8*)(bc + (long)blt * 256 + c8 * 8) = o;
}

// ---------------- fused conv(X) + prep + stateL ----------------
__global__ __launch_bounds__(256) void k_prepL(const bf16* __restrict__ zx, const bf16* __restrict__ bc,
                                               const float* __restrict__ cw_l, const float* __restrict__ cb_l,
                                               const float* __restrict__ dt_bias_l,
                                               const float* __restrict__ Alog,
                                               float* __restrict__ Sarr, float* __restrict__ dtc,
                                               float* __restrict__ Pcb,
                                               bf16* __restrict__ XT, bf16* __restrict__ Lbuf) {
    __shared__ float S_lds[128], wl_lds[128], wtot[2];
    __shared__ bf16 Xs[136 * 64];
    __shared__ bf16 Xw[64 * 128];
    __shared__ bf16 Bt[128 * 128];
    int blk = blockIdx.x;
    int b = blk / (NHEADS * NCH);
    int r = blk % (NHEADS * NCH);
    int h = r / NCH;
    int c = r % NCH;
    int tid = threadIdx.x, lane = tid & 63, wid = tid >> 6;
    long brow0 = (long)b * SEQ + c * QCH;
#pragma unroll
    for (int i = 0; i < 5; ++i) {
        int base = i * 256 + wid * 64;
        if (base < 1048) {
            int idx = base + lane;
            long g = brow0 - 3 + (idx >> 3);
            if (g < 0) g = 0;
            if (g > (long)ROWS - 1) g = (long)ROWS - 1;
            GLD(zx + g * NPAD + DINNER + h * HEADDIM + (idx & 7) * 8,
                (char*)Xs + (long)base * 16);
        }
    }
    float ps = 0.f, dtv = 0.f;
    if (tid < 128) {
        float raw = (float)zx[(brow0 + tid) * NPAD + DINNER + CONVDIM + h] + dt_bias_l[h];
        dtv = (raw > 15.f) ? raw : log1pf(__expf(raw));
        float Ah = -__expf(Alog[h]);
        ps = dtv * Ah;
#pragma unroll
        for (int off = 1; off < 64; off <<= 1) {
            float o = __shfl_up(ps, off, 64);
            if ((tid & 63) >= off) ps += o;
        }
        if ((tid & 63) == 63) wtot[tid >> 6] = ps;
    }
    __syncthreads();
    if (tid < 128) {
        if (tid >= 64) ps += wtot[0];
        S_lds[tid] = ps;
    }
    __syncthreads();
    float Sl = S_lds[127];
    if (tid < 128) {
        wl_lds[tid] = __expf(Sl - ps) * dtv;
        Sarr[blk * QCH + tid] = ps;
        dtc[blk * QCH + tid] = dtv;
        if (tid == 127) Pcb[blk] = __expf(Sl);
    }
    __syncthreads();
    {
        int p = tid >> 2, q = tid & 3;
        float4 cwv = *(const float4*)(cw_l + (h * HEADDIM + p) * 4);
        float cbv = cb_l[h * HEADDIM + p];
        float cwa[4] = {cwv.x, cwv.y, cwv.z, cwv.w};
        char* xtb = (char*)XT + (((long)blk) << 14);
#pragma unroll
        for (int ub = 0; ub < 4; ++ub) {
            int u0 = q * 32 + ub * 8;
            bf16x8 vx, vw;
#pragma unroll
            for (int k = 0; k < 8; ++k) {
                int u = u0 + k;
                float a = cbv;
#pragma unroll
                for (int tt = 0; tt < 4; ++tt) {
                    if (c > 0 || u + tt >= 3)
                        a += (float)Xs[(u + tt) * 64 + p] * cwa[tt];
                }
                bf16 xb = (bf16)fsilu(a);
                vx[k] = xb;
                vw[k] = (bf16)((float)xb * wl_lds[u]);
            }
            long off = (long)((p * 256 + u0 * 2) ^ ((p & 7) << 4));
            *(bf16x8*)(xtb + off) = vx;
            *(bf16x8*)((char*)Xw + off) = vw;
        }
    }
#pragma unroll
    for (int nb = 0; nb < 2; ++nb) {
        __syncthreads();
#pragma unroll
        for (int i = 0; i < 4; ++i) {
            int idx = i * 256 + tid;
            GLD(bc + (brow0 + (idx >> 3)) * 256 + nb * 64 + (idx & 7) * 8,
                (char*)Xs + (i * 256 + wid * 64) * 16);
        }
        __syncthreads();
        int nl = tid >> 2, q = tid & 3;
        int n = nb * 64 + nl;
#pragma unroll
        for (int ub = 0; ub < 4; ++ub) {
            int u0 = q * 32 + ub * 8;
            bf16x8 v;
#pragma unroll
            for (int k = 0; k < 8; ++k) v[k] = Xs[(u0 + k) * 64 + nl];
            long off = (long)((n * 256 + u0 * 2) ^ ((n & 7) << 4));
            *(bf16x8*)((char*)Bt + off) = v;
        }
    }
    __syncthreads();
    f32x4 acc[4][2];
    const f32x4 vz = {0.f, 0.f, 0.f, 0.f};
#pragma unroll
    for (int mi = 0; mi < 4; ++mi)
#pragma unroll
        for (int ni = 0; ni < 2; ++ni) acc[mi][ni] = vz;
    const char* XwB = (const char*)Xw;
    const char* BtB = (const char*)Bt;
    __builtin_amdgcn_s_setprio(1);
#pragma unroll
    for (int ks = 0; ks < 4; ++ks) {
        bf16x8 af[4], bfr[2];
#pragma unroll
        for (int mi = 0; mi < 4; ++mi) {
            int pp = mi * 16 + (lane & 15);
            af[mi] = *(const bf16x8*)(XwB + ((pp * 256 + ks * 64 + (lane >> 4) * 16) ^ ((pp & 7) << 4)));
        }
#pragma unroll
        for (int ni = 0; ni < 2; ++ni) {
            int n = wid * 32 + ni * 16 + (lane & 15);
            bfr[ni] = *(const bf16x8*)(BtB + ((n * 256 + ks * 64 + (lane >> 4) * 16) ^ ((n & 7) << 4)));
        }
#pragma unroll
        for (int mi = 0; mi < 4; ++mi)
#pragma unroll
            for (int ni = 0; ni < 2; ++ni)
                acc[mi][ni] = __builtin_amdgcn_mfma_f32_16x16x32_bf16(af[mi], bfr[ni], acc[mi][ni], 0, 0, 0);
    }
    __builtin_amdgcn_s_setprio(0);
    char* lb = (char*)Lbuf + (((long)blk) << 14);
#pragma unroll
    for (int mi = 0; mi < 4; ++mi)
#pragma unroll
        for (int ni = 0; ni < 2; ++ni)
#pragma unroll
            for (int j = 0; j < 4; ++j) {
                int pp = mi * 16 + (lane >> 4) * 4 + j;
                int n = wid * 32 + ni * 16 + (lane & 15);
                *(bf16*)(lb + ((pp * 256 + n * 2) ^ ((pp & 7) << 4))) = (bf16)acc[mi][ni][j];
            }
}

// ---------------- Pass B: sequential inter-chunk combine ----------------
__global__ __launch_bounds__(256) void k_scanB(bf16* __restrict__ Lbuf, const float* __restrict__ Pc) {
    int bh = blockIdx.x >> 2;
    int q = blockIdx.x & 3;
    int off = (q * 256 + threadIdx.x) * 8;
    long base = ((long)bh * NCH) << 13;
    float s[8] = {0.f};
#pragma unroll
    for (int c = 0; c < NCH; ++c) {
        bf16* p = Lbuf + base + ((long)c << 13) + off;
        bf16x8 L = *(bf16x8*)p;
        bf16x8 I;
#pragma unroll
        for (int k = 0; k < 8; ++k) I[k] = (bf16)s[k];
        float P = Pc[bh * NCH + c];
#pragma unroll
        for (int k = 0; k < 8; ++k) s[k] = P * s[k] + (float)L[k];
        *(bf16x8*)p = I;
    }
}

// ---------------- chunk Y via MFMA -> bf16 ----------------
__global__ __launch_bounds__(512) void k_chunkY(const bf16* __restrict__ bc,
                                                const float* __restrict__ Sarr, const float* __restrict__ dtc,
                                                const float* __restrict__ Dp,
                                                const bf16* __restrict__ XT, const bf16* __restrict__ Lbuf,
                                                bf16* __restrict__ ysb) {
    __shared__ bf16 Cs[128 * 128];
    __shared__ bf16 Bs[128 * 128];
    __shared__ bf16 Xts[64 * 128];
    __shared__ bf16 Is[64 * 128];
    __shared__ float S_lds[128], dt_lds[128];
    int blk = blockIdx.x;
    int b = blk / (NHEADS * NCH);
    int r = blk % (NHEADS * NCH);
    int h = r / NCH;
    int c = r % NCH;
    int tid = threadIdx.x, lane = tid & 63, wid = tid >> 6;
    long brow0 = (long)b * SEQ + c * QCH;
    const char* bcB = (const char*)bc;
#pragma unroll
    for (int i = 0; i < 4; ++i) {
        int trow = i * 32 + wid * 4 + (lane >> 4);
        int blk16 = lane & 15;
        const char* rp = bcB + (brow0 + trow) * 512;
        int sb = (blk16 ^ (trow & 7)) << 4;
        GLD(rp + 256 + sb, (char*)Cs + (i * 32 + wid * 4) * 256);
        GLD(rp + sb,       (char*)Bs + (i * 32 + wid * 4) * 256);
    }
    const char* xt = (const char*)XT + (((long)blk) << 14);
    const char* ib = (const char*)Lbuf + (((long)blk) << 14);
#pragma unroll
    for (int i = 0; i < 2; ++i) {
        GLD(xt + (long)(i * 512 + tid) * 16, (char*)Xts + (i * 512 + wid * 64) * 16);
        GLD(ib + (long)(i * 512 + tid) * 16, (char*)Is + (i * 512 + wid * 64) * 16);
    }
    if (tid < 128) { S_lds[tid] = Sarr[blk * QCH + tid]; dt_lds[tid] = dtc[blk * QCH + tid]; }
    float Dh = Dp[h];
    asm volatile("s_waitcnt vmcnt(4) lgkmcnt(0)" ::: "memory");
    bar_sync();
    const char* CsB = (const char*)Cs;
    char* BsB = (char*)Bs;
    const char* IsB = (const char*)Is;
    const char* XtB = (const char*)Xts;
    const f32x4 vz = {0.f, 0.f, 0.f, 0.f};
    int wmG = wid >> 2, wnG = wid & 3;
    f32x4 accg[4][2];
#pragma unroll
    for (int mi = 0; mi < 4; ++mi)
#pragma unroll
        for (int ni = 0; ni < 2; ++ni) accg[mi][ni] = vz;
#pragma unroll
    for (int ks = 0; ks < 4; ++ks) {
        bf16x8 af[4], bfr[2];
#pragma unroll
        for (int mi = 0; mi < 4; ++mi) {
            int t = wmG * 64 + mi * 16 + (lane & 15);
            af[mi] = *(const bf16x8*)(CsB + ((t * 256 + ks * 64 + (lane >> 4) * 16) ^ ((t & 7) << 4)));
        }
#pragma unroll
        for (int ni = 0; ni < 2; ++ni) {
            int u = wnG * 32 + ni * 16 + (lane & 15);
            bfr[ni] = *(const bf16x8*)(BsB + ((u * 256 + ks * 64 + (lane >> 4) * 16) ^ ((u & 7) << 4)));
        }
#pragma unroll
        for (int mi = 0; mi < 4; ++mi)
#pragma unroll
            for (int ni = 0; ni < 2; ++ni)
                accg[mi][ni] = __builtin_amdgcn_mfma_f32_16x16x32_bf16(af[mi], bfr[ni], accg[mi][ni], 0, 0, 0);
    }
    bar_sync();
#pragma unroll
    for (int mi = 0; mi < 4; ++mi) {
#pragma unroll
        for (int j = 0; j < 4; ++j) {
            int t = wmG * 64 + mi * 16 + (lane >> 4) * 4 + j;
            float St = S_lds[t];
#pragma unroll
            for (int ni = 0; ni < 2; ++ni) {
                int u = wnG * 32 + ni * 16 + (lane & 15);
                float v = 0.f;
                if (u <= t) v = accg[mi][ni][j] * __expf(St - S_lds[u]) * dt_lds[u];
                *(bf16*)(BsB + ((t * 256 + u * 2) ^ ((t & 7) << 4))) = (bf16)v;
            }
        }
    }
    asm volatile("s_waitcnt vmcnt(0) lgkmcnt(0)" ::: "memory");
    bar_sync();
    int wmY = wid >> 1, wnY = wid & 1;
    f32x4 accy[2][2];
#pragma unroll
    for (int mi = 0; mi < 2; ++mi)
#pragma unroll
        for (int ni = 0; ni < 2; ++ni) accy[mi][ni] = vz;
#pragma unroll
    for (int ks = 0; ks < 4; ++ks) {
        bf16x8 af[2], bfr[2];
#pragma unroll
        for (int mi = 0; mi < 2; ++mi) {
            int t = wmY * 32 + mi * 16 + (lane & 15);
            af[mi] = *(const bf16x8*)(CsB + ((t * 256 + ks * 64 + (lane >> 4) * 16) ^ ((t & 7) << 4)));
        }
#pragma unroll
        for (int ni = 0; ni < 2; ++ni) {
            int pp = wnY * 32 + ni * 16 + (lane & 15);
            bfr[ni] = *(const bf16x8*)(IsB + ((pp * 256 + ks * 64 + (lane >> 4) * 16) ^ ((pp & 7) << 4)));
        }
#pragma unroll
        for (int mi = 0; mi < 2; ++mi)
#pragma unroll
            for (int ni = 0; ni < 2; ++ni)
                accy[mi][ni] = __builtin_amdgcn_mfma_f32_16x16x32_bf16(af[mi], bfr[ni], accy[mi][ni], 0, 0, 0);
    }
#pragma unroll
    for (int mi = 0; mi < 2; ++mi)
#pragma unroll
        for (int j = 0; j < 4; ++j) {
            int t = wmY * 32 + mi * 16 + (lane >> 4) * 4 + j;
            float e = __expf(S_lds[t]);
#pragma unroll
            for (int ni = 0; ni < 2; ++ni) accy[mi][ni][j] *= e;
        }
#pragma unroll
    for (int ks = 0; ks < 4; ++ks) {
        bf16x8 af[2], bfr[2];
#pragma unroll
        for (int mi = 0; mi < 2; ++mi) {
            int t = wmY * 32 + mi * 16 + (lane & 15);
            af[mi] = *(const bf16x8*)(BsB + ((t * 256 + ks * 64 + (lane >> 4) * 16) ^ ((t & 7) << 4)));
        }
#pragma unroll
        for (int ni = 0; ni < 2; ++ni) {
            int pp = wnY * 32 + ni * 16 + (lane & 15);
            bfr[ni] = *(const bf16x8*)(XtB + ((pp * 256 + ks * 64 + (lane >> 4) * 16) ^ ((pp & 7) << 4)));
        }
#pragma unroll
        for (int mi = 0; mi < 2; ++mi)
#pragma unroll
            for (int ni = 0; ni < 2; ++ni)
                accy[mi][ni] = __builtin_amdgcn_mfma_f32_16x16x32_bf16(af[mi], bfr[ni], accy[mi][ni], 0, 0, 0);
    }
#pragma unroll
    for (int mi = 0; mi < 2; ++mi)
#pragma unroll
        for (int ni = 0; ni < 2; ++ni)
#pragma unroll
            for (int j = 0; j < 4; ++j) {
                int t = wmY * 32 + mi * 16 + (lane >> 4) * 4 + j;
                int pp = wnY * 32 + ni * 16 + (lane & 15);
                float xv = (float)*(const bf16*)(XtB + ((pp * 256 + t * 2) ^ ((pp & 7) << 4)));
                ysb[(brow0 + t) * DINNER + h * HEADDIM + pp] = (bf16)(accy[mi][ni][j] + Dh * xv);
            }
}

// ---------------- gated rmsnorm ----------------
__global__ __launch_bounds__(256) void k_gated(const bf16* __restrict__ ys, const bf16* __restrict__ zx,
                                               const float* __restrict__ w, bf16* __restrict__ out) {
    __shared__ float sm[4];
    int r = blockIdx.x, tid = threadIdx.x;
    float v[6]; float ss = 0.f;
#pragma unroll
    for (int k = 0; k < 6; ++k) {
        int d = tid + k * 256;
        float z = (float)zx[(long)r * NPAD + d];
        float t = (float)ys[(long)r * DINNER + d] * fsilu(z);
        v[k] = t; ss += t * t;
    }
#pragma unroll
    for (int off = 32; off; off >>= 1) ss += __shfl_down(ss, off, 64);
    if ((tid & 63) == 0) sm[tid >> 6] = ss;
    __syncthreads();
    float tot = sm[0] + sm[1] + sm[2] + sm[3];
    float sc = rsqrtf(tot / (float)DINNER + EPS);
#pragma unroll
    for (int k = 0; k < 6; ++k) {
        int d = tid + k * 256;
        out[(long)r * DINNER + d] = (bf16)(v[k] * sc * w[d]);
    }
}

// ---------------- head: 32 rows/block, 1 atomic/block ----------------
__global__ __launch_bounds__(256) void k_head(const bf16* __restrict__ hn, const float* __restrict__ Wh,
                                              const float* __restrict__ y, float* __restrict__ out,
                                              float* __restrict__ loss) {
    __shared__ float sl[4];
    int tid = threadIdx.x, lane = tid & 63, wid = tid >> 6;
    float wv[5][12];
#pragma unroll
    for (int o = 0; o < 5; ++o)
#pragma unroll
        for (int j = 0; j < 12; ++j) wv[o][j] = Wh[o * DMODEL + lane * 12 + j];
    float lsum = 0.f;
#pragma unroll
    for (int rr = 0; rr < 8; ++rr) {
        long r = (long)blockIdx.x * 32 + wid * 8 + rr;
        const bf16* hp = hn + r * DMODEL + lane * 12;
        float hv[12];
#pragma unroll
        for (int q = 0; q < 3; ++q) {
            bf16x4 v4 = *(const bf16x4*)(hp + q * 4);
#pragma unroll
            for (int j = 0; j < 4; ++j) hv[q * 4 + j] = (float)v4[j];
        }
        float acc[5];
#pragma unroll
        for (int o = 0; o < 5; ++o) {
            float a = 0.f;
#pragma unroll
            for (int j = 0; j < 12; ++j) a += hv[j] * wv[o][j];
            acc[o] = a;
        }
#pragma unroll
        for (int o = 0; o < 5; ++o)
#pragma unroll
            for (int m = 32; m; m >>= 1) acc[o] += __shfl_xor(acc[o], m, 64);
        if (lane == 0) {
#pragma unroll
            for (int o = 0; o < 5; ++o) {
                out[r * 5 + o] = acc[o];
                float d = acc[o] - y[r * 5 + o];
                lsum += d * d;
            }
        }
    }
    if (lane == 0) sl[wid] = lsum;
    __syncthreads();
    if (tid == 0) atomicAdd(loss, (sl[0] + sl[1] + sl[2] + sl[3]) * (1.f / ((float)ROWS * 5.f)));
}

extern "C" void kernel_launch(void* const* d_in, const int* in_sizes, int n_in,
                              void* d_out, int out_size, void* d_ws, size_t ws_size,
                              hipStream_t stream) {
    const float* x      = (const float*)d_in[0];
    const float* y      = (const float*)d_in[1];
    const float* W_emb  = (const float*)d_in[2];
    const float* b_emb  = (const float*)d_in[3];
    const float* W_in   = (const float*)d_in[4];
    const float* conv_w = (const float*)d_in[5];
    const float* conv_b = (const float*)d_in[6];
    const float* dt_bias= (const float*)d_in[7];
    const float* A_log  = (const float*)d_in[8];
    const float* Dp     = (const float*)d_in[9];
    const float* norm_w = (const float*)d_in[10];
    const float* W_out  = (const float*)d_in[11];
    const float* bnw    = (const float*)d_in[12];
    const float* nfw    = (const float*)d_in[13];
    const float* W_head = (const float*)d_in[14];

    char* ws = (char*)d_ws;
    float* res  = (float*)ws;  ws += (size_t)ROWS * DMODEL * 4;
    bf16*  Lbuf = (bf16*)ws;   ws += (size_t)BATCH * NHEADS * NCH * 8192 * 2;
    bf16*  hnb  = (bf16*)ws;   ws += (size_t)ROWS * DMODEL * 2;
    bf16*  zx   = (bf16*)ws;   ws += (size_t)ROWS * NPAD * 2;
    bf16*  bc   = (bf16*)ws;   ws += (size_t)ROWS * 256 * 2;
    bf16*  ysb  = (bf16*)ws;   ws += (size_t)ROWS * DINNER * 2;
    bf16*  yfb  = (bf16*)ws;   ws += (size_t)ROWS * DINNER * 2;
    bf16*  Wib  = (bf16*)ws;   ws += (size_t)NLAYER * NPADW * DMODEL * 2;
    bf16*  Wob  = (bf16*)ws;   ws += (size_t)NLAYER * DMODEL * DINNER * 2;
    float* Pcb  = (float*)ws;  ws += (size_t)BATCH * NHEADS * NCH * 4;
    float* Sarr = (float*)ws;  ws += (size_t)BATCH * NHEADS * NCH * QCH * 4;
    float* dtc  = (float*)ws;  ws += (size_t)BATCH * NHEADS * NCH * QCH * 4;
    bf16*  XT   = (bf16*)ws;   ws += (size_t)BATCH * NHEADS * NCH * 8192 * 2;

    float* out_p  = (float*)d_out;
    float* loss_p = out_p + (size_t)ROWS * 5;

    hipMemsetAsync(loss_p, 0, 4, stream);
    k_embed<<<ROWS * DMODEL / 256, 256, 0, stream>>>(x, W_emb, b_emb, res);
    k_cvt_in<<<NLAYER * NPADW * DMODEL / 256, 256, 0, stream>>>(W_in, Wib);
    k_cvt_out<<<NLAYER * DMODEL * DINNER / 256, 256, 0, stream>>>(W_out, Wob);

    const int NBHC = BATCH * NHEADS * NCH;   // 1536
    for (int l = 0; l < NLAYER; ++l) {
        const float* cw_l = conv_w + (size_t)l * CONVDIM * 4;
        const float* cb_l = conv_b + (size_t)l * CONVDIM;
        k_rmsnorm<<<ROWS, 256, 0, stream>>>(res, bnw + l * DMODEL, hnb);
        dim3 g1(ROWS / 256, NPADW / 256);
        k_gemm<bf16, 256, 256, 512, false><<<g1, 512, 0, stream>>>(hnb, Wib + (size_t)l * NPADW * DMODEL, zx, DMODEL, NPAD, NPAD);
        k_convBC<<<ROWS * 32 / 256, 256, 0, stream>>>(zx, cw_l, cb_l, bc);
        k_prepL<<<NBHC, 256, 0, stream>>>(zx, bc, cw_l, cb_l, dt_bias + l * NHEADS, A_log + l * NHEADS,
                                          Sarr, dtc, Pcb, XT, Lbuf);
        k_scanB<<<BATCH * NHEADS * 4, 256, 0, stream>>>(Lbuf, Pcb);
        k_chunkY<<<NBHC, 512, 0, stream>>>(bc, Sarr, dtc, Dp + l * NHEADS, XT, Lbuf, ysb);
        k_gated<<<ROWS, 256, 0, stream>>>(ysb, zx, norm_w + l * DINNER, yfb);
        dim3 g2(ROWS / 128, DMODEL / 64);
        k_gemm<float, 128, 64, 256, true><<<g2, 256, 0, stream>>>(yfb, Wob + (size_t)l * DMODEL * DINNER, res, DINNER, DMODEL, DMODEL);
    }

    k_rmsnorm<<<ROWS, 256, 0, stream>>>(res, nfw, hnb);
    k_head<<<256, 256, 0, stream>>>(hnb, W_head, y, out_p, loss_p);
}

// Round 11
// 1732.032 us; speedup vs baseline: 6.7092x; 1.0051x over previous
//
#include <hip/hip_runtime.h>
#include <hip/hip_bf16.h>
#include <math.h>

#define BATCH 4
#define SEQ 2048
#define DMODEL 768
#define NLAYER 8
#define DINNER 1536
#define HEADDIM 64
#define NHEADS 24
#define DSTATE 128
#define CONVDIM 1792
#define DINPROJ 3352
#define NPAD 3456
#define NPADW 3584
#define ROWS (BATCH*SEQ)
#define EPS 1e-5f
#define QCH 128
#define NCH (SEQ/QCH)

typedef __bf16 bf16;
typedef bf16 bf16x8 __attribute__((ext_vector_type(8)));
typedef bf16 bf16x4 __attribute__((ext_vector_type(4)));
typedef float f32x4 __attribute__((ext_vector_type(4)));

#define GLD(src, dst) __builtin_amdgcn_global_load_lds( \
    (const __attribute__((address_space(1))) void*)(src), \
    (__attribute__((address_space(3))) void*)(dst), 16, 0, 0)

__device__ __forceinline__ void bar_sync() {
    asm volatile("" ::: "memory");
    __builtin_amdgcn_s_barrier();
    asm volatile("" ::: "memory");
}

__device__ __forceinline__ float fsilu(float x) { return x / (1.f + __expf(-x)); }

// ---------------- embed: res = x @ W_emb^T + b_emb ----------------
__global__ void k_embed(const float* __restrict__ x, const float* __restrict__ We,
                        const float* __restrict__ be, float* __restrict__ res) {
    int idx = blockIdx.x * 256 + threadIdx.x;
    int d = idx % DMODEL; int bl = idx / DMODEL;
    float acc = be[d];
#pragma unroll
    for (int i = 0; i < 6; ++i) acc += x[bl * 6 + i] * We[d * 6 + i];
    res[idx] = acc;
}

// ---------------- read-only rmsnorm ----------------
__global__ __launch_bounds__(256) void k_rmsnorm(const float* __restrict__ res,
                                                 const float* __restrict__ w,
                                                 bf16* __restrict__ out) {
    __shared__ float sm[4];
    int r = blockIdx.x, tid = threadIdx.x;
    float v[3]; float ss = 0.f;
#pragma unroll
    for (int k = 0; k < 3; ++k) {
        int d = tid + k * 256;
        float t = res[r * DMODEL + d];
        v[k] = t; ss += t * t;
    }
#pragma unroll
    for (int off = 32; off; off >>= 1) ss += __shfl_down(ss, off, 64);
    if ((tid & 63) == 0) sm[tid >> 6] = ss;
    __syncthreads();
    float tot = sm[0] + sm[1] + sm[2] + sm[3];
    float sc = rsqrtf(tot / (float)DMODEL + EPS);
#pragma unroll
    for (int k = 0; k < 3; ++k) {
        int d = tid + k * 256;
        out[r * DMODEL + d] = (bf16)(v[k] * sc * w[d]);
    }
}

// ---------------- batched weight conversions ----------------
__global__ void k_cvt_in(const float* __restrict__ src, bf16* __restrict__ dst) {
    int idx = blockIdx.x * 256 + threadIdx.x;          // NLAYER*NPADW*DMODEL
    int l = idx / (NPADW * DMODEL);
    int rem = idx % (NPADW * DMODEL);
    int n = rem / DMODEL;
    int d = rem % DMODEL;
    dst[idx] = (n < DINPROJ) ? (bf16)src[(long)l * DINPROJ * DMODEL + n * DMODEL + d] : (bf16)0.f;
}
__global__ void k_cvt_out(const float* __restrict__ src, bf16* __restrict__ dst) {
    int idx = blockIdx.x * 256 + threadIdx.x;
    dst[idx] = (bf16)src[idx];
}

// ---------------- bf16 MFMA GEMM: C[M,N] (=|+=) A[M,K] @ B[N,K]^T ----------------
// BMxBN tile, BK=64, counted-vmcnt depth-2 pipeline, XOR-swizzled LDS.
// Early-stage variant: all frags for tile t read to regs -> lgkmcnt(0)+barrier
// (buf dead) -> stage(t+2) issued -> second MFMA half overlaps the GLDs.
template <typename OT, int BM, int BN, int TH, bool ACC>
__global__ __launch_bounds__(TH) void k_gemm(const bf16* __restrict__ A, const bf16* __restrict__ B,
                                             OT* __restrict__ C, int K, int ldc, int Nact) {
    constexpr int NW  = TH / 64;
    constexpr int nWn = (BN / 64 < 4) ? BN / 64 : 4;
    constexpr int nWm = NW / nWn;
    constexpr int WMR = BM / nWm;
    constexpr int MI  = WMR / 16;
    constexpr int MH  = MI / 2;          // half split (MI is 2,4 or 8)
    constexpr int NI  = 4;
    constexpr int RG  = TH / 8;          // rows per GLD group
    constexpr int AG  = BM / RG;
    constexpr int BG  = BN / RG;
    __shared__ bf16 As[2][BM * 64];
    __shared__ bf16 Bs[2][BN * 64];
    const int tid = threadIdx.x;
    const int lane = tid & 63;
    const int w = tid >> 6;
    const int wm = w / nWn, wn = w % nWn;
    const long rowA0 = (long)blockIdx.x * BM;
    const long rowB0 = (long)blockIdx.y * BN;
    const int srow = tid >> 3;
    const int scol = ((tid & 7) ^ (srow & 7)) * 8;
    const bf16* Ab = A + rowA0 * K + scol;
    const bf16* Bb = B + rowB0 * K + scol;

    f32x4 acc[MI][NI];
    const f32x4 vz = {0.f, 0.f, 0.f, 0.f};
#pragma unroll
    for (int mi = 0; mi < MI; ++mi)
#pragma unroll
        for (int ni = 0; ni < NI; ++ni) acc[mi][ni] = vz;

    auto stage = [&](int buf, int kt) {
#pragma unroll
        for (int j = 0; j < AG; ++j)
            GLD(Ab + (long)(j * RG + srow) * K + kt, &As[buf][(j * TH + w * 64) * 8]);
#pragma unroll
        for (int j = 0; j < BG; ++j)
            GLD(Bb + (long)(j * RG + srow) * K + kt, &Bs[buf][(j * TH + w * 64) * 8]);
    };
    auto waitv = [&]() {
        if constexpr (AG + BG == 8) asm volatile("s_waitcnt vmcnt(8)" ::: "memory");
        else                        asm volatile("s_waitcnt vmcnt(6)" ::: "memory");
    };

    bf16x8 bfr[NI][2];
    bf16x8 af[MH][2];
    auto rd_bfr = [&](int buf) {
        const char* BsB = (const char*)Bs[buf];
#pragma unroll
        for (int ni = 0; ni < NI; ++ni)
#pragma unroll
            for (int ks = 0; ks < 2; ++ks) {
                int r = wn * 64 + ni * 16 + (lane & 15);
                bfr[ni][ks] = *(const bf16x8*)(BsB + r * 128 + ((ks * 64 + (lane >> 4) * 16) ^ ((r & 7) << 4)));
            }
    };
    auto rd_af = [&](int buf, int m0) {
        const char* AsB = (const char*)As[buf];
#pragma unroll
        for (int mi = 0; mi < MH; ++mi)
#pragma unroll
            for (int ks = 0; ks < 2; ++ks) {
                int r = wm * WMR + (m0 + mi) * 16 + (lane & 15);
                af[mi][ks] = *(const bf16x8*)(AsB + r * 128 + ((ks * 64 + (lane >> 4) * 16) ^ ((r & 7) << 4)));
            }
    };
    auto do_half = [&](int m0) {
#pragma unroll
        for (int mi = 0; mi < MH; ++mi)
#pragma unroll
            for (int ni = 0; ni < NI; ++ni)
#pragma unroll
                for (int ks = 0; ks < 2; ++ks)
                    acc[m0 + mi][ni] = __builtin_amdgcn_mfma_f32_16x16x32_bf16(af[mi][ks], bfr[ni][ks], acc[m0 + mi][ni], 0, 0, 0);
    };

    const int NT = K / 64;
    stage(0, 0);
    stage(1, 64);
    for (int t = 0; t < NT - 2; ++t) {
        waitv();
        bar_sync();                  // buf (t&1) holds tile t, fully landed
        rd_bfr(t & 1);
        rd_af(t & 1, 0);
        do_half(0);                  // MFMA half 0
        rd_af(t & 1, MH);            // last LDS reads of this buf
        asm volatile("s_waitcnt lgkmcnt(0)" ::: "memory");   // reads retired before barrier
        bar_sync();                  // buf (t&1) dead across ALL waves
        stage(t & 1, (t + 2) * 64);  // refill issued BEFORE half-1 MFMAs
        __builtin_amdgcn_sched_barrier(0);
        do_half(MH);                 // MFMA half 1 overlaps GLD flight
    }
    {   // tile NT-2 (no more staging)
        waitv();
        bar_sync();
        rd_bfr((NT - 2) & 1);
        rd_af((NT - 2) & 1, 0);
        do_half(0);
        rd_af((NT - 2) & 1, MH);
        do_half(MH);
    }
    {   // tile NT-1
        asm volatile("s_waitcnt vmcnt(0)" ::: "memory");
        bar_sync();
        rd_bfr((NT - 1) & 1);
        rd_af((NT - 1) & 1, 0);
        do_half(0);
        rd_af((NT - 1) & 1, MH);
        do_half(MH);
    }

    const int crow = (lane >> 4) * 4;
    const int ccol = lane & 15;
#pragma unroll
    for (int mi = 0; mi < MI; ++mi)
#pragma unroll
        for (int ni = 0; ni < NI; ++ni) {
            long r0 = rowA0 + wm * WMR + mi * 16 + crow;
            long c0 = rowB0 + wn * 64 + ni * 16 + ccol;
            if ((int)c0 < Nact) {
#pragma unroll
                for (int j = 0; j < 4; ++j) {
                    if constexpr (ACC) C[(r0 + j) * ldc + c0] += (OT)acc[mi][ni][j];
                    else               C[(r0 + j) * ldc + c0]  = (OT)acc[mi][ni][j];
                }
            }
        }
}

// ---------------- slim conv for B/C channels only -> bc[ROWS][256] ----------------
__global__ void k_convBC(const bf16* __restrict__ zx, const float* __restrict__ cw,
                         const float* __restrict__ cb, bf16* __restrict__ bc) {
    int idx = blockIdx.x * 256 + threadIdx.x;   // ROWS * 32
    int c8 = idx & 31; int blt = idx >> 5;
    int t = blt % SEQ;
    int ch = DINNER + c8 * 8;
    long bbase = (long)(blt - t) * NPAD;
    float cwa[8][4];
#pragma unroll
    for (int j = 0; j < 8; ++j) {
        float4 tv = *(const float4*)(cw + (ch + j) * 4);
        cwa[j][0] = tv.x; cwa[j][1] = tv.y; cwa[j][2] = tv.z; cwa[j][3] = tv.w;
    }
    float acc[8];
#pragma unroll
    for (int j = 0; j < 8; ++j) acc[j] = cb[ch + j];
#pragma unroll
    for (int k = 0; k < 4; ++k) {
        int tt = t + k - 3;
        if (tt >= 0) {
            bf16x8 v = *(const bf16x8*)(zx + bbase + (long)tt * NPAD + DINNER + ch);
#pragma unroll
            for (int j = 0; j < 8; ++j) acc[j] += (float)v[j] * cwa[j][k];
        }
    }
    bf16x8 o;
#pragma unroll
    for (int j = 0; j < 8; ++j) o[j] = (bf16)fsilu(acc[j]);
    *(bf16x8*)(bc + (long)blt * 256 + c8 * 8) = o;
}

// ---------------- fused conv(X) + prep + stateL ----------------
__global__ __launch_bounds__(256) void k_prepL(const bf16* __restrict__ zx, const bf16* __restrict__ bc,
                                               const float* __restrict__ cw_l, const float* __restrict__ cb_l,
                                               const float* __restrict__ dt_bias_l,
                                               const float* __restrict__ Alog,
                                               float* __restrict__ Sarr, float* __restrict__ dtc,
                                               float* __restrict__ Pcb,
                                               bf16* __restrict__ XT, bf16* __restrict__ Lbuf) {
    __shared__ float S_lds[128], wl_lds[128], wtot[2];
    __shared__ bf16 Xs[136 * 64];
    __shared__ bf16 Xw[64 * 128];
    __shared__ bf16 Bt[128 * 128];
    int blk = blockIdx.x;
    int b = blk / (NHEADS * NCH);
    int r = blk % (NHEADS * NCH);
    int h = r / NCH;
    int c = r % NCH;
    int tid = threadIdx.x, lane = tid & 63, wid = tid >> 6;
    long brow0 = (long)b * SEQ + c * QCH;
#pragma unroll
    for (int i = 0; i < 5; ++i) {
        int base = i * 256 + wid * 64;
        if (base < 1048) {
            int idx = base + lane;
            long g = brow0 - 3 + (idx >> 3);
            if (g < 0) g = 0;
            if (g > (long)ROWS - 1) g = (long)ROWS - 1;
            GLD(zx + g * NPAD + DINNER + h * HEADDIM + (idx & 7) * 8,
                (char*)Xs + (long)base * 16);
        }
    }
    float ps = 0.f, dtv = 0.f;
    if (tid < 128) {
        float raw = (float)zx[(brow0 + tid) * NPAD + DINNER + CONVDIM + h] + dt_bias_l[h];
        dtv = (raw > 15.f) ? raw : log1pf(__expf(raw));
        float Ah = -__expf(Alog[h]);
        ps = dtv * Ah;
#pragma unroll
        for (int off = 1; off < 64; off <<= 1) {
            float o = __shfl_up(ps, off, 64);
            if ((tid & 63) >= off) ps += o;
        }
        if ((tid & 63) == 63) wtot[tid >> 6] = ps;
    }
    __syncthreads();
    if (tid < 128) {
        if (tid >= 64) ps += wtot[0];
        S_lds[tid] = ps;
    }
    __syncthreads();
    float Sl = S_lds[127];
    if (tid < 128) {
        wl_lds[tid] = __expf(Sl - ps) * dtv;
        Sarr[blk * QCH + tid] = ps;
        dtc[blk * QCH + tid] = dtv;
        if (tid == 127) Pcb[blk] = __expf(Sl);
    }
    __syncthreads();
    {
        int p = tid >> 2, q = tid & 3;
        float4 cwv = *(const float4*)(cw_l + (h * HEADDIM + p) * 4);
        float cbv = cb_l[h * HEADDIM + p];
        float cwa[4] = {cwv.x, cwv.y, cwv.z, cwv.w};
        char* xtb = (char*)XT + (((long)blk) << 14);
#pragma unroll
        for (int ub = 0; ub < 4; ++ub) {
            int u0 = q * 32 + ub * 8;
            bf16x8 vx, vw;
#pragma unroll
            for (int k = 0; k < 8; ++k) {
                int u = u0 + k;
                float a = cbv;
#pragma unroll
                for (int tt = 0; tt < 4; ++tt) {
                    if (c > 0 || u + tt >= 3)
                        a += (float)Xs[(u + tt) * 64 + p] * cwa[tt];
                }
                bf16 xb = (bf16)fsilu(a);
                vx[k] = xb;
                vw[k] = (bf16)((float)xb * wl_lds[u]);
            }
            long off = (long)((p * 256 + u0 * 2) ^ ((p & 7) << 4));
            *(bf16x8*)(xtb + off) = vx;
            *(bf16x8*)((char*)Xw + off) = vw;
        }
    }
#pragma unroll
    for (int nb = 0; nb < 2; ++nb) {
        __syncthreads();
#pragma unroll
        for (int i = 0; i < 4; ++i) {
            int idx = i * 256 + tid;
            GLD(bc + (brow0 + (idx >> 3)) * 256 + nb * 64 + (idx & 7) * 8,
                (char*)Xs + (i * 256 + wid * 64) * 16);
        }
        __syncthreads();
        int nl = tid >> 2, q = tid & 3;
        int n = nb * 64 + nl;
#pragma unroll
        for (int ub = 0; ub < 4; ++ub) {
            int u0 = q * 32 + ub * 8;
            bf16x8 v;
#pragma unroll
            for (int k = 0; k < 8; ++k) v[k] = Xs[(u0 + k) * 64 + nl];
            long off = (long)((n * 256 + u0 * 2) ^ ((n & 7) << 4));
            *(bf16x8*)((char*)Bt + off) = v;
        }
    }
    __syncthreads();
    f32x4 acc[4][2];
    const f32x4 vz = {0.f, 0.f, 0.f, 0.f};
#pragma unroll
    for (int mi = 0; mi < 4; ++mi)
#pragma unroll
        for (int ni = 0; ni < 2; ++ni) acc[mi][ni] = vz;
    const char* XwB = (const char*)Xw;
    const char* BtB = (const char*)Bt;
    __builtin_amdgcn_s_setprio(1);
#pragma unroll
    for (int ks = 0; ks < 4; ++ks) {
        bf16x8 af[4], bfr[2];
#pragma unroll
        for (int mi = 0; mi < 4; ++mi) {
            int pp = mi * 16 + (lane & 15);
            af[mi] = *(const bf16x8*)(XwB + ((pp * 256 + ks * 64 + (lane >> 4) * 16) ^ ((pp & 7) << 4)));
        }
#pragma unroll
        for (int ni = 0; ni < 2; ++ni) {
            int n = wid * 32 + ni * 16 + (lane & 15);
            bfr[ni] = *(const bf16x8*)(BtB + ((n * 256 + ks * 64 + (lane >> 4) * 16) ^ ((n & 7) << 4)));
        }
#pragma unroll
        for (int mi = 0; mi < 4; ++mi)
#pragma unroll
            for (int ni = 0; ni < 2; ++ni)
                acc[mi][ni] = __builtin_amdgcn_mfma_f32_16x16x32_bf16(af[mi], bfr[ni], acc[mi][ni], 0, 0, 0);
    }
    __builtin_amdgcn_s_setprio(0);
    char* lb = (char*)Lbuf + (((long)blk) << 14);
#pragma unroll
    for (int mi = 0; mi < 4; ++mi)
#pragma unroll
        for (int ni = 0; ni < 2; ++ni)
#pragma unroll
            for (int j = 0; j < 4; ++j) {
                int pp = mi * 16 + (lane >> 4) * 4 + j;
                int n = wid * 32 + ni * 16 + (lane & 15);
                *(bf16*)(lb + ((pp * 256 + n * 2) ^ ((pp & 7) << 4))) = (bf16)acc[mi][ni][j];
            }
}

// ---------------- Pass B: sequential inter-chunk combine ----------------
__global__ __launch_bounds__(256) void k_scanB(bf16* __restrict__ Lbuf, const float* __restrict__ Pc) {
    int bh = blockIdx.x >> 2;
    int q = blockIdx.x & 3;
    int off = (q * 256 + threadIdx.x) * 8;
    long base = ((long)bh * NCH) << 13;
    float s[8] = {0.f};
#pragma unroll
    for (int c = 0; c < NCH; ++c) {
        bf16* p = Lbuf + base + ((long)c << 13) + off;
        bf16x8 L = *(bf16x8*)p;
        bf16x8 I;
#pragma unroll
        for (int k = 0; k < 8; ++k) I[k] = (bf16)s[k];
        float P = Pc[bh * NCH + c];
#pragma unroll
        for (int k = 0; k < 8; ++k) s[k] = P * s[k] + (float)L[k];
        *(bf16x8*)p = I;
    }
}

// ---------------- chunk Y via MFMA -> bf16 ----------------
__global__ __launch_bounds__(512) void k_chunkY(const bf16* __restrict__ bc,
                                                const float* __restrict__ Sarr, const float* __restrict__ dtc,
                                                const float* __restrict__ Dp,
                                                const bf16* __restrict__ XT, const bf16* __restrict__ Lbuf,
                                                bf16* __restrict__ ysb) {
    __shared__ bf16 Cs[128 * 128];
    __shared__ bf16 Bs[128 * 128];
    __shared__ bf16 Xts[64 * 128];
    __shared__ bf16 Is[64 * 128];
    __shared__ float S_lds[128], dt_lds[128];
    int blk = blockIdx.x;
    int b = blk / (NHEADS * NCH);
    int r = blk % (NHEADS * NCH);
    int h = r / NCH;
    int c = r % NCH;
    int tid = threadIdx.x, lane = tid & 63, wid = tid >> 6;
    long brow0 = (long)b * SEQ + c * QCH;
    const char* bcB = (const char*)bc;
#pragma unroll
    for (int i = 0; i < 4; ++i) {
        int trow = i * 32 + wid * 4 + (lane >> 4);
        int blk16 = lane & 15;
        const char* rp = bcB + (brow0 + trow) * 512;
        int sb = (blk16 ^ (trow & 7)) << 4;
        GLD(rp + 256 + sb, (char*)Cs + (i * 32 + wid * 4) * 256);
        GLD(rp + sb,       (char*)Bs + (i * 32 + wid * 4) * 256);
    }
    const char* xt = (const char*)XT + (((long)blk) << 14);
    const char* ib = (const char*)Lbuf + (((long)blk) << 14);
#pragma unroll
    for (int i = 0; i < 2; ++i) {
        GLD(xt + (long)(i * 512 + tid) * 16, (char*)Xts + (i * 512 + wid * 64) * 16);
        GLD(ib + (long)(i * 512 + tid) * 16, (char*)Is + (i * 512 + wid * 64) * 16);
    }
    if (tid < 128) { S_lds[tid] = Sarr[blk * QCH + tid]; dt_lds[tid] = dtc[blk * QCH + tid]; }
    float Dh = Dp[h];
    asm volatile("s_waitcnt vmcnt(4) lgkmcnt(0)" ::: "memory");
    bar_sync();
    const char* CsB = (const char*)Cs;
    char* BsB = (char*)Bs;
    const char* IsB = (const char*)Is;
    const char* XtB = (const char*)Xts;
    const f32x4 vz = {0.f, 0.f, 0.f, 0.f};
    int wmG = wid >> 2, wnG = wid & 3;
    f32x4 accg[4][2];
#pragma unroll
    for (int mi = 0; mi < 4; ++mi)
#pragma unroll
        for (int ni = 0; ni < 2; ++ni) accg[mi][ni] = vz;
#pragma unroll
    for (int ks = 0; ks < 4; ++ks) {
        bf16x8 af[4], bfr[2];
#pragma unroll
        for (int mi = 0; mi < 4; ++mi) {
            int t = wmG * 64 + mi * 16 + (lane & 15);
            af[mi] = *(const bf16x8*)(CsB + ((t * 256 + ks * 64 + (lane >> 4) * 16) ^ ((t & 7) << 4)));
        }
#pragma unroll
        for (int ni = 0; ni < 2; ++ni) {
            int u = wnG * 32 + ni * 16 + (lane & 15);
            bfr[ni] = *(const bf16x8*)(BsB + ((u * 256 + ks * 64 + (lane >> 4) * 16) ^ ((u & 7) << 4)));
        }
#pragma unroll
        for (int mi = 0; mi < 4; ++mi)
#pragma unroll
            for (int ni = 0; ni < 2; ++ni)
                accg[mi][ni] = __builtin_amdgcn_mfma_f32_16x16x32_bf16(af[mi], bfr[ni], accg[mi][ni], 0, 0, 0);
    }
    bar_sync();
#pragma unroll
    for (int mi = 0; mi < 4; ++mi) {
#pragma unroll
        for (int j = 0; j < 4; ++j) {
            int t = wmG * 64 + mi * 16 + (lane >> 4) * 4 + j;
            float St = S_lds[t];
#pragma unroll
            for (int ni = 0; ni < 2; ++ni) {
                int u = wnG * 32 + ni * 16 + (lane & 15);
                float v = 0.f;
                if (u <= t) v = accg[mi][ni][j] * __expf(St - S_lds[u]) * dt_lds[u];
                *(bf16*)(BsB + ((t * 256 + u * 2) ^ ((t & 7) << 4))) = (bf16)v;
            }
        }
    }
    asm volatile("s_waitcnt vmcnt(0) lgkmcnt(0)" ::: "memory");
    bar_sync();
    int wmY = wid >> 1, wnY = wid & 1;
    f32x4 accy[2][2];
#pragma unroll
    for (int mi = 0; mi < 2; ++mi)
#pragma unroll
        for (int ni = 0; ni < 2; ++ni) accy[mi][ni] = vz;
#pragma unroll
    for (int ks = 0; ks < 4; ++ks) {
        bf16x8 af[2], bfr[2];
#pragma unroll
        for (int mi = 0; mi < 2; ++mi) {
            int t = wmY * 32 + mi * 16 + (lane & 15);
            af[mi] = *(const bf16x8*)(CsB + ((t * 256 + ks * 64 + (lane >> 4) * 16) ^ ((t & 7) << 4)));
        }
#pragma unroll
        for (int ni = 0; ni < 2; ++ni) {
            int pp = wnY * 32 + ni * 16 + (lane & 15);
            bfr[ni] = *(const bf16x8*)(IsB + ((pp * 256 + ks * 64 + (lane >> 4) * 16) ^ ((pp & 7) << 4)));
        }
#pragma unroll
        for (int mi = 0; mi < 2; ++mi)
#pragma unroll
            for (int ni = 0; ni < 2; ++ni)
                accy[mi][ni] = __builtin_amdgcn_mfma_f32_16x16x32_bf16(af[mi], bfr[ni], accy[mi][ni], 0, 0, 0);
    }
#pragma unroll
    for (int mi = 0; mi < 2; ++mi)
#pragma unroll
        for (int j = 0; j < 4; ++j) {
            int t = wmY * 32 + mi * 16 + (lane >> 4) * 4 + j;
            float e = __expf(S_lds[t]);
#pragma unroll
            for (int ni = 0; ni < 2; ++ni) accy[mi][ni][j] *= e;
        }
#pragma unroll
    for (int ks = 0; ks < 4; ++ks) {
        bf16x8 af[2], bfr[2];
#pragma unroll
        for (int mi = 0; mi < 2; ++mi) {
            int t = wmY * 32 + mi * 16 + (lane & 15);
            af[mi] = *(const bf16x8*)(BsB + ((t * 256 + ks * 64 + (lane >> 4) * 16) ^ ((t & 7) << 4)));
        }
#pragma unroll
        for (int ni = 0; ni < 2; ++ni) {
            int pp = wnY * 32 + ni * 16 + (lane & 15);
            bfr[ni] = *(const bf16x8*)(XtB + ((pp * 256 + ks * 64 + (lane >> 4) * 16) ^ ((pp & 7) << 4)));
        }
#pragma unroll
        for (int mi = 0; mi < 2; ++mi)
#pragma unroll
            for (int ni = 0; ni < 2; ++ni)
                accy[mi][ni] = __builtin_amdgcn_mfma_f32_16x16x32_bf16(af[mi], bfr[ni], accy[mi][ni], 0, 0, 0);
    }
#pragma unroll
    for (int mi = 0; mi < 2; ++mi)
#pragma unroll
        for (int ni = 0; ni < 2; ++ni)
#pragma unroll
            for (int j = 0; j < 4; ++j) {
                int t = wmY * 32 + mi * 16 + (lane >> 4) * 4 + j;
                int pp = wnY * 32 + ni * 16 + (lane & 15);
                float xv = (float)*(const bf16*)(XtB + ((pp * 256 + t * 2) ^ ((pp & 7) << 4)));
                ysb[(brow0 + t) * DINNER + h * HEADDIM + pp] = (bf16)(accy[mi][ni][j] + Dh * xv);
            }
}

// ---------------- gated rmsnorm ----------------
__global__ __launch_bounds__(256) void k_gated(const bf16* __restrict__ ys, const bf16* __restrict__ zx,
                                               const float* __restrict__ w, bf16* __restrict__ out) {
    __shared__ float sm[4];
    int r = blockIdx.x, tid = threadIdx.x;
    float v[6]; float ss = 0.f;
#pragma unroll
    for (int k = 0; k < 6; ++k) {
        int d = tid + k * 256;
        float z = (float)zx[(long)r * NPAD + d];
        float t = (float)ys[(long)r * DINNER + d] * fsilu(z);
        v[k] = t; ss += t * t;
    }
#pragma unroll
    for (int off = 32; off; off >>= 1) ss += __shfl_down(ss, off, 64);
    if ((tid & 63) == 0) sm[tid >> 6] = ss;
    __syncthreads();
    float tot = sm[0] + sm[1] + sm[2] + sm[3];
    float sc = rsqrtf(tot / (float)DINNER + EPS);
#pragma unroll
    for (int k = 0; k < 6; ++k) {
        int d = tid + k * 256;
        out[(long)r * DINNER + d] = (bf16)(v[k] * sc * w[d]);
    }
}

// ---------------- head: 32 rows/block, 1 atomic/block ----------------
__global__ __launch_bounds__(256) void k_head(const bf16* __restrict__ hn, const float* __restrict__ Wh,
                                              const float* __restrict__ y, float* __restrict__ out,
                                              float* __restrict__ loss) {
    __shared__ float sl[4];
    int tid = threadIdx.x, lane = tid & 63, wid = tid >> 6;
    float wv[5][12];
#pragma unroll
    for (int o = 0; o < 5; ++o)
#pragma unroll
        for (int j = 0; j < 12; ++j) wv[o][j] = Wh[o * DMODEL + lane * 12 + j];
    float lsum = 0.f;
#pragma unroll
    for (int rr = 0; rr < 8; ++rr) {
        long r = (long)blockIdx.x * 32 + wid * 8 + rr;
        const bf16* hp = hn + r * DMODEL + lane * 12;
        float hv[12];
#pragma unroll
        for (int q = 0; q < 3; ++q) {
            bf16x4 v4 = *(const bf16x4*)(hp + q * 4);
#pragma unroll
            for (int j = 0; j < 4; ++j) hv[q * 4 + j] = (float)v4[j];
        }
        float acc[5];
#pragma unroll
        for (int o = 0; o < 5; ++o) {
            float a = 0.f;
#pragma unroll
            for (int j = 0; j < 12; ++j) a += hv[j] * wv[o][j];
            acc[o] = a;
        }
#pragma unroll
        for (int o = 0; o < 5; ++o)
#pragma unroll
            for (int m = 32; m; m >>= 1) acc[o] += __shfl_xor(acc[o], m, 64);
        if (lane == 0) {
#pragma unroll
            for (int o = 0; o < 5; ++o) {
                out[r * 5 + o] = acc[o];
                float d = acc[o] - y[r * 5 + o];
                lsum += d * d;
            }
        }
    }
    if (lane == 0) sl[wid] = lsum;
    __syncthreads();
    if (tid == 0) atomicAdd(loss, (sl[0] + sl[1] + sl[2] + sl[3]) * (1.f / ((float)ROWS * 5.f)));
}

extern "C" void kernel_launch(void* const* d_in, const int* in_sizes, int n_in,
                              void* d_out, int out_size, void* d_ws, size_t ws_size,
                              hipStream_t stream) {
    const float* x      = (const float*)d_in[0];
    const float* y      = (const float*)d_in[1];
    const float* W_emb  = (const float*)d_in[2];
    const float* b_emb  = (const float*)d_in[3];
    const float* W_in   = (const float*)d_in[4];
    const float* conv_w = (const float*)d_in[5];
    const float* conv_b = (const float*)d_in[6];
    const float* dt_bias= (const float*)d_in[7];
    const float* A_log  = (const float*)d_in[8];
    const float* Dp     = (const float*)d_in[9];
    const float* norm_w = (const float*)d_in[10];
    const float* W_out  = (const float*)d_in[11];
    const float* bnw    = (const float*)d_in[12];
    const float* nfw    = (const float*)d_in[13];
    const float* W_head = (const float*)d_in[14];

    char* ws = (char*)d_ws;
    float* res  = (float*)ws;  ws += (size_t)ROWS * DMODEL * 4;
    bf16*  Lbuf = (bf16*)ws;   ws += (size_t)BATCH * NHEADS * NCH * 8192 * 2;
    bf16*  hnb  = (bf16*)ws;   ws += (size_t)ROWS * DMODEL * 2;
    bf16*  zx   = (bf16*)ws;   ws += (size_t)ROWS * NPAD * 2;
    bf16*  bc   = (bf16*)ws;   ws += (size_t)ROWS * 256 * 2;
    bf16*  ysb  = (bf16*)ws;   ws += (size_t)ROWS * DINNER * 2;
    bf16*  yfb  = (bf16*)ws;   ws += (size_t)ROWS * DINNER * 2;
    bf16*  Wib  = (bf16*)ws;   ws += (size_t)NLAYER * NPADW * DMODEL * 2;
    bf16*  Wob  = (bf16*)ws;   ws += (size_t)NLAYER * DMODEL * DINNER * 2;
    float* Pcb  = (float*)ws;  ws += (size_t)BATCH * NHEADS * NCH * 4;
    float* Sarr = (float*)ws;  ws += (size_t)BATCH * NHEADS * NCH * QCH * 4;
    float* dtc  = (float*)ws;  ws += (size_t)BATCH * NHEADS * NCH * QCH * 4;
    bf16*  XT   = (bf16*)ws;   ws += (size_t)BATCH * NHEADS * NCH * 8192 * 2;

    float* out_p  = (float*)d_out;
    float* loss_p = out_p + (size_t)ROWS * 5;

    hipMemsetAsync(loss_p, 0, 4, stream);
    k_embed<<<ROWS * DMODEL / 256, 256, 0, stream>>>(x, W_emb, b_emb, res);
    k_cvt_in<<<NLAYER * NPADW * DMODEL / 256, 256, 0, stream>>>(W_in, Wib);
    k_cvt_out<<<NLAYER * DMODEL * DINNER / 256, 256, 0, stream>>>(W_out, Wob);

    const int NBHC = BATCH * NHEADS * NCH;   // 1536
    for (int l = 0; l < NLAYER; ++l) {
        const float* cw_l = conv_w + (size_t)l * CONVDIM * 4;
        const float* cb_l = conv_b + (size_t)l * CONVDIM;
        k_rmsnorm<<<ROWS, 256, 0, stream>>>(res, bnw + l * DMODEL, hnb);
        dim3 g1(ROWS / 256, NPADW / 256);
        k_gemm<bf16, 256, 256, 512, false><<<g1, 512, 0, stream>>>(hnb, Wib + (size_t)l * NPADW * DMODEL, zx, DMODEL, NPAD, NPAD);
        k_convBC<<<ROWS * 32 / 256, 256, 0, stream>>>(zx, cw_l, cb_l, bc);
        k_prepL<<<NBHC, 256, 0, stream>>>(zx, bc, cw_l, cb_l, dt_bias + l * NHEADS, A_log + l * NHEADS,
                                          Sarr, dtc, Pcb, XT, Lbuf);
        k_scanB<<<BATCH * NHEADS * 4, 256, 0, stream>>>(Lbuf, Pcb);
        k_chunkY<<<NBHC, 512, 0, stream>>>(bc, Sarr, dtc, Dp + l * NHEADS, XT, Lbuf, ysb);
        k_gated<<<ROWS, 256, 0, stream>>>(ysb, zx, norm_w + l * DINNER, yfb);
        dim3 g2(ROWS / 128, DMODEL / 64);
        k_gemm<float, 128, 64, 256, true><<<g2, 256, 0, stream>>>(yfb, Wob + (size_t)l * DMODEL * DINNER, res, DINNER, DMODEL, DMODEL);
    }

    k_rmsnorm<<<ROWS, 256, 0, stream>>>(res, nfw, hnb);
    k_head<<<256, 256, 0, stream>>>(hnb, W_head, y, out_p, loss_p);
}

// Round 12
// 1705.880 us; speedup vs baseline: 6.8121x; 1.0153x over previous
//
#include <hip/hip_runtime.h>
#include <hip/hip_bf16.h>
#include <math.h>

#define BATCH 4
#define SEQ 2048
#define DMODEL 768
#define NLAYER 8
#define DINNER 1536
#define HEADDIM 64
#define NHEADS 24
#define DSTATE 128
#define CONVDIM 1792
#define DINPROJ 3352
#define NPAD 3456
#define NPADW 3584
#define ROWS (BATCH*SEQ)
#define EPS 1e-5f
#define QCH 128
#define NCH (SEQ/QCH)

typedef __bf16 bf16;
typedef bf16 bf16x8 __attribute__((ext_vector_type(8)));
typedef bf16 bf16x4 __attribute__((ext_vector_type(4)));
typedef float f32x4 __attribute__((ext_vector_type(4)));

#define GLD(src, dst) __builtin_amdgcn_global_load_lds( \
    (const __attribute__((address_space(1))) void*)(src), \
    (__attribute__((address_space(3))) void*)(dst), 16, 0, 0)

__device__ __forceinline__ void bar_sync() {
    asm volatile("" ::: "memory");
    __builtin_amdgcn_s_barrier();
    asm volatile("" ::: "memory");
}

__device__ __forceinline__ float fsilu(float x) { return x / (1.f + __expf(-x)); }

// ---------------- embed: res = x @ W_emb^T + b_emb ----------------
__global__ void k_embed(const float* __restrict__ x, const float* __restrict__ We,
                        const float* __restrict__ be, float* __restrict__ res) {
    int idx = blockIdx.x * 256 + threadIdx.x;
    int d = idx % DMODEL; int bl = idx / DMODEL;
    float acc = be[d];
#pragma unroll
    for (int i = 0; i < 6; ++i) acc += x[bl * 6 + i] * We[d * 6 + i];
    res[idx] = acc;
}

// ---------------- read-only rmsnorm (vectorized, 192 thr x float4) ----------------
__global__ __launch_bounds__(192) void k_rmsnorm(const float* __restrict__ res,
                                                 const float* __restrict__ w,
                                                 bf16* __restrict__ out) {
    __shared__ float sm[3];
    int r = blockIdx.x, tid = threadIdx.x;
    int d0 = tid * 4;
    float4 v = *(const float4*)(res + (long)r * DMODEL + d0);
    float ss = v.x * v.x + v.y * v.y + v.z * v.z + v.w * v.w;
#pragma unroll
    for (int off = 32; off; off >>= 1) ss += __shfl_down(ss, off, 64);
    if ((tid & 63) == 0) sm[tid >> 6] = ss;
    __syncthreads();
    float sc = rsqrtf((sm[0] + sm[1] + sm[2]) / (float)DMODEL + EPS);
    float4 wv = *(const float4*)(w + d0);
    bf16x4 o;
    o[0] = (bf16)(v.x * sc * wv.x);
    o[1] = (bf16)(v.y * sc * wv.y);
    o[2] = (bf16)(v.z * sc * wv.z);
    o[3] = (bf16)(v.w * sc * wv.w);
    *(bf16x4*)(out + (long)r * DMODEL + d0) = o;
}

// ---------------- batched weight conversions ----------------
__global__ void k_cvt_in(const float* __restrict__ src, bf16* __restrict__ dst) {
    int idx = blockIdx.x * 256 + threadIdx.x;          // NLAYER*NPADW*DMODEL
    int l = idx / (NPADW * DMODEL);
    int rem = idx % (NPADW * DMODEL);
    int n = rem / DMODEL;
    int d = rem % DMODEL;
    dst[idx] = (n < DINPROJ) ? (bf16)src[(long)l * DINPROJ * DMODEL + n * DMODEL + d] : (bf16)0.f;
}
__global__ void k_cvt_out(const float* __restrict__ src, bf16* __restrict__ dst) {
    int idx = blockIdx.x * 256 + threadIdx.x;
    dst[idx] = (bf16)src[idx];
}

// ---------------- bf16 MFMA GEMM: C[M,N] (=|+=) A[M,K] @ B[N,K]^T ----------------
template <typename OT, int BM, int BN, int TH, bool ACC>
__global__ __launch_bounds__(TH) void k_gemm(const bf16* __restrict__ A, const bf16* __restrict__ B,
                                             OT* __restrict__ C, int K, int ldc, int Nact) {
    constexpr int NW  = TH / 64;
    constexpr int nWn = (BN / 64 < 4) ? BN / 64 : 4;
    constexpr int nWm = NW / nWn;
    constexpr int WMR = BM / nWm;
    constexpr int MI  = WMR / 16;
    constexpr int MH  = MI / 2;
    constexpr int NI  = 4;
    constexpr int RG  = TH / 8;
    constexpr int AG  = BM / RG;
    constexpr int BG  = BN / RG;
    __shared__ bf16 As[2][BM * 64];
    __shared__ bf16 Bs[2][BN * 64];
    const int tid = threadIdx.x;
    const int lane = tid & 63;
    const int w = tid >> 6;
    const int wm = w / nWn, wn = w % nWn;
    const long rowA0 = (long)blockIdx.x * BM;
    const long rowB0 = (long)blockIdx.y * BN;
    const int srow = tid >> 3;
    const int scol = ((tid & 7) ^ (srow & 7)) * 8;
    const bf16* Ab = A + rowA0 * K + scol;
    const bf16* Bb = B + rowB0 * K + scol;

    f32x4 acc[MI][NI];
    const f32x4 vz = {0.f, 0.f, 0.f, 0.f};
#pragma unroll
    for (int mi = 0; mi < MI; ++mi)
#pragma unroll
        for (int ni = 0; ni < NI; ++ni) acc[mi][ni] = vz;

    auto stage = [&](int buf, int kt) {
#pragma unroll
        for (int j = 0; j < AG; ++j)
            GLD(Ab + (long)(j * RG + srow) * K + kt, &As[buf][(j * TH + w * 64) * 8]);
#pragma unroll
        for (int j = 0; j < BG; ++j)
            GLD(Bb + (long)(j * RG + srow) * K + kt, &Bs[buf][(j * TH + w * 64) * 8]);
    };
    auto waitv = [&]() {
        if constexpr (AG + BG == 8) asm volatile("s_waitcnt vmcnt(8)" ::: "memory");
        else                        asm volatile("s_waitcnt vmcnt(6)" ::: "memory");
    };

    bf16x8 bfr[NI][2];
    bf16x8 af[MH][2];
    auto rd_bfr = [&](int buf) {
        const char* BsB = (const char*)Bs[buf];
#pragma unroll
        for (int ni = 0; ni < NI; ++ni)
#pragma unroll
            for (int ks = 0; ks < 2; ++ks) {
                int r = wn * 64 + ni * 16 + (lane & 15);
                bfr[ni][ks] = *(const bf16x8*)(BsB + r * 128 + ((ks * 64 + (lane >> 4) * 16) ^ ((r & 7) << 4)));
            }
    };
    auto rd_af = [&](int buf, int m0) {
        const char* AsB = (const char*)As[buf];
#pragma unroll
        for (int mi = 0; mi < MH; ++mi)
#pragma unroll
            for (int ks = 0; ks < 2; ++ks) {
                int r = wm * WMR + (m0 + mi) * 16 + (lane & 15);
                af[mi][ks] = *(const bf16x8*)(AsB + r * 128 + ((ks * 64 + (lane >> 4) * 16) ^ ((r & 7) << 4)));
            }
    };
    auto do_half = [&](int m0) {
#pragma unroll
        for (int mi = 0; mi < MH; ++mi)
#pragma unroll
            for (int ni = 0; ni < NI; ++ni)
#pragma unroll
                for (int ks = 0; ks < 2; ++ks)
                    acc[m0 + mi][ni] = __builtin_amdgcn_mfma_f32_16x16x32_bf16(af[mi][ks], bfr[ni][ks], acc[m0 + mi][ni], 0, 0, 0);
    };

    const int NT = K / 64;
    stage(0, 0);
    stage(1, 64);
    for (int t = 0; t < NT - 2; ++t) {
        waitv();
        bar_sync();
        rd_bfr(t & 1);
        rd_af(t & 1, 0);
        do_half(0);
        rd_af(t & 1, MH);
        asm volatile("s_waitcnt lgkmcnt(0)" ::: "memory");
        bar_sync();
        stage(t & 1, (t + 2) * 64);
        __builtin_amdgcn_sched_barrier(0);
        do_half(MH);
    }
    {
        waitv();
        bar_sync();
        rd_bfr((NT - 2) & 1);
        rd_af((NT - 2) & 1, 0);
        do_half(0);
        rd_af((NT - 2) & 1, MH);
        do_half(MH);
    }
    {
        asm volatile("s_waitcnt vmcnt(0)" ::: "memory");
        bar_sync();
        rd_bfr((NT - 1) & 1);
        rd_af((NT - 1) & 1, 0);
        do_half(0);
        rd_af((NT - 1) & 1, MH);
        do_half(MH);
    }

    const int crow = (lane >> 4) * 4;
    const int ccol = lane & 15;
#pragma unroll
    for (int mi = 0; mi < MI; ++mi)
#pragma unroll
        for (int ni = 0; ni < NI; ++ni) {
            long r0 = rowA0 + wm * WMR + mi * 16 + crow;
            long c0 = rowB0 + wn * 64 + ni * 16 + ccol;
            if ((int)c0 < Nact) {
#pragma unroll
                for (int j = 0; j < 4; ++j) {
                    if constexpr (ACC) C[(r0 + j) * ldc + c0] += (OT)acc[mi][ni][j];
                    else               C[(r0 + j) * ldc + c0]  = (OT)acc[mi][ni][j];
                }
            }
        }
}

// ---------------- slim conv for B/C channels only -> bc[ROWS][256] ----------------
__global__ void k_convBC(const bf16* __restrict__ zx, const float* __restrict__ cw,
                         const float* __restrict__ cb, bf16* __restrict__ bc) {
    int idx = blockIdx.x * 256 + threadIdx.x;   // ROWS * 32
    int c8 = idx & 31; int blt = idx >> 5;
    int t = blt % SEQ;
    int ch = DINNER + c8 * 8;
    long bbase = (long)(blt - t) * NPAD;
    float cwa[8][4];
#pragma unroll
    for (int j = 0; j < 8; ++j) {
        float4 tv = *(const float4*)(cw + (ch + j) * 4);
        cwa[j][0] = tv.x; cwa[j][1] = tv.y; cwa[j][2] = tv.z; cwa[j][3] = tv.w;
    }
    float acc[8];
#pragma unroll
    for (int j = 0; j < 8; ++j) acc[j] = cb[ch + j];
#pragma unroll
    for (int k = 0; k < 4; ++k) {
        int tt = t + k - 3;
        if (tt >= 0) {
            bf16x8 v = *(const bf16x8*)(zx + bbase + (long)tt * NPAD + DINNER + ch);
#pragma unroll
            for (int j = 0; j < 8; ++j) acc[j] += (float)v[j] * cwa[j][k];
        }
    }
    bf16x8 o;
#pragma unroll
    for (int j = 0; j < 8; ++j) o[j] = (bf16)fsilu(acc[j]);
    *(bf16x8*)(bc + (long)blt * 256 + c8 * 8) = o;
}

// ---------------- fused conv(X) + prep + stateL ----------------
__global__ __launch_bounds__(256) void k_prepL(const bf16* __restrict__ zx, const bf16* __restrict__ bc,
                                               const float* __restrict__ cw_l, const float* __restrict__ cb_l,
                                               const float* __restrict__ dt_bias_l,
                                               const float* __restrict__ Alog,
                                               float* __restrict__ Sarr, float* __restrict__ dtc,
                                               float* __restrict__ Pcb,
                                               bf16* __restrict__ XT, bf16* __restrict__ Lbuf) {
    __shared__ float S_lds[128], wl_lds[128], wtot[2];
    __shared__ bf16 Xs[136 * 64];
    __shared__ bf16 Xw[64 * 128];
    __shared__ bf16 Bt[128 * 128];
    int blk = blockIdx.x;
    int b = blk / (NHEADS * NCH);
    int r = blk % (NHEADS * NCH);
    int h = r / NCH;
    int c = r % NCH;
    int tid = threadIdx.x, lane = tid & 63, wid = tid >> 6;
    long brow0 = (long)b * SEQ + c * QCH;
#pragma unroll
    for (int i = 0; i < 5; ++i) {
        int base = i * 256 + wid * 64;
        if (base < 1048) {
            int idx = base + lane;
            long g = brow0 - 3 + (idx >> 3);
            if (g < 0) g = 0;
            if (g > (long)ROWS - 1) g = (long)ROWS - 1;
            GLD(zx + g * NPAD + DINNER + h * HEADDIM + (idx & 7) * 8,
                (char*)Xs + (long)base * 16);
        }
    }
    float ps = 0.f, dtv = 0.f;
    if (tid < 128) {
        float raw = (float)zx[(brow0 + tid) * NPAD + DINNER + CONVDIM + h] + dt_bias_l[h];
        dtv = (raw > 15.f) ? raw : log1pf(__expf(raw));
        float Ah = -__expf(Alog[h]);
        ps = dtv * Ah;
#pragma unroll
        for (int off = 1; off < 64; off <<= 1) {
            float o = __shfl_up(ps, off, 64);
            if ((tid & 63) >= off) ps += o;
        }
        if ((tid & 63) == 63) wtot[tid >> 6] = ps;
    }
    __syncthreads();
    if (tid < 128) {
        if (tid >= 64) ps += wtot[0];
        S_lds[tid] = ps;
    }
    __syncthreads();
    float Sl = S_lds[127];
    if (tid < 128) {
        wl_lds[tid] = __expf(Sl - ps) * dtv;
        Sarr[blk * QCH + tid] = ps;
        dtc[blk * QCH + tid] = dtv;
        if (tid == 127) Pcb[blk] = __expf(Sl);
    }
    __syncthreads();
    {
        int p = tid >> 2, q = tid & 3;
        float4 cwv = *(const float4*)(cw_l + (h * HEADDIM + p) * 4);
        float cbv = cb_l[h * HEADDIM + p];
        float cwa[4] = {cwv.x, cwv.y, cwv.z, cwv.w};
        char* xtb = (char*)XT + (((long)blk) << 14);
#pragma unroll
        for (int ub = 0; ub < 4; ++ub) {
            int u0 = q * 32 + ub * 8;
            bf16x8 vx, vw;
#pragma unroll
            for (int k = 0; k < 8; ++k) {
                int u = u0 + k;
                float a = cbv;
#pragma unroll
                for (int tt = 0; tt < 4; ++tt) {
                    if (c > 0 || u + tt >= 3)
                        a += (float)Xs[(u + tt) * 64 + p] * cwa[tt];
                }
                bf16 xb = (bf16)fsilu(a);
                vx[k] = xb;
                vw[k] = (bf16)((float)xb * wl_lds[u]);
            }
            long off = (long)((p * 256 + u0 * 2) ^ ((p & 7) << 4));
            *(bf16x8*)(xtb + off) = vx;
            *(bf16x8*)((char*)Xw + off) = vw;
        }
    }
#pragma unroll
    for (int nb = 0; nb < 2; ++nb) {
        __syncthreads();
#pragma unroll
        for (int i = 0; i < 4; ++i) {
            int idx = i * 256 + tid;
            GLD(bc + (brow0 + (idx >> 3)) * 256 + nb * 64 + (idx & 7) * 8,
                (char*)Xs + (i * 256 + wid * 64) * 16);
        }
        __syncthreads();
        int nl = tid >> 2, q = tid & 3;
        int n = nb * 64 + nl;
#pragma unroll
        for (int ub = 0; ub < 4; ++ub) {
            int u0 = q * 32 + ub * 8;
            bf16x8 v;
#pragma unroll
            for (int k = 0; k < 8; ++k) v[k] = Xs[(u0 + k) * 64 + nl];
            long off = (long)((n * 256 + u0 * 2) ^ ((n & 7) << 4));
            *(bf16x8*)((char*)Bt + off) = v;
        }
    }
    __syncthreads();
    f32x4 acc[4][2];
    const f32x4 vz = {0.f, 0.f, 0.f, 0.f};
#pragma unroll
    for (int mi = 0; mi < 4; ++mi)
#pragma unroll
        for (int ni = 0; ni < 2; ++ni) acc[mi][ni] = vz;
    const char* XwB = (const char*)Xw;
    const char* BtB = (const char*)Bt;
    __builtin_amdgcn_s_setprio(1);
#pragma unroll
    for (int ks = 0; ks < 4; ++ks) {
        bf16x8 af[4], bfr[2];
#pragma unroll
        for (int mi = 0; mi < 4; ++mi) {
            int pp = mi * 16 + (lane & 15);
            af[mi] = *(const bf16x8*)(XwB + ((pp * 256 + ks * 64 + (lane >> 4) * 16) ^ ((pp & 7) << 4)));
        }
#pragma unroll
        for (int ni = 0; ni < 2; ++ni) {
            int n = wid * 32 + ni * 16 + (lane & 15);
            bfr[ni] = *(const bf16x8*)(BtB + ((n * 256 + ks * 64 + (lane >> 4) * 16) ^ ((n & 7) << 4)));
        }
#pragma unroll
        for (int mi = 0; mi < 4; ++mi)
#pragma unroll
            for (int ni = 0; ni < 2; ++ni)
                acc[mi][ni] = __builtin_amdgcn_mfma_f32_16x16x32_bf16(af[mi], bfr[ni], acc[mi][ni], 0, 0, 0);
    }
    __builtin_amdgcn_s_setprio(0);
    char* lb = (char*)Lbuf + (((long)blk) << 14);
#pragma unroll
    for (int mi = 0; mi < 4; ++mi)
#pragma unroll
        for (int ni = 0; ni < 2; ++ni)
#pragma unroll
            for (int j = 0; j < 4; ++j) {
                int pp = mi * 16 + (lane >> 4) * 4 + j;
                int n = wid * 32 + ni * 16 + (lane & 15);
                *(bf16*)(lb + ((pp * 256 + n * 2) ^ ((pp & 7) << 4))) = (bf16)acc[mi][ni][j];
            }
}

// ---------------- Pass B: sequential inter-chunk combine ----------------
__global__ __launch_bounds__(256) void k_scanB(bf16* __restrict__ Lbuf, const float* __restrict__ Pc) {
    int bh = blockIdx.x >> 2;
    int q = blockIdx.x & 3;
    int off = (q * 256 + threadIdx.x) * 8;
    long base = ((long)bh * NCH) << 13;
    float s[8] = {0.f};
#pragma unroll
    for (int c = 0; c < NCH; ++c) {
        bf16* p = Lbuf + base + ((long)c << 13) + off;
        bf16x8 L = *(bf16x8*)p;
        bf16x8 I;
#pragma unroll
        for (int k = 0; k < 8; ++k) I[k] = (bf16)s[k];
        float P = Pc[bh * NCH + c];
#pragma unroll
        for (int k = 0; k < 8; ++k) s[k] = P * s[k] + (float)L[k];
        *(bf16x8*)p = I;
    }
}

// ---------------- chunk Y via MFMA -> bf16 (Cs/Bs in LDS; X/I fragments direct from global) ----------------
__global__ __launch_bounds__(512) void k_chunkY(const bf16* __restrict__ bc,
                                                const float* __restrict__ Sarr, const float* __restrict__ dtc,
                                                const float* __restrict__ Dp,
                                                const bf16* __restrict__ XT, const bf16* __restrict__ Lbuf,
                                                bf16* __restrict__ ysb) {
    __shared__ bf16 Cs[128 * 128];
    __shared__ bf16 Bs[128 * 128];
    __shared__ float S_lds[128], dt_lds[128];
    int blk = blockIdx.x;
    int b = blk / (NHEADS * NCH);
    int r = blk % (NHEADS * NCH);
    int h = r / NCH;
    int c = r % NCH;
    int tid = threadIdx.x, lane = tid & 63, wid = tid >> 6;
    long brow0 = (long)b * SEQ + c * QCH;
    const char* bcB = (const char*)bc;
#pragma unroll
    for (int i = 0; i < 4; ++i) {
        int trow = i * 32 + wid * 4 + (lane >> 4);
        int blk16 = lane & 15;
        const char* rp = bcB + (brow0 + trow) * 512;
        int sb = (blk16 ^ (trow & 7)) << 4;
        GLD(rp + 256 + sb, (char*)Cs + (i * 32 + wid * 4) * 256);
        GLD(rp + sb,       (char*)Bs + (i * 32 + wid * 4) * 256);
    }
    if (tid < 128) { S_lds[tid] = Sarr[blk * QCH + tid]; dt_lds[tid] = dtc[blk * QCH + tid]; }
    float Dh = Dp[h];
    const char* xtG = (const char*)XT + (((long)blk) << 14);
    const char* ibG = (const char*)Lbuf + (((long)blk) << 14);
    asm volatile("s_waitcnt vmcnt(0) lgkmcnt(0)" ::: "memory");
    bar_sync();
    const char* CsB = (const char*)Cs;
    char* BsB = (char*)Bs;
    const f32x4 vz = {0.f, 0.f, 0.f, 0.f};
    int wmG = wid >> 2, wnG = wid & 3;
    f32x4 accg[4][2];
#pragma unroll
    for (int mi = 0; mi < 4; ++mi)
#pragma unroll
        for (int ni = 0; ni < 2; ++ni) accg[mi][ni] = vz;
#pragma unroll
    for (int ks = 0; ks < 4; ++ks) {
        bf16x8 af[4], bfr[2];
#pragma unroll
        for (int mi = 0; mi < 4; ++mi) {
            int t = wmG * 64 + mi * 16 + (lane & 15);
            af[mi] = *(const bf16x8*)(CsB + ((t * 256 + ks * 64 + (lane >> 4) * 16) ^ ((t & 7) << 4)));
        }
#pragma unroll
        for (int ni = 0; ni < 2; ++ni) {
            int u = wnG * 32 + ni * 16 + (lane & 15);
            bfr[ni] = *(const bf16x8*)(BsB + ((u * 256 + ks * 64 + (lane >> 4) * 16) ^ ((u & 7) << 4)));
        }
#pragma unroll
        for (int mi = 0; mi < 4; ++mi)
#pragma unroll
            for (int ni = 0; ni < 2; ++ni)
                accg[mi][ni] = __builtin_amdgcn_mfma_f32_16x16x32_bf16(af[mi], bfr[ni], accg[mi][ni], 0, 0, 0);
    }
    bar_sync();
#pragma unroll
    for (int mi = 0; mi < 4; ++mi) {
#pragma unroll
        for (int j = 0; j < 4; ++j) {
            int t = wmG * 64 + mi * 16 + (lane >> 4) * 4 + j;
            float St = S_lds[t];
#pragma unroll
            for (int ni = 0; ni < 2; ++ni) {
                int u = wnG * 32 + ni * 16 + (lane & 15);
                float v = 0.f;
                if (u <= t) v = accg[mi][ni][j] * __expf(St - S_lds[u]) * dt_lds[u];
                *(bf16*)(BsB + ((t * 256 + u * 2) ^ ((t & 7) << 4))) = (bf16)v;
            }
        }
    }
    asm volatile("s_waitcnt lgkmcnt(0)" ::: "memory");
    bar_sync();
    int wmY = wid >> 1, wnY = wid & 1;
    f32x4 accy[2][2];
#pragma unroll
    for (int mi = 0; mi < 2; ++mi)
#pragma unroll
        for (int ni = 0; ni < 2; ++ni) accy[mi][ni] = vz;
    // Yinter = C @ I^T : I fragments read directly from global (pre-swizzled layout)
#pragma unroll
    for (int ks = 0; ks < 4; ++ks) {
        bf16x8 af[2], bfr[2];
#pragma unroll
        for (int mi = 0; mi < 2; ++mi) {
            int t = wmY * 32 + mi * 16 + (lane & 15);
            af[mi] = *(const bf16x8*)(CsB + ((t * 256 + ks * 64 + (lane >> 4) * 16) ^ ((t & 7) << 4)));
        }
#pragma unroll
        for (int ni = 0; ni < 2; ++ni) {
            int pp = wnY * 32 + ni * 16 + (lane & 15);
            bfr[ni] = *(const bf16x8*)(ibG + ((pp * 256 + ks * 64 + (lane >> 4) * 16) ^ ((pp & 7) << 4)));
        }
#pragma unroll
        for (int mi = 0; mi < 2; ++mi)
#pragma unroll
            for (int ni = 0; ni < 2; ++ni)
                accy[mi][ni] = __builtin_amdgcn_mfma_f32_16x16x32_bf16(af[mi], bfr[ni], accy[mi][ni], 0, 0, 0);
    }
#pragma unroll
    for (int mi = 0; mi < 2; ++mi)
#pragma unroll
        for (int j = 0; j < 4; ++j) {
            int t = wmY * 32 + mi * 16 + (lane >> 4) * 4 + j;
            float e = __expf(S_lds[t]);
#pragma unroll
            for (int ni = 0; ni < 2; ++ni) accy[mi][ni][j] *= e;
        }
    // Yintra += MG @ XT^T : X fragments direct from global
#pragma unroll
    for (int ks = 0; ks < 4; ++ks) {
        bf16x8 af[2], bfr[2];
#pragma unroll
        for (int mi = 0; mi < 2; ++mi) {
            int t = wmY * 32 + mi * 16 + (lane & 15);
            af[mi] = *(const bf16x8*)(BsB + ((t * 256 + ks * 64 + (lane >> 4) * 16) ^ ((t & 7) << 4)));
        }
#pragma unroll
        for (int ni = 0; ni < 2; ++ni) {
            int pp = wnY * 32 + ni * 16 + (lane & 15);
            bfr[ni] = *(const bf16x8*)(xtG + ((pp * 256 + ks * 64 + (lane >> 4) * 16) ^ ((pp & 7) << 4)));
        }
#pragma unroll
        for (int mi = 0; mi < 2; ++mi)
#pragma unroll
            for (int ni = 0; ni < 2; ++ni)
                accy[mi][ni] = __builtin_amdgcn_mfma_f32_16x16x32_bf16(af[mi], bfr[ni], accy[mi][ni], 0, 0, 0);
    }
#pragma unroll
    for (int mi = 0; mi < 2; ++mi)
#pragma unroll
        for (int ni = 0; ni < 2; ++ni)
#pragma unroll
            for (int j = 0; j < 4; ++j) {
                int t = wmY * 32 + mi * 16 + (lane >> 4) * 4 + j;
                int pp = wnY * 32 + ni * 16 + (lane & 15);
                float xv = (float)*(const bf16*)(xtG + ((pp * 256 + t * 2) ^ ((pp & 7) << 4)));
                ysb[(brow0 + t) * DINNER + h * HEADDIM + pp] = (bf16)(accy[mi][ni][j] + Dh * xv);
            }
}

// ---------------- gated rmsnorm (vectorized, 192 thr x bf16x8) ----------------
__global__ __launch_bounds__(192) void k_gated(const bf16* __restrict__ ys, const bf16* __restrict__ zx,
                                               const float* __restrict__ w, bf16* __restrict__ out) {
    __shared__ float sm[3];
    int r = blockIdx.x, tid = threadIdx.x;
    int d0 = tid * 8;
    bf16x8 yv = *(const bf16x8*)(ys + (long)r * DINNER + d0);
    bf16x8 zv = *(const bf16x8*)(zx + (long)r * NPAD + d0);
    float v[8]; float ss = 0.f;
#pragma unroll
    for (int j = 0; j < 8; ++j) {
        float t = (float)yv[j] * fsilu((float)zv[j]);
        v[j] = t; ss += t * t;
    }
#pragma unroll
    for (int off = 32; off; off >>= 1) ss += __shfl_down(ss, off, 64);
    if ((tid & 63) == 0) sm[tid >> 6] = ss;
    __syncthreads();
    float sc = rsqrtf((sm[0] + sm[1] + sm[2]) / (float)DINNER + EPS);
    float4 w0 = *(const float4*)(w + d0);
    float4 w1 = *(const float4*)(w + d0 + 4);
    float wa[8] = {w0.x, w0.y, w0.z, w0.w, w1.x, w1.y, w1.z, w1.w};
    bf16x8 o;
#pragma unroll
    for (int j = 0; j < 8; ++j) o[j] = (bf16)(v[j] * sc * wa[j]);
    *(bf16x8*)(out + (long)r * DINNER + d0) = o;
}

// ---------------- head: 32 rows/block, 1 atomic/block ----------------
__global__ __launch_bounds__(256) void k_head(const bf16* __restrict__ hn, const float* __restrict__ Wh,
                                              const float* __restrict__ y, float* __restrict__ out,
                                              float* __restrict__ loss) {
    __shared__ float sl[4];
    int tid = threadIdx.x, lane = tid & 63, wid = tid >> 6;
    float wv[5][12];
#pragma unroll
    for (int o = 0; o < 5; ++o)
#pragma unroll
        for (int j = 0; j < 12; ++j) wv[o][j] = Wh[o * DMODEL + lane * 12 + j];
    float lsum = 0.f;
#pragma unroll
    for (int rr = 0; rr < 8; ++rr) {
        long r = (long)blockIdx.x * 32 + wid * 8 + rr;
        const bf16* hp = hn + r * DMODEL + lane * 12;
        float hv[12];
#pragma unroll
        for (int q = 0; q < 3; ++q) {
            bf16x4 v4 = *(const bf16x4*)(hp + q * 4);
#pragma unroll
            for (int j = 0; j < 4; ++j) hv[q * 4 + j] = (float)v4[j];
        }
        float acc[5];
#pragma unroll
        for (int o = 0; o < 5; ++o) {
            float a = 0.f;
#pragma unroll
            for (int j = 0; j < 12; ++j) a += hv[j] * wv[o][j];
            acc[o] = a;
        }
#pragma unroll
        for (int o = 0; o < 5; ++o)
#pragma unroll
            for (int m = 32; m; m >>= 1) acc[o] += __shfl_xor(acc[o], m, 64);
        if (lane == 0) {
#pragma unroll
            for (int o = 0; o < 5; ++o) {
                out[r * 5 + o] = acc[o];
                float d = acc[o] - y[r * 5 + o];
                lsum += d * d;
            }
        }
    }
    if (lane == 0) sl[wid] = lsum;
    __syncthreads();
    if (tid == 0) atomicAdd(loss, (sl[0] + sl[1] + sl[2] + sl[3]) * (1.f / ((float)ROWS * 5.f)));
}

extern "C" void kernel_launch(void* const* d_in, const int* in_sizes, int n_in,
                              void* d_out, int out_size, void* d_ws, size_t ws_size,
                              hipStream_t stream) {
    const float* x      = (const float*)d_in[0];
    const float* y      = (const float*)d_in[1];
    const float* W_emb  = (const float*)d_in[2];
    const float* b_emb  = (const float*)d_in[3];
    const float* W_in   = (const float*)d_in[4];
    const float* conv_w = (const float*)d_in[5];
    const float* conv_b = (const float*)d_in[6];
    const float* dt_bias= (const float*)d_in[7];
    const float* A_log  = (const float*)d_in[8];
    const float* Dp     = (const float*)d_in[9];
    const float* norm_w = (const float*)d_in[10];
    const float* W_out  = (const float*)d_in[11];
    const float* bnw    = (const float*)d_in[12];
    const float* nfw    = (const float*)d_in[13];
    const float* W_head = (const float*)d_in[14];

    char* ws = (char*)d_ws;
    float* res  = (float*)ws;  ws += (size_t)ROWS * DMODEL * 4;
    bf16*  Lbuf = (bf16*)ws;   ws += (size_t)BATCH * NHEADS * NCH * 8192 * 2;
    bf16*  hnb  = (bf16*)ws;   ws += (size_t)ROWS * DMODEL * 2;
    bf16*  zx   = (bf16*)ws;   ws += (size_t)ROWS * NPAD * 2;
    bf16*  bc   = (bf16*)ws;   ws += (size_t)ROWS * 256 * 2;
    bf16*  ysb  = (bf16*)ws;   ws += (size_t)ROWS * DINNER * 2;
    bf16*  yfb  = (bf16*)ws;   ws += (size_t)ROWS * DINNER * 2;
    bf16*  Wib  = (bf16*)ws;   ws += (size_t)NLAYER * NPADW * DMODEL * 2;
    bf16*  Wob  = (bf16*)ws;   ws += (size_t)NLAYER * DMODEL * DINNER * 2;
    float* Pcb  = (float*)ws;  ws += (size_t)BATCH * NHEADS * NCH * 4;
    float* Sarr = (float*)ws;  ws += (size_t)BATCH * NHEADS * NCH * QCH * 4;
    float* dtc  = (float*)ws;  ws += (size_t)BATCH * NHEADS * NCH * QCH * 4;
    bf16*  XT   = (bf16*)ws;   ws += (size_t)BATCH * NHEADS * NCH * 8192 * 2;

    float* out_p  = (float*)d_out;
    float* loss_p = out_p + (size_t)ROWS * 5;

    hipMemsetAsync(loss_p, 0, 4, stream);
    k_embed<<<ROWS * DMODEL / 256, 256, 0, stream>>>(x, W_emb, b_emb, res);
    k_cvt_in<<<NLAYER * NPADW * DMODEL / 256, 256, 0, stream>>>(W_in, Wib);
    k_cvt_out<<<NLAYER * DMODEL * DINNER / 256, 256, 0, stream>>>(W_out, Wob);

    const int NBHC = BATCH * NHEADS * NCH;   // 1536
    for (int l = 0; l < NLAYER; ++l) {
        const float* cw_l = conv_w + (size_t)l * CONVDIM * 4;
        const float* cb_l = conv_b + (size_t)l * CONVDIM;
        k_rmsnorm<<<ROWS, 192, 0, stream>>>(res, bnw + l * DMODEL, hnb);
        dim3 g1(ROWS / 256, NPADW / 256);
        k_gemm<bf16, 256, 256, 512, false><<<g1, 512, 0, stream>>>(hnb, Wib + (size_t)l * NPADW * DMODEL, zx, DMODEL, NPAD, NPAD);
        k_convBC<<<ROWS * 32 / 256, 256, 0, stream>>>(zx, cw_l, cb_l, bc);
        k_prepL<<<NBHC, 256, 0, stream>>>(zx, bc, cw_l, cb_l, dt_bias + l * NHEADS, A_log + l * NHEADS,
                                          Sarr, dtc, Pcb, XT, Lbuf);
        k_scanB<<<BATCH * NHEADS * 4, 256, 0, stream>>>(Lbuf, Pcb);
        k_chunkY<<<NBHC, 512, 0, stream>>>(bc, Sarr, dtc, Dp + l * NHEADS, XT, Lbuf, ysb);
        k_gated<<<ROWS, 192, 0, stream>>>(ysb, zx, norm_w + l * DINNER, yfb);
        dim3 g2(ROWS / 128, DMODEL / 64);
        k_gemm<float, 128, 64, 256, true><<<g2, 256, 0, stream>>>(yfb, Wob + (size_t)l * DMODEL * DINNER, res, DINNER, DMODEL, DMODEL);
    }

    k_rmsnorm<<<ROWS, 192, 0, stream>>>(res, nfw, hnb);
    k_head<<<256, 256, 0, stream>>>(hnb, W_head, y, out_p, loss_p);
}